// Round 4
// baseline (403.954 us; speedup 1.0000x reference)
//
#include <hip/hip_runtime.h>
#include <hip/hip_bf16.h>
#include <math.h>

#define HW 16384   // 128*128 bev pixels

typedef __attribute__((ext_vector_type(8))) short short8;
typedef __attribute__((ext_vector_type(4))) float floatx4;
typedef __attribute__((ext_vector_type(2))) float floatx2;

__device__ __forceinline__ float gelu_exact(float x){
    return 0.5f * x * (1.0f + erff(x * 0.7071067811865475f));
}

__device__ __forceinline__ floatx2 bf2x(unsigned int u){
    floatx2 r;
    r.x = __uint_as_float(u << 16);
    r.y = __uint_as_float(u & 0xffff0000u);
    return r;
}

// ---------------- all-level feat transpose: (N,C,H,W) fp32 -> (N,H,W,C) bf16 ----------------
// LDS-tiled: coalesced reads along x, coalesced 16B HWC writes.
template<int CW, int HL, int WL>
__device__ __forceinline__ void ft_tile(
    float* tile, const float* __restrict__ in, __hip_bfloat16* __restrict__ out,
    int n, int y, int x0, int base, int t)
{
    // read: 128 channels x CW floats (coalesced along x)
    const float* src = in + ((size_t)n * 128 * HL + y) * WL + x0;
    constexpr int NE = 128 * CW;
    for (int idx = t; idx < NE; idx += 256) {
        int c = idx / CW, x = idx - c * CW;
        tile[c * 45 + x] = src[(size_t)c * (HL * WL) + x];
    }
    __syncthreads();
    // write: CW pixels x 16 uint4 (128 bf16 per pixel, contiguous)
    __hip_bfloat16* dst = out + base + ((size_t)(n * HL + y) * WL + x0) * 128;
    constexpr int NO = CW * 16;
    for (int idx = t; idx < NO; idx += 256) {
        int x = idx >> 4, g = idx & 15;
        union { __hip_bfloat16 h[8]; uint4 u; } pk;
        #pragma unroll
        for (int jj = 0; jj < 8; jj++)
            pk.h[jj] = __float2bfloat16(tile[(g * 8 + jj) * 45 + x]);
        *(uint4*)&dst[(size_t)x * 128 + g * 8] = pk.u;
    }
}

__global__ __launch_bounds__(256) void feat_transpose_all_k(
    const float* __restrict__ f0, const float* __restrict__ f1,
    const float* __restrict__ f2, const float* __restrict__ f3,
    __hip_bfloat16* __restrict__ out)
{
    __shared__ float tile[128 * 45];
    int b = blockIdx.x, t = threadIdx.x;
    if (b < 384) {            // l0: 6 cams * 32 y * 2 xchunks
        int n = b >> 6, q = b & 63, y = q >> 1, x0 = (q & 1) * 44;
        ft_tile<44, 32, 88>(tile, f0, out, n, y, x0, 0, t);
    } else if (b < 480) {     // l1: 6 * 16
        int r = b - 384, n = r >> 4, y = r & 15;
        ft_tile<44, 16, 44>(tile, f1, out, n, y, 0, 2162688, t);
    } else if (b < 528) {     // l2: 6 * 8
        int r = b - 480, n = r >> 3, y = r & 7;
        ft_tile<22, 8, 22>(tile, f2, out, n, y, 0, 2703360, t);
    } else {                  // l3: 6 * 4
        int r = b - 528, n = r >> 2, y = r & 3;
        ft_tile<11, 4, 11>(tile, f3, out, n, y, 0, 2838528, t);
    }
}

// ---------------- unified weight prep (block-range dispatch) ----------------
__global__ __launch_bounds__(256) void prep_k(
    const float* __restrict__ mid_w1, const float* __restrict__ mid_w2,
    const float* __restrict__ mid_w3, const float* __restrict__ pe_w2,
    const float* __restrict__ off_w,  const float* __restrict__ off_b,
    const float* __restrict__ sw_w,   const float* __restrict__ sw_b,
    const float* __restrict__ in_w,   const float* __restrict__ out_w,
    __hip_bfloat16* __restrict__ Wb1, __hip_bfloat16* __restrict__ Wb2,
    __hip_bfloat16* __restrict__ Wb3, __hip_bfloat16* __restrict__ Wpe,
    __hip_bfloat16* __restrict__ Wof, float* __restrict__ Bof,
    __hip_bfloat16* __restrict__ Wcv1, __hip_bfloat16* __restrict__ Wcv2)
{
    int b = blockIdx.x, t = threadIdx.x;
    if (b < 2048) {
        int i = b * 256 + t; Wb1[i] = __float2bfloat16(mid_w1[i]);
    } else if (b < 3072) {
        int i = (b - 2048) * 256 + t; Wb2[i] = __float2bfloat16(mid_w2[i]);
    } else if (b < 3328) {
        int i = (b - 3072) * 256 + t; Wb3[i] = __float2bfloat16(mid_w3[i]);
    } else if (b < 3456) {
        int n = b - 3328; Wpe[n * 256 + t] = __float2bfloat16(pe_w2[t * 128 + n]);
    } else if (b < 3584) {
        int n = b - 3456;
        if (t < 128) {
            float w = 0.f;
            if (n < 24)      w = off_w[n * 128 + t];
            else if (n < 56) w = sw_w[(n - 24) * 128 + t];
            Wof[n * 128 + t] = __float2bfloat16(w);
            if (t == 0) Bof[n] = (n < 24) ? off_b[n] : ((n < 56) ? sw_b[n - 24] : 0.f);
        }
    } else if (b < 3712) {
        int o = b - 3584;
        for (int idx = t; idx < 1152; idx += 256) {
            int s = idx >> 7, i = idx & 127;
            Wcv1[o * 1152 + idx] = __float2bfloat16(in_w[(o * 128 + i) * 9 + s]);
        }
    } else {
        int o = b - 3712;
        for (int idx = t; idx < 1152; idx += 256) {
            int s = idx >> 7, i = idx & 127;
            Wcv2[o * 1152 + idx] = __float2bfloat16(out_w[(o * 128 + i) * 9 + s]);
        }
    }
}

// ---------------- CHW fp32 [128][128^2] -> padded HWC bf16 [130][130][128] (interior) ----------------
// stats (optional): per-channel {sum, sumsq}; applies instance-norm while packing.
__global__ __launch_bounds__(256) void chw2hwc_pad_k(
    const float* __restrict__ q, const float* __restrict__ stats,
    __hip_bfloat16* __restrict__ out)
{
    __shared__ float tile[128][65];
    __shared__ float sm[128], sr[128];
    int t = threadIdx.x;
    if (t < 128) {
        if (stats) {
            float s = stats[2 * t], s2 = stats[2 * t + 1];
            float mean = s * (1.0f / HW);
            sm[t] = mean;
            sr[t] = rsqrtf(s2 * (1.0f / HW) - mean * mean + 1e-5f);
        } else {
            sm[t] = 0.f; sr[t] = 1.f;
        }
    }
    int b = blockIdx.x;            // 256 blocks: y = b>>1, x0 = (b&1)*64
    int y = b >> 1, x0 = (b & 1) * 64;
    int xi = t & 63, c0 = t >> 6;
    for (int c = c0; c < 128; c += 4)
        tile[c][xi] = q[c * HW + y * 128 + x0 + xi];
    __syncthreads();
    int xp = t >> 2, cg = (t & 3) * 32;
    __hip_bfloat16* dst = out + ((size_t)(y + 1) * 130 + (x0 + 1 + xp)) * 128;
    #pragma unroll
    for (int g = 0; g < 4; g++) {
        int c = cg + g * 8;
        union { __hip_bfloat16 h[8]; uint4 u; } pk;
        #pragma unroll
        for (int j = 0; j < 8; j++)
            pk.h[j] = __float2bfloat16((tile[c + j][xp] - sm[c + j]) * sr[c + j]);
        *(uint4*)&dst[c] = pk.u;
    }
}

// ---------------- bf16 MFMA GEMM: out[m][n] = act(bias[n] + sum_k X[m][k] W[n][k]) ----------------
// OUTT: 0 -> bf16 [M][N]; 1 -> fp32 [N][M] (CHW, + optional residual res[n][m]).
// CONV: X is padded HWC bf16 [130][130][128]; k = s*128+c.
// rstats: normalize residual with {sum,sumsq}; ostats: accumulate output {sum,sumsq} (OUTT==1 only).
// K-loop: NBUF-deep LDS pipeline with counted vmcnt (never 0 in steady state) + raw s_barrier.
// LDS XOR-swizzle (both-sides): global source chunk permuted on stage, ds_read slot permuted to match.
template<int BM, int BN, int ACT, int OUTT, int CONV>
__global__ __launch_bounds__(256) void bgemm_k(
    const __hip_bfloat16* __restrict__ X, const __hip_bfloat16* __restrict__ W,
    const float* __restrict__ bias, void* __restrict__ outp,
    const float* __restrict__ res,
    const float* __restrict__ rstats, float* __restrict__ ostats,
    int M, int K, int N)
{
    constexpr int ROWS = BM + BN;
    constexpr int ITERS = (ROWS * 4) / 256;       // global_load_lds per lane per stage
    constexpr int BUFE  = ROWS * 32;              // bf16 elements per buffer
    constexpr int NBUF  = (ITERS == 2) ? 4 : 3;   // 32 KB / 48 KB LDS
    __shared__ __align__(16) __hip_bfloat16 SH[NBUF * BUFE];
    int t = threadIdx.x;
    int w = t >> 6, lane = t & 63;
    int mb = blockIdx.y * BM, nb = blockIdx.x * BN;
    int cy = mb >> 7, cx = mb & 127;   // conv tile coords (CONV only)
    constexpr int WM = BM / 2;
    constexpr int MI = WM / 16;
    constexpr int NJ = BN / 32;
    int wm = (w & 1) * WM, wn = (w >> 1) * (BN / 2);
    int lm = lane & 15, lq = lane >> 4;
    int sl = (lq ^ ((lm >> 1) & 3)) * 8;          // swizzled k-slot for ds_read
    floatx4 zero = {0.f, 0.f, 0.f, 0.f};
    floatx4 acc[MI][NJ];
    #pragma unroll
    for (int i = 0; i < MI; i++)
        #pragma unroll
        for (int j = 0; j < NJ; j++) acc[i][j] = zero;

    const int nsteps = K >> 5;

    auto STAGE = [&](int bufi, int tk2) {
        int kb_ = tk2 * 32;
        int s_ = kb_ >> 7;
        int dyi_ = s_ / 3, dxi_ = s_ - dyi_ * 3;   // tap indices (CONV only)
        #pragma unroll
        for (int it = 0; it < ITERS; it++) {
            int chunk = it * 256 + t;
            int row = chunk >> 2;
            int ko = ((chunk & 3) ^ ((row >> 1) & 3)) * 8;   // source-side swizzle
            const __hip_bfloat16* src;
            if (row < BM) {
                if (CONV)
                    src = X + (((size_t)(cy + dyi_) * 130) + (cx + dxi_ + row)) * 128 + (kb_ & 127) + ko;
                else
                    src = X + (size_t)(mb + row) * K + kb_ + ko;
            } else {
                src = W + (size_t)(nb + row - BM) * K + kb_ + ko;
            }
            __builtin_amdgcn_global_load_lds(
                (const __attribute__((address_space(1))) void*)src,
                (__attribute__((address_space(3))) void*)&SH[bufi * BUFE + (it * 256 + (t & ~63)) * 8],
                16, 0, 0);
        }
    };

    #pragma unroll
    for (int pi = 0; pi < NBUF - 1; pi++)
        if (pi < nsteps) STAGE(pi, pi);

    for (int tk = 0; tk < nsteps; ++tk) {
        int rem = nsteps - 1 - tk;
        if constexpr (ITERS == 2) {                // NBUF=4: up to 2 stages beyond current
            if (rem >= 2)      asm volatile("s_waitcnt vmcnt(4)" ::: "memory");
            else if (rem == 1) asm volatile("s_waitcnt vmcnt(2)" ::: "memory");
            else               asm volatile("s_waitcnt vmcnt(0)" ::: "memory");
        } else {                                   // NBUF=3: up to 1 stage beyond current
            if (rem >= 1)      asm volatile("s_waitcnt vmcnt(4)" ::: "memory");
            else               asm volatile("s_waitcnt vmcnt(0)" ::: "memory");
        }
        __builtin_amdgcn_s_barrier();
        int tkn = tk + NBUF - 1;
        if (tkn < nsteps) STAGE(tkn % NBUF, tkn);

        const __hip_bfloat16* As = SH + (tk % NBUF) * BUFE;
        const __hip_bfloat16* Bs = As + BM * 32;
        short8 af[MI], bf[NJ];
        #pragma unroll
        for (int i = 0; i < MI; i++)
            af[i] = *(const short8*)&As[(wm + i * 16 + lm) * 32 + sl];
        #pragma unroll
        for (int j = 0; j < NJ; j++)
            bf[j] = *(const short8*)&Bs[(wn + j * 16 + lm) * 32 + sl];
        #pragma unroll
        for (int i = 0; i < MI; i++)
            #pragma unroll
            for (int j = 0; j < NJ; j++)
                acc[i][j] = __builtin_amdgcn_mfma_f32_16x16x32_bf16(af[i], bf[j], acc[i][j], 0, 0, 0);
    }

    float invM = 1.0f / (float)M;
    #pragma unroll
    for (int j = 0; j < NJ; j++) {
        int n = nb + wn + j * 16 + lm;
        float bv = bias[n];
        float rmean = 0.f, rrstd = 0.f;
        if (OUTT == 1 && res && rstats) {
            float s = rstats[2 * n], s2 = rstats[2 * n + 1];
            rmean = s * invM;
            rrstd = rsqrtf(s2 * invM - rmean * rmean + 1e-5f);
        }
        float ss = 0.f, ss2 = 0.f;
        #pragma unroll
        for (int i = 0; i < MI; i++) {
            #pragma unroll
            for (int r = 0; r < 4; r++) {
                int m = mb + wm + i * 16 + lq * 4 + r;
                float v = acc[i][j][r] + bv;
                if (ACT) v = gelu_exact(v);
                if (OUTT == 0) {
                    ((__hip_bfloat16*)outp)[(size_t)m * N + n] = __float2bfloat16(v);
                } else {
                    if (res) {
                        float rv = res[(size_t)n * M + m];
                        v += rstats ? (rv - rmean) * rrstd : rv;
                    }
                    ((float*)outp)[(size_t)n * M + m] = v;
                    ss += v; ss2 += v * v;
                }
            }
        }
        if (OUTT == 1 && ostats) {
            ss  += __shfl_xor(ss, 16);  ss  += __shfl_xor(ss, 32);
            ss2 += __shfl_xor(ss2, 16); ss2 += __shfl_xor(ss2, 32);
            if (lq == 0) {
                atomicAdd(&ostats[2 * n], ss);
                atomicAdd(&ostats[2 * n + 1], ss2);
            }
        }
    }
}

// ---------------- fused PE: hidden = relu(rn @ w1 + b1) on the fly, GEMM vs Wpe ----------------
__global__ __launch_bounds__(256) void pe_bgemm_k(
    const float* __restrict__ pts, const float* __restrict__ pe_w1,
    const float* __restrict__ pe_b1, const __hip_bfloat16* __restrict__ W,
    const float* __restrict__ bias, __hip_bfloat16* __restrict__ out)
{
    __shared__ __align__(16) __hip_bfloat16 As[128 * 32];
    __shared__ __align__(16) __hip_bfloat16 Bs[128 * 32];
    __shared__ __align__(16) float wps[4][256];   // [b1, w1_x, w1_y, w1_z][256]
    int t = threadIdx.x;
    int w = t >> 6, lane = t & 63;
    int mb = blockIdx.x * 128;
    {
        int d = t >> 6, c = (t & 63) * 4;
        float4 v;
        if (d == 0) v = *(const float4*)&pe_b1[c];
        else        v = *(const float4*)&pe_w1[(d - 1) * 256 + c];
        *(float4*)&wps[d][c] = v;
    }
    int cg = t & 3;
    int r0 = t >> 2;
    float rn[2][3];
    #pragma unroll
    for (int h = 0; h < 2; h++) {
        int r = mb + r0 + h * 64;
        rn[h][0] = (pts[(size_t)r * 3 + 0] + 50.f) * 0.01f;
        rn[h][1] = (pts[(size_t)r * 3 + 1] + 50.f) * 0.01f;
        rn[h][2] = (pts[(size_t)r * 3 + 2] + 4.f) * 0.125f;
    }
    int wm = (w & 1) * 64, wn = (w >> 1) * 64;
    int lm = lane & 15, lq = lane >> 4;
    floatx4 zero = {0.f, 0.f, 0.f, 0.f};
    floatx4 acc[4][4];
    #pragma unroll
    for (int i = 0; i < 4; i++)
        #pragma unroll
        for (int j = 0; j < 4; j++) acc[i][j] = zero;
    for (int kb = 0; kb < 256; kb += 32) {
        __syncthreads();
        #pragma unroll
        for (int it = 0; it < 2; it++) {
            int chunk = it * 256 + t;
            int brow = chunk >> 2, ko = (chunk & 3) * 8;
            const __hip_bfloat16* src = W + (size_t)brow * 256 + kb + ko;
            __builtin_amdgcn_global_load_lds(
                (const __attribute__((address_space(1))) void*)src,
                (__attribute__((address_space(3))) void*)&Bs[(size_t)(it * 256 + (t & ~63)) * 8],
                16, 0, 0);
        }
        int c0 = kb + cg * 8;
        float4 bva = *(const float4*)&wps[0][c0], bvb = *(const float4*)&wps[0][c0 + 4];
        float4 wxa = *(const float4*)&wps[1][c0], wxb = *(const float4*)&wps[1][c0 + 4];
        float4 wya = *(const float4*)&wps[2][c0], wyb = *(const float4*)&wps[2][c0 + 4];
        float4 wza = *(const float4*)&wps[3][c0], wzb = *(const float4*)&wps[3][c0 + 4];
        #pragma unroll
        for (int h = 0; h < 2; h++) {
            const float* bv = (const float*)&bva;
            const float* wx = (const float*)&wxa;
            const float* wy = (const float*)&wya;
            const float* wz = (const float*)&wza;
            union { __hip_bfloat16 hh[8]; uint4 u; } pk;
            #pragma unroll
            for (int j = 0; j < 4; j++) {
                float v = bv[j] + rn[h][0] * wx[j] + rn[h][1] * wy[j] + rn[h][2] * wz[j];
                pk.hh[j] = __float2bfloat16(fmaxf(v, 0.f));
            }
            bv = (const float*)&bvb; wx = (const float*)&wxb;
            wy = (const float*)&wyb; wz = (const float*)&wzb;
            #pragma unroll
            for (int j = 0; j < 4; j++) {
                float v = bv[j] + rn[h][0] * wx[j] + rn[h][1] * wy[j] + rn[h][2] * wz[j];
                pk.hh[4 + j] = __float2bfloat16(fmaxf(v, 0.f));
            }
            *(uint4*)&As[(r0 + h * 64) * 32 + cg * 8] = pk.u;
        }
        __syncthreads();
        short8 af[4], bf[4];
        #pragma unroll
        for (int i = 0; i < 4; i++)
            af[i] = *(const short8*)&As[(wm + i * 16 + lm) * 32 + lq * 8];
        #pragma unroll
        for (int j = 0; j < 4; j++)
            bf[j] = *(const short8*)&Bs[(wn + j * 16 + lm) * 32 + lq * 8];
        #pragma unroll
        for (int i = 0; i < 4; i++)
            #pragma unroll
            for (int j = 0; j < 4; j++)
                acc[i][j] = __builtin_amdgcn_mfma_f32_16x16x32_bf16(af[i], bf[j], acc[i][j], 0, 0, 0);
    }
    #pragma unroll
    for (int i = 0; i < 4; i++) {
        #pragma unroll
        for (int j = 0; j < 4; j++) {
            int n = wn + j * 16 + lm;
            float bv = bias[n];
            #pragma unroll
            for (int r = 0; r < 4; r++) {
                int m = mb + wm + i * 16 + lq * 4 + r;
                out[(size_t)m * 128 + n] = __float2bfloat16(acc[i][j][r] + bv);
            }
        }
    }
}

// ---------------- final instance norm apply (stats precomputed in producer epilogue) ----------------
__global__ __launch_bounds__(256) void inorm_apply_k(
    const float* __restrict__ in, const float* __restrict__ stats, float* __restrict__ out)
{
    int b = blockIdx.x;           // 1024 blocks: c = b>>3, seg = b&7 (2048 floats each)
    int c = b >> 3, seg = b & 7;
    float s = stats[2 * c], s2 = stats[2 * c + 1];
    float mean = s * (1.0f / HW);
    float rstd = rsqrtf(s2 * (1.0f / HW) - mean * mean + 1e-5f);
    const float4* pi = (const float4*)(in + (size_t)c * HW + seg * 2048);
    float4*       po = (float4*)(out + (size_t)c * HW + seg * 2048);
    int t = threadIdx.x;
    #pragma unroll
    for (int k = 0; k < 2; k++) {
        float4 v = pi[t + k * 256];
        v.x = (v.x - mean) * rstd; v.y = (v.y - mean) * rstd;
        v.z = (v.z - mean) * rstd; v.w = (v.w - mean) * rstd;
        po[t + k * 256] = v;
    }
}

// ---------------- offsw epilogue: raw [n][16384] fp32 -> pts/swn/height ----------------
__global__ __launch_bounds__(256) void offpost_k(
    const float* __restrict__ raw, const float* __restrict__ bev_pos,
    float* __restrict__ pts, float* __restrict__ swn, float* __restrict__ height_out)
{
    int pix = blockIdx.x * 256 + threadIdx.x;
    const float pcmin[3] = {-50.f, -50.f, -4.f};
    const float rng[3]   = {100.f, 100.f, 8.f};
    float bp[3];
    #pragma unroll
    for (int d = 0; d < 3; d++) bp[d] = bev_pos[pix * 3 + d];
    #pragma unroll
    for (int p = 0; p < 8; p++) {
        #pragma unroll
        for (int d = 0; d < 3; d++) {
            float acc = raw[(p * 3 + d) * HW + pix];
            float sv = 1.f / (1.f + expf(-acc));
            float lim = (d == 2) ? (4.0f + 1e-6f) : (0.25f + 1e-6f);
            float offv = sv * 2.f * lim - lim;
            float refv = bp[d] * rng[d] + pcmin[d];
            pts[pix * 24 + p * 3 + d] = refv + offv;
            if (d == 2) height_out[p * HW + pix] = offv;
        }
        float r[4], m = -1e30f;
        #pragma unroll
        for (int l = 0; l < 4; l++) {
            r[l] = raw[(24 + p * 4 + l) * HW + pix];
            m = fmaxf(m, r[l]);
        }
        float sum = 0.f;
        #pragma unroll
        for (int l = 0; l < 4; l++) { r[l] = expf(r[l] - m); sum += r[l]; }
        float inv = 1.f / sum;
        #pragma unroll
        for (int l = 0; l < 4; l++) swn[pix * 32 + p * 4 + l] = r[l] * inv;
    }
}

// ---------------- sampling: phase-1 projection + cull, phase-2 bf16 packed gather ----------------
// 512 threads = 8 waves; wave wv owns p = wv (one slot per wave).
// Gather (R2 structure): per-lane floatx2 channels, 4 independent corner loads per tap,
// 2-tap unroll with split accumulators -> 8 loads in flight.
// XCD swizzle: pix = (bid&7)*2048 + (bid>>3) gives each XCD a contiguous BEV band for L2 reuse.
__global__ __launch_bounds__(512) void sample_k(
    const __hip_bfloat16* __restrict__ featT, const float* __restrict__ pts,
    const float* __restrict__ swn,   const float* __restrict__ l2i,
    __hip_bfloat16* __restrict__ sf)
{
    int bid = blockIdx.x;
    int pix = (bid & 7) * 2048 + (bid >> 3);
    int t = threadIdx.x;
    int lane = t & 63, wv = t >> 6;
    __shared__ float pts_s[24];
    __shared__ float swl_s[32];
    __shared__ float M[96];
    __shared__ __align__(16) int   offs[8][24][4];   // byte offsets into featT
    __shared__ __align__(16) float wts[8][24][4];
    __shared__ int cnt[8];
    if (t < 96) M[t] = l2i[t];
    if (t < 24) pts_s[t] = pts[pix * 24 + t];
    if (t < 32) swl_s[t] = swn[pix * 32 + t];
    if (t < 8)  cnt[t] = 0;
    __syncthreads();

    floatx2 acc;
    {
        unsigned int u = *(const unsigned int*)&sf[(size_t)pix * 1024 + wv * 128 + 2 * lane];
        acc = bf2x(u);
    }

    const int lHt[4] = {32, 16, 8, 4}, lWt[4] = {88, 44, 22, 11};
    const int loff[4] = {0, 2162688, 2703360, 2838528};
    if (t < 192) {
        int p = t / 24;
        int rr = t - p * 24;
        int n = rr >> 2, l = rr & 3;
        float X = pts_s[p * 3], Y = pts_s[p * 3 + 1], Z = pts_s[p * 3 + 2];
        const float* Mn = &M[n * 16];
        float zc = Mn[8] * X + Mn[9] * Y + Mn[10] * Z + Mn[11];
        if (zc > 1e-5f) {
            float inv = 1.f / zc;
            float xn = (Mn[0] * X + Mn[1] * Y + Mn[2] * Z + Mn[3]) * inv * (1.f / 704.f);
            float yn = (Mn[4] * X + Mn[5] * Y + Mn[6] * Z + Mn[7]) * inv * (1.f / 256.f);
            int Wl = lWt[l], Hl = lHt[l];
            float px = xn * Wl - 0.5f, py = yn * Hl - 0.5f;
            px = fminf(fmaxf(px, -2.f), (float)(Wl + 1));
            py = fminf(fmaxf(py, -2.f), (float)(Hl + 1));
            float x0f = floorf(px), y0f = floorf(py);
            float wx = px - x0f, wy = py - y0f;
            int x0 = (int)x0f, y0 = (int)y0f;
            bool xi0 = (unsigned)x0 < (unsigned)Wl, xi1 = (unsigned)(x0 + 1) < (unsigned)Wl;
            bool yi0 = (unsigned)y0 < (unsigned)Hl, yi1 = (unsigned)(y0 + 1) < (unsigned)Hl;
            if ((xi0 || xi1) && (yi0 || yi1)) {
                float wl = swl_s[p * 4 + l];
                float w00 = wl * (1.f - wx) * (1.f - wy) * (float)(xi0 && yi0);
                float w10 = wl * wx * (1.f - wy)         * (float)(xi1 && yi0);
                float w01 = wl * (1.f - wx) * wy         * (float)(xi0 && yi1);
                float w11 = wl * wx * wy                 * (float)(xi1 && yi1);
                int x0c = min(max(x0, 0), Wl - 1), x1c = min(max(x0 + 1, 0), Wl - 1);
                int y0c = min(max(y0, 0), Hl - 1), y1c = min(max(y0 + 1, 0), Hl - 1);
                int base = loff[l] + n * Hl * Wl * 128;
                int idx = atomicAdd(&cnt[p], 1);
                offs[p][idx][0] = (base + (y0c * Wl + x0c) * 128) * 2;
                offs[p][idx][1] = (base + (y0c * Wl + x1c) * 128) * 2;
                offs[p][idx][2] = (base + (y1c * Wl + x0c) * 128) * 2;
                offs[p][idx][3] = (base + (y1c * Wl + x1c) * 128) * 2;
                wts[p][idx][0] = w00; wts[p][idx][1] = w10;
                wts[p][idx][2] = w01; wts[p][idx][3] = w11;
            }
        }
    }
    __syncthreads();

    const char* fbase = (const char*)featT;
    int lane4 = lane * 4;
    {
        int p = wv;
        int np = cnt[p];
        floatx2 a0 = acc;
        floatx2 a1 = {0.f, 0.f};
        int j = 0;
        #pragma unroll 1
        for (; j + 2 <= np; j += 2) {
            int4   oA = *(const int4*)&offs[p][j][0];
            float4 wA = *(const float4*)&wts[p][j][0];
            int4   oB = *(const int4*)&offs[p][j + 1][0];
            float4 wB = *(const float4*)&wts[p][j + 1][0];
            unsigned int v0 = *(const unsigned int*)(fbase + (unsigned)(oA.x + lane4));
            unsigned int v1 = *(const unsigned int*)(fbase + (unsigned)(oA.y + lane4));
            unsigned int v2 = *(const unsigned int*)(fbase + (unsigned)(oA.z + lane4));
            unsigned int v3 = *(const unsigned int*)(fbase + (unsigned)(oA.w + lane4));
            unsigned int v4 = *(const unsigned int*)(fbase + (unsigned)(oB.x + lane4));
            unsigned int v5 = *(const unsigned int*)(fbase + (unsigned)(oB.y + lane4));
            unsigned int v6 = *(const unsigned int*)(fbase + (unsigned)(oB.z + lane4));
            unsigned int v7 = *(const unsigned int*)(fbase + (unsigned)(oB.w + lane4));
            a0 += bf2x(v0) * wA.x;
            a0 += bf2x(v1) * wA.y;
            a0 += bf2x(v2) * wA.z;
            a0 += bf2x(v3) * wA.w;
            a1 += bf2x(v4) * wB.x;
            a1 += bf2x(v5) * wB.y;
            a1 += bf2x(v6) * wB.z;
            a1 += bf2x(v7) * wB.w;
        }
        if (j < np) {
            int4   o = *(const int4*)&offs[p][j][0];
            float4 w = *(const float4*)&wts[p][j][0];
            unsigned int v0 = *(const unsigned int*)(fbase + (unsigned)(o.x + lane4));
            unsigned int v1 = *(const unsigned int*)(fbase + (unsigned)(o.y + lane4));
            unsigned int v2 = *(const unsigned int*)(fbase + (unsigned)(o.z + lane4));
            unsigned int v3 = *(const unsigned int*)(fbase + (unsigned)(o.w + lane4));
            a0 += bf2x(v0) * w.x;
            a0 += bf2x(v1) * w.y;
            a0 += bf2x(v2) * w.z;
            a0 += bf2x(v3) * w.w;
        }
        acc = a0 + a1;
    }
    {
        union { __hip_bfloat16 h[2]; unsigned int u; } pk;
        pk.h[0] = __float2bfloat16(acc.x);
        pk.h[1] = __float2bfloat16(acc.y);
        *(unsigned int*)&sf[(size_t)pix * 1024 + wv * 128 + 2 * lane] = pk.u;
    }
}

extern "C" void kernel_launch(void* const* d_in, const int* in_sizes, int n_in,
                              void* d_out, int out_size, void* d_ws, size_t ws_size,
                              hipStream_t stream)
{
    const float* feat[4] = {(const float*)d_in[0], (const float*)d_in[1],
                            (const float*)d_in[2], (const float*)d_in[3]};
    const float* l2i       = (const float*)d_in[4];
    const float* bev_query = (const float*)d_in[5];
    const float* bev_pos   = (const float*)d_in[6];
    const float* in_w  = (const float*)d_in[7];  const float* in_b  = (const float*)d_in[8];
    const float* off_w = (const float*)d_in[9];  const float* off_b = (const float*)d_in[10];
    const float* sw_w  = (const float*)d_in[11]; const float* sw_b  = (const float*)d_in[12];
    const float* pe_w1 = (const float*)d_in[13]; const float* pe_b1 = (const float*)d_in[14];
    const float* pe_w2 = (const float*)d_in[15]; const float* pe_b2 = (const float*)d_in[16];
    const float* mid_w1 = (const float*)d_in[17]; const float* mid_b1 = (const float*)d_in[18];
    const float* mid_w2 = (const float*)d_in[19]; const float* mid_b2 = (const float*)d_in[20];
    const float* mid_w3 = (const float*)d_in[21]; const float* mid_b3 = (const float*)d_in[22];
    const float* out_w  = (const float*)d_in[23]; const float* out_b  = (const float*)d_in[24];

    float* ws = (float*)d_ws;
    float* fTf = ws;                    // 1,436,160 : transposed feats bf16
    __hip_bfloat16* fT = (__hip_bfloat16*)fTf;
    float* Bb  = fTf + 1436160;         // 2,097,152 : offsw raw / q1 raw (CHW)
    float* Cb  = Bb + 2097152;          // 2,097,152 : q0 raw (conv1 out, CHW)
    float* Gb  = Cb + 2097152;          // 2,097,152 : conv2 raw (CHW)
    float* Dp  = Gb + 2097152;          //   393,216 : pts
    float* Eb  = Dp + 393216;           //   524,288 : swn
    float* QTf = Eb + 524288;           // 1,081,600 : padded HWC bf16 (130*130*128)
    __hip_bfloat16* qT = (__hip_bfloat16*)QTf;
    float* SFf = QTf + 1081600;         // 8,388,608 : sf bf16 131072x128
    __hip_bfloat16* sfb = (__hip_bfloat16*)SFf;
    float* M1f = SFf + 8388608;         // 4,194,304 : m1 bf16
    __hip_bfloat16* m1b = (__hip_bfloat16*)M1f;
    float* M2f = M1f + 4194304;         // 4,194,304 : m2 bf16
    __hip_bfloat16* m2b = (__hip_bfloat16*)M2f;
    float* WC1 = M2f + 4194304;         //    73,728 : conv1 weights bf16
    __hip_bfloat16* Wcv1 = (__hip_bfloat16*)WC1;
    float* WC2 = WC1 + 73728;           //    73,728 : conv2 weights bf16
    __hip_bfloat16* Wcv2 = (__hip_bfloat16*)WC2;
    float* W1f = WC2 + 73728;           //   262,144
    __hip_bfloat16* Wb1 = (__hip_bfloat16*)W1f;
    float* W2f = W1f + 262144;          //   131,072
    __hip_bfloat16* Wb2 = (__hip_bfloat16*)W2f;
    float* W3f = W2f + 131072;          //    32,768
    __hip_bfloat16* Wb3 = (__hip_bfloat16*)W3f;
    float* WPf = W3f + 32768;           //    16,384 : pe_w2^T bf16
    __hip_bfloat16* Wpe = (__hip_bfloat16*)WPf;
    float* WOf = WPf + 16384;           //     8,192 : offsw packed weight bf16
    __hip_bfloat16* Wof = (__hip_bfloat16*)WOf;
    float* Bof = WOf + 8192;            //       128 : offsw packed bias fp32
    float* Stats = Bof + 128;           //       768 : 3 x 128 x {sum,sumsq}
    float* stats1 = Stats;
    float* stats2 = Stats + 256;
    float* stats3 = Stats + 512;

    float* q_out = (float*)d_out;
    float* h_out = q_out + 2097152;

    hipMemsetAsync(qT, 0, (size_t)130 * 130 * 128 * sizeof(__hip_bfloat16), stream);
    hipMemsetAsync(Stats, 0, 768 * sizeof(float), stream);

    feat_transpose_all_k<<<552, 256, 0, stream>>>(feat[0], feat[1], feat[2], feat[3], fT);
    prep_k<<<3840, 256, 0, stream>>>(mid_w1, mid_w2, mid_w3, pe_w2, off_w, off_b, sw_w, sw_b,
                                     in_w, out_w, Wb1, Wb2, Wb3, Wpe, Wof, Bof, Wcv1, Wcv2);

    // conv1: q0raw = bev_query + conv3x3(bev_query) -> Cb, stats1 accumulated in epilogue
    chw2hwc_pad_k<<<256, 256, 0, stream>>>(bev_query, nullptr, qT);
    bgemm_k<64, 64, 0, 1, 1><<<dim3(2, 256), 256, 0, stream>>>(
        qT, Wcv1, in_b, Cb, bev_query, nullptr, stats1, HW, 1152, 128);

    // offsets/sample-weights GEMM over center tap of normalized q0 + epilogue
    chw2hwc_pad_k<<<256, 256, 0, stream>>>(Cb, stats1, qT);   // applies inorm(q0raw)
    bgemm_k<64, 64, 0, 1, 1><<<dim3(2, 256), 256, 0, stream>>>(
        qT + 131 * 128, Wof, Bof, Bb, nullptr, nullptr, nullptr, HW, 128, 128);
    offpost_k<<<64, 256, 0, stream>>>(Bb, bev_pos, Dp, Eb, h_out);

    // fused PE (hidden on the fly + MFMA GEMM) -> sf
    pe_bgemm_k<<<1024, 256, 0, stream>>>(Dp, pe_w1, pe_b1, Wpe, pe_b2, sfb);

    // sampling accumulates taps onto sf
    sample_k<<<HW, 512, 0, stream>>>(fT, Dp, Eb, l2i, sfb);

    // mid MLP: 1024 -> 512 gelu -> 512 gelu -> 128 linear (+ normalized q0 residual)
    bgemm_k<128, 128, 1, 0, 0><<<dim3(4, 128), 256, 0, stream>>>(
        sfb, Wb1, mid_b1, m1b, nullptr, nullptr, nullptr, HW, 1024, 512);
    bgemm_k<128, 128, 1, 0, 0><<<dim3(4, 128), 256, 0, stream>>>(
        m1b, Wb2, mid_b2, m2b, nullptr, nullptr, nullptr, HW, 512, 512);
    bgemm_k<64, 64, 0, 1, 0><<<dim3(2, 256), 256, 0, stream>>>(
        m2b, Wb3, mid_b3, Bb, Cb, stats1, stats2, HW, 512, 128);   // q1raw -> Bb, stats2

    // conv2: q = inorm(q1n + conv3x3(q1n)); q1n applied on the fly from stats2
    chw2hwc_pad_k<<<256, 256, 0, stream>>>(Bb, stats2, qT);
    bgemm_k<64, 64, 0, 1, 1><<<dim3(2, 256), 256, 0, stream>>>(
        qT, Wcv2, out_b, Gb, Bb, stats2, stats3, HW, 1152, 128);   // conv2 raw -> Gb, stats3
    inorm_apply_k<<<1024, 256, 0, stream>>>(Gb, stats3, q_out);
}

// Round 5
// 393.370 us; speedup vs baseline: 1.0269x; 1.0269x over previous
//
#include <hip/hip_runtime.h>
#include <hip/hip_bf16.h>
#include <math.h>

#define HW 16384   // 128*128 bev pixels

typedef __attribute__((ext_vector_type(8))) short short8;
typedef __attribute__((ext_vector_type(4))) float floatx4;
typedef __attribute__((ext_vector_type(2))) float floatx2;

__device__ __forceinline__ float gelu_exact(float x){
    return 0.5f * x * (1.0f + erff(x * 0.7071067811865475f));
}

__device__ __forceinline__ floatx2 bf2x(unsigned int u){
    floatx2 r;
    r.x = __uint_as_float(u << 16);
    r.y = __uint_as_float(u & 0xffff0000u);
    return r;
}

// ---------------- all-level feat transpose: (N,C,H,W) fp32 -> (N,H,W,C) bf16 ----------------
// LDS-tiled: coalesced reads along x, coalesced 16B HWC writes.
template<int CW, int HL, int WL>
__device__ __forceinline__ void ft_tile(
    float* tile, const float* __restrict__ in, __hip_bfloat16* __restrict__ out,
    int n, int y, int x0, int base, int t)
{
    // read: 128 channels x CW floats (coalesced along x)
    const float* src = in + ((size_t)n * 128 * HL + y) * WL + x0;
    constexpr int NE = 128 * CW;
    for (int idx = t; idx < NE; idx += 256) {
        int c = idx / CW, x = idx - c * CW;
        tile[c * 45 + x] = src[(size_t)c * (HL * WL) + x];
    }
    __syncthreads();
    // write: CW pixels x 16 uint4 (128 bf16 per pixel, contiguous)
    __hip_bfloat16* dst = out + base + ((size_t)(n * HL + y) * WL + x0) * 128;
    constexpr int NO = CW * 16;
    for (int idx = t; idx < NO; idx += 256) {
        int x = idx >> 4, g = idx & 15;
        union { __hip_bfloat16 h[8]; uint4 u; } pk;
        #pragma unroll
        for (int jj = 0; jj < 8; jj++)
            pk.h[jj] = __float2bfloat16(tile[(g * 8 + jj) * 45 + x]);
        *(uint4*)&dst[(size_t)x * 128 + g * 8] = pk.u;
    }
}

__global__ __launch_bounds__(256) void feat_transpose_all_k(
    const float* __restrict__ f0, const float* __restrict__ f1,
    const float* __restrict__ f2, const float* __restrict__ f3,
    __hip_bfloat16* __restrict__ out)
{
    __shared__ float tile[128 * 45];
    int b = blockIdx.x, t = threadIdx.x;
    if (b < 384) {            // l0: 6 cams * 32 y * 2 xchunks
        int n = b >> 6, q = b & 63, y = q >> 1, x0 = (q & 1) * 44;
        ft_tile<44, 32, 88>(tile, f0, out, n, y, x0, 0, t);
    } else if (b < 480) {     // l1: 6 * 16
        int r = b - 384, n = r >> 4, y = r & 15;
        ft_tile<44, 16, 44>(tile, f1, out, n, y, 0, 2162688, t);
    } else if (b < 528) {     // l2: 6 * 8
        int r = b - 480, n = r >> 3, y = r & 7;
        ft_tile<22, 8, 22>(tile, f2, out, n, y, 0, 2703360, t);
    } else {                  // l3: 6 * 4
        int r = b - 528, n = r >> 2, y = r & 3;
        ft_tile<11, 4, 11>(tile, f3, out, n, y, 0, 2838528, t);
    }
}

// ---------------- unified weight prep (block-range dispatch) ----------------
__global__ __launch_bounds__(256) void prep_k(
    const float* __restrict__ mid_w1, const float* __restrict__ mid_w2,
    const float* __restrict__ mid_w3, const float* __restrict__ pe_w2,
    const float* __restrict__ off_w,  const float* __restrict__ off_b,
    const float* __restrict__ sw_w,   const float* __restrict__ sw_b,
    const float* __restrict__ in_w,   const float* __restrict__ out_w,
    __hip_bfloat16* __restrict__ Wb1, __hip_bfloat16* __restrict__ Wb2,
    __hip_bfloat16* __restrict__ Wb3, __hip_bfloat16* __restrict__ Wpe,
    __hip_bfloat16* __restrict__ Wof, float* __restrict__ Bof,
    __hip_bfloat16* __restrict__ Wcv1, __hip_bfloat16* __restrict__ Wcv2)
{
    int b = blockIdx.x, t = threadIdx.x;
    if (b < 2048) {
        int i = b * 256 + t; Wb1[i] = __float2bfloat16(mid_w1[i]);
    } else if (b < 3072) {
        int i = (b - 2048) * 256 + t; Wb2[i] = __float2bfloat16(mid_w2[i]);
    } else if (b < 3328) {
        int i = (b - 3072) * 256 + t; Wb3[i] = __float2bfloat16(mid_w3[i]);
    } else if (b < 3456) {
        int n = b - 3328; Wpe[n * 256 + t] = __float2bfloat16(pe_w2[t * 128 + n]);
    } else if (b < 3584) {
        int n = b - 3456;
        if (t < 128) {
            float w = 0.f;
            if (n < 24)      w = off_w[n * 128 + t];
            else if (n < 56) w = sw_w[(n - 24) * 128 + t];
            Wof[n * 128 + t] = __float2bfloat16(w);
            if (t == 0) Bof[n] = (n < 24) ? off_b[n] : ((n < 56) ? sw_b[n - 24] : 0.f);
        }
    } else if (b < 3712) {
        int o = b - 3584;
        for (int idx = t; idx < 1152; idx += 256) {
            int s = idx >> 7, i = idx & 127;
            Wcv1[o * 1152 + idx] = __float2bfloat16(in_w[(o * 128 + i) * 9 + s]);
        }
    } else {
        int o = b - 3712;
        for (int idx = t; idx < 1152; idx += 256) {
            int s = idx >> 7, i = idx & 127;
            Wcv2[o * 1152 + idx] = __float2bfloat16(out_w[(o * 128 + i) * 9 + s]);
        }
    }
}

// ---------------- CHW fp32 [128][128^2] -> padded HWC bf16 [130][130][128] (interior) ----------------
// stats (optional): per-channel {sum, sumsq}; applies instance-norm while packing.
__global__ __launch_bounds__(256) void chw2hwc_pad_k(
    const float* __restrict__ q, const float* __restrict__ stats,
    __hip_bfloat16* __restrict__ out)
{
    __shared__ float tile[128][65];
    __shared__ float sm[128], sr[128];
    int t = threadIdx.x;
    if (t < 128) {
        if (stats) {
            float s = stats[2 * t], s2 = stats[2 * t + 1];
            float mean = s * (1.0f / HW);
            sm[t] = mean;
            sr[t] = rsqrtf(s2 * (1.0f / HW) - mean * mean + 1e-5f);
        } else {
            sm[t] = 0.f; sr[t] = 1.f;
        }
    }
    int b = blockIdx.x;            // 256 blocks: y = b>>1, x0 = (b&1)*64
    int y = b >> 1, x0 = (b & 1) * 64;
    int xi = t & 63, c0 = t >> 6;
    for (int c = c0; c < 128; c += 4)
        tile[c][xi] = q[c * HW + y * 128 + x0 + xi];
    __syncthreads();
    int xp = t >> 2, cg = (t & 3) * 32;
    __hip_bfloat16* dst = out + ((size_t)(y + 1) * 130 + (x0 + 1 + xp)) * 128;
    #pragma unroll
    for (int g = 0; g < 4; g++) {
        int c = cg + g * 8;
        union { __hip_bfloat16 h[8]; uint4 u; } pk;
        #pragma unroll
        for (int j = 0; j < 8; j++)
            pk.h[j] = __float2bfloat16((tile[c + j][xp] - sm[c + j]) * sr[c + j]);
        *(uint4*)&dst[c] = pk.u;
    }
}

// ---------------- bf16 MFMA GEMM: out[m][n] = act(bias[n] + sum_k X[m][k] W[n][k]) ----------------
// OUTT: 0 -> bf16 [M][N]; 1 -> fp32 [N][M] (CHW, + optional residual res[n][m]).
// CONV: X is padded HWC bf16 [130][130][128]; k = s*128+c.
// rstats: normalize residual with {sum,sumsq}; ostats: accumulate output {sum,sumsq} (OUTT==1 only).
// K-loop: NBUF-deep LDS pipeline with counted vmcnt (never 0 in steady state) + raw s_barrier.
// LDS XOR-swizzle (both-sides): global source chunk permuted on stage, ds_read slot permuted to match.
template<int BM, int BN, int ACT, int OUTT, int CONV>
__global__ __launch_bounds__(256) void bgemm_k(
    const __hip_bfloat16* __restrict__ X, const __hip_bfloat16* __restrict__ W,
    const float* __restrict__ bias, void* __restrict__ outp,
    const float* __restrict__ res,
    const float* __restrict__ rstats, float* __restrict__ ostats,
    int M, int K, int N)
{
    constexpr int ROWS = BM + BN;
    constexpr int ITERS = (ROWS * 4) / 256;       // global_load_lds per lane per stage
    constexpr int BUFE  = ROWS * 32;              // bf16 elements per buffer
    constexpr int NBUF  = (ITERS == 2) ? 4 : 3;   // 32 KB / 48 KB LDS
    __shared__ __align__(16) __hip_bfloat16 SH[NBUF * BUFE];
    int t = threadIdx.x;
    int w = t >> 6, lane = t & 63;
    int mb = blockIdx.y * BM, nb = blockIdx.x * BN;
    int cy = mb >> 7, cx = mb & 127;   // conv tile coords (CONV only)
    constexpr int WM = BM / 2;
    constexpr int MI = WM / 16;
    constexpr int NJ = BN / 32;
    int wm = (w & 1) * WM, wn = (w >> 1) * (BN / 2);
    int lm = lane & 15, lq = lane >> 4;
    int sl = (lq ^ ((lm >> 1) & 3)) * 8;          // swizzled k-slot for ds_read
    floatx4 zero = {0.f, 0.f, 0.f, 0.f};
    floatx4 acc[MI][NJ];
    #pragma unroll
    for (int i = 0; i < MI; i++)
        #pragma unroll
        for (int j = 0; j < NJ; j++) acc[i][j] = zero;

    const int nsteps = K >> 5;

    auto STAGE = [&](int bufi, int tk2) {
        int kb_ = tk2 * 32;
        int s_ = kb_ >> 7;
        int dyi_ = s_ / 3, dxi_ = s_ - dyi_ * 3;   // tap indices (CONV only)
        #pragma unroll
        for (int it = 0; it < ITERS; it++) {
            int chunk = it * 256 + t;
            int row = chunk >> 2;
            int ko = ((chunk & 3) ^ ((row >> 1) & 3)) * 8;   // source-side swizzle
            const __hip_bfloat16* src;
            if (row < BM) {
                if (CONV)
                    src = X + (((size_t)(cy + dyi_) * 130) + (cx + dxi_ + row)) * 128 + (kb_ & 127) + ko;
                else
                    src = X + (size_t)(mb + row) * K + kb_ + ko;
            } else {
                src = W + (size_t)(nb + row - BM) * K + kb_ + ko;
            }
            __builtin_amdgcn_global_load_lds(
                (const __attribute__((address_space(1))) void*)src,
                (__attribute__((address_space(3))) void*)&SH[bufi * BUFE + (it * 256 + (t & ~63)) * 8],
                16, 0, 0);
        }
    };

    #pragma unroll
    for (int pi = 0; pi < NBUF - 1; pi++)
        if (pi < nsteps) STAGE(pi, pi);

    for (int tk = 0; tk < nsteps; ++tk) {
        int rem = nsteps - 1 - tk;
        if constexpr (ITERS == 2) {                // NBUF=4: up to 2 stages beyond current
            if (rem >= 2)      asm volatile("s_waitcnt vmcnt(4)" ::: "memory");
            else if (rem == 1) asm volatile("s_waitcnt vmcnt(2)" ::: "memory");
            else               asm volatile("s_waitcnt vmcnt(0)" ::: "memory");
        } else {                                   // NBUF=3: up to 1 stage beyond current
            if (rem >= 1)      asm volatile("s_waitcnt vmcnt(4)" ::: "memory");
            else               asm volatile("s_waitcnt vmcnt(0)" ::: "memory");
        }
        __builtin_amdgcn_s_barrier();
        int tkn = tk + NBUF - 1;
        if (tkn < nsteps) STAGE(tkn % NBUF, tkn);

        const __hip_bfloat16* As = SH + (tk % NBUF) * BUFE;
        const __hip_bfloat16* Bs = As + BM * 32;
        short8 af[MI], bf[NJ];
        #pragma unroll
        for (int i = 0; i < MI; i++)
            af[i] = *(const short8*)&As[(wm + i * 16 + lm) * 32 + sl];
        #pragma unroll
        for (int j = 0; j < NJ; j++)
            bf[j] = *(const short8*)&Bs[(wn + j * 16 + lm) * 32 + sl];
        #pragma unroll
        for (int i = 0; i < MI; i++)
            #pragma unroll
            for (int j = 0; j < NJ; j++)
                acc[i][j] = __builtin_amdgcn_mfma_f32_16x16x32_bf16(af[i], bf[j], acc[i][j], 0, 0, 0);
    }

    float invM = 1.0f / (float)M;
    #pragma unroll
    for (int j = 0; j < NJ; j++) {
        int n = nb + wn + j * 16 + lm;
        float bv = bias[n];
        float rmean = 0.f, rrstd = 0.f;
        if (OUTT == 1 && res && rstats) {
            float s = rstats[2 * n], s2 = rstats[2 * n + 1];
            rmean = s * invM;
            rrstd = rsqrtf(s2 * invM - rmean * rmean + 1e-5f);
        }
        float ss = 0.f, ss2 = 0.f;
        #pragma unroll
        for (int i = 0; i < MI; i++) {
            #pragma unroll
            for (int r = 0; r < 4; r++) {
                int m = mb + wm + i * 16 + lq * 4 + r;
                float v = acc[i][j][r] + bv;
                if (ACT) v = gelu_exact(v);
                if (OUTT == 0) {
                    ((__hip_bfloat16*)outp)[(size_t)m * N + n] = __float2bfloat16(v);
                } else {
                    if (res) {
                        float rv = res[(size_t)n * M + m];
                        v += rstats ? (rv - rmean) * rrstd : rv;
                    }
                    ((float*)outp)[(size_t)n * M + m] = v;
                    ss += v; ss2 += v * v;
                }
            }
        }
        if (OUTT == 1 && ostats) {
            ss  += __shfl_xor(ss, 16);  ss  += __shfl_xor(ss, 32);
            ss2 += __shfl_xor(ss2, 16); ss2 += __shfl_xor(ss2, 32);
            if (lq == 0) {
                atomicAdd(&ostats[2 * n], ss);
                atomicAdd(&ostats[2 * n + 1], ss2);
            }
        }
    }
}

// ---------------- fused PE: hidden = relu(rn @ w1 + b1) on the fly, GEMM vs Wpe ----------------
__global__ __launch_bounds__(256) void pe_bgemm_k(
    const float* __restrict__ pts, const float* __restrict__ pe_w1,
    const float* __restrict__ pe_b1, const __hip_bfloat16* __restrict__ W,
    const float* __restrict__ bias, __hip_bfloat16* __restrict__ out)
{
    __shared__ __align__(16) __hip_bfloat16 As[128 * 32];
    __shared__ __align__(16) __hip_bfloat16 Bs[128 * 32];
    __shared__ __align__(16) float wps[4][256];   // [b1, w1_x, w1_y, w1_z][256]
    int t = threadIdx.x;
    int w = t >> 6, lane = t & 63;
    int mb = blockIdx.x * 128;
    {
        int d = t >> 6, c = (t & 63) * 4;
        float4 v;
        if (d == 0) v = *(const float4*)&pe_b1[c];
        else        v = *(const float4*)&pe_w1[(d - 1) * 256 + c];
        *(float4*)&wps[d][c] = v;
    }
    int cg = t & 3;
    int r0 = t >> 2;
    float rn[2][3];
    #pragma unroll
    for (int h = 0; h < 2; h++) {
        int r = mb + r0 + h * 64;
        rn[h][0] = (pts[(size_t)r * 3 + 0] + 50.f) * 0.01f;
        rn[h][1] = (pts[(size_t)r * 3 + 1] + 50.f) * 0.01f;
        rn[h][2] = (pts[(size_t)r * 3 + 2] + 4.f) * 0.125f;
    }
    int wm = (w & 1) * 64, wn = (w >> 1) * 64;
    int lm = lane & 15, lq = lane >> 4;
    floatx4 zero = {0.f, 0.f, 0.f, 0.f};
    floatx4 acc[4][4];
    #pragma unroll
    for (int i = 0; i < 4; i++)
        #pragma unroll
        for (int j = 0; j < 4; j++) acc[i][j] = zero;
    for (int kb = 0; kb < 256; kb += 32) {
        __syncthreads();
        #pragma unroll
        for (int it = 0; it < 2; it++) {
            int chunk = it * 256 + t;
            int brow = chunk >> 2, ko = (chunk & 3) * 8;
            const __hip_bfloat16* src = W + (size_t)brow * 256 + kb + ko;
            __builtin_amdgcn_global_load_lds(
                (const __attribute__((address_space(1))) void*)src,
                (__attribute__((address_space(3))) void*)&Bs[(size_t)(it * 256 + (t & ~63)) * 8],
                16, 0, 0);
        }
        int c0 = kb + cg * 8;
        float4 bva = *(const float4*)&wps[0][c0], bvb = *(const float4*)&wps[0][c0 + 4];
        float4 wxa = *(const float4*)&wps[1][c0], wxb = *(const float4*)&wps[1][c0 + 4];
        float4 wya = *(const float4*)&wps[2][c0], wyb = *(const float4*)&wps[2][c0 + 4];
        float4 wza = *(const float4*)&wps[3][c0], wzb = *(const float4*)&wps[3][c0 + 4];
        #pragma unroll
        for (int h = 0; h < 2; h++) {
            const float* bv = (const float*)&bva;
            const float* wx = (const float*)&wxa;
            const float* wy = (const float*)&wya;
            const float* wz = (const float*)&wza;
            union { __hip_bfloat16 hh[8]; uint4 u; } pk;
            #pragma unroll
            for (int j = 0; j < 4; j++) {
                float v = bv[j] + rn[h][0] * wx[j] + rn[h][1] * wy[j] + rn[h][2] * wz[j];
                pk.hh[j] = __float2bfloat16(fmaxf(v, 0.f));
            }
            bv = (const float*)&bvb; wx = (const float*)&wxb;
            wy = (const float*)&wyb; wz = (const float*)&wzb;
            #pragma unroll
            for (int j = 0; j < 4; j++) {
                float v = bv[j] + rn[h][0] * wx[j] + rn[h][1] * wy[j] + rn[h][2] * wz[j];
                pk.hh[4 + j] = __float2bfloat16(fmaxf(v, 0.f));
            }
            *(uint4*)&As[(r0 + h * 64) * 32 + cg * 8] = pk.u;
        }
        __syncthreads();
        short8 af[4], bf[4];
        #pragma unroll
        for (int i = 0; i < 4; i++)
            af[i] = *(const short8*)&As[(wm + i * 16 + lm) * 32 + lq * 8];
        #pragma unroll
        for (int j = 0; j < 4; j++)
            bf[j] = *(const short8*)&Bs[(wn + j * 16 + lm) * 32 + lq * 8];
        #pragma unroll
        for (int i = 0; i < 4; i++)
            #pragma unroll
            for (int j = 0; j < 4; j++)
                acc[i][j] = __builtin_amdgcn_mfma_f32_16x16x32_bf16(af[i], bf[j], acc[i][j], 0, 0, 0);
    }
    #pragma unroll
    for (int i = 0; i < 4; i++) {
        #pragma unroll
        for (int j = 0; j < 4; j++) {
            int n = wn + j * 16 + lm;
            float bv = bias[n];
            #pragma unroll
            for (int r = 0; r < 4; r++) {
                int m = mb + wm + i * 16 + lq * 4 + r;
                out[(size_t)m * 128 + n] = __float2bfloat16(acc[i][j][r] + bv);
            }
        }
    }
}

// ---------------- final instance norm apply (stats precomputed in producer epilogue) ----------------
__global__ __launch_bounds__(256) void inorm_apply_k(
    const float* __restrict__ in, const float* __restrict__ stats, float* __restrict__ out)
{
    int b = blockIdx.x;           // 1024 blocks: c = b>>3, seg = b&7 (2048 floats each)
    int c = b >> 3, seg = b & 7;
    float s = stats[2 * c], s2 = stats[2 * c + 1];
    float mean = s * (1.0f / HW);
    float rstd = rsqrtf(s2 * (1.0f / HW) - mean * mean + 1e-5f);
    const float4* pi = (const float4*)(in + (size_t)c * HW + seg * 2048);
    float4*       po = (float4*)(out + (size_t)c * HW + seg * 2048);
    int t = threadIdx.x;
    #pragma unroll
    for (int k = 0; k < 2; k++) {
        float4 v = pi[t + k * 256];
        v.x = (v.x - mean) * rstd; v.y = (v.y - mean) * rstd;
        v.z = (v.z - mean) * rstd; v.w = (v.w - mean) * rstd;
        po[t + k * 256] = v;
    }
}

// ---------------- offsw epilogue: raw [n][16384] fp32 -> pts/swn/height ----------------
__global__ __launch_bounds__(256) void offpost_k(
    const float* __restrict__ raw, const float* __restrict__ bev_pos,
    float* __restrict__ pts, float* __restrict__ swn, float* __restrict__ height_out)
{
    int pix = blockIdx.x * 256 + threadIdx.x;
    const float pcmin[3] = {-50.f, -50.f, -4.f};
    const float rng[3]   = {100.f, 100.f, 8.f};
    float bp[3];
    #pragma unroll
    for (int d = 0; d < 3; d++) bp[d] = bev_pos[pix * 3 + d];
    #pragma unroll
    for (int p = 0; p < 8; p++) {
        #pragma unroll
        for (int d = 0; d < 3; d++) {
            float acc = raw[(p * 3 + d) * HW + pix];
            float sv = 1.f / (1.f + expf(-acc));
            float lim = (d == 2) ? (4.0f + 1e-6f) : (0.25f + 1e-6f);
            float offv = sv * 2.f * lim - lim;
            float refv = bp[d] * rng[d] + pcmin[d];
            pts[pix * 24 + p * 3 + d] = refv + offv;
            if (d == 2) height_out[p * HW + pix] = offv;
        }
        float r[4], m = -1e30f;
        #pragma unroll
        for (int l = 0; l < 4; l++) {
            r[l] = raw[(24 + p * 4 + l) * HW + pix];
            m = fmaxf(m, r[l]);
        }
        float sum = 0.f;
        #pragma unroll
        for (int l = 0; l < 4; l++) { r[l] = expf(r[l] - m); sum += r[l]; }
        float inv = 1.f / sum;
        #pragma unroll
        for (int l = 0; l < 4; l++) swn[pix * 32 + p * 4 + l] = r[l] * inv;
    }
}

// ---------------- sampling: phase-1 projection + cull, phase-2 bf16 packed gather ----------------
// 256 threads = 4 waves; wave wv owns p = wv*2 + {0,1} (serial).
// Gather: per-lane floatx2 channels, 4 independent corner loads per tap,
// 4-tap unroll with 4 split accumulators -> 16 loads in flight.
__global__ __launch_bounds__(256) void sample_k(
    const __hip_bfloat16* __restrict__ featT, const float* __restrict__ pts,
    const float* __restrict__ swn,   const float* __restrict__ l2i,
    __hip_bfloat16* __restrict__ sf)
{
    int pix = blockIdx.x;
    int t = threadIdx.x;
    int lane = t & 63, wv = t >> 6;
    __shared__ float pts_s[24];
    __shared__ float swl_s[32];
    __shared__ float M[96];
    __shared__ __align__(16) int   offs[8][24][4];   // byte offsets into featT
    __shared__ __align__(16) float wts[8][24][4];
    __shared__ int cnt[8];
    if (t < 96) M[t] = l2i[t];
    if (t < 24) pts_s[t] = pts[pix * 24 + t];
    if (t < 32) swl_s[t] = swn[pix * 32 + t];
    if (t < 8)  cnt[t] = 0;
    __syncthreads();

    floatx2 acc[2];
    #pragma unroll
    for (int i = 0; i < 2; i++) {
        unsigned int u = *(const unsigned int*)&sf[(size_t)pix * 1024 + (wv * 2 + i) * 128 + 2 * lane];
        acc[i] = bf2x(u);
    }

    const int lHt[4] = {32, 16, 8, 4}, lWt[4] = {88, 44, 22, 11};
    const int loff[4] = {0, 2162688, 2703360, 2838528};
    if (t < 192) {
        int p = t / 24;
        int rr = t - p * 24;
        int n = rr >> 2, l = rr & 3;
        float X = pts_s[p * 3], Y = pts_s[p * 3 + 1], Z = pts_s[p * 3 + 2];
        const float* Mn = &M[n * 16];
        float zc = Mn[8] * X + Mn[9] * Y + Mn[10] * Z + Mn[11];
        if (zc > 1e-5f) {
            float inv = 1.f / zc;
            float xn = (Mn[0] * X + Mn[1] * Y + Mn[2] * Z + Mn[3]) * inv * (1.f / 704.f);
            float yn = (Mn[4] * X + Mn[5] * Y + Mn[6] * Z + Mn[7]) * inv * (1.f / 256.f);
            int Wl = lWt[l], Hl = lHt[l];
            float px = xn * Wl - 0.5f, py = yn * Hl - 0.5f;
            px = fminf(fmaxf(px, -2.f), (float)(Wl + 1));
            py = fminf(fmaxf(py, -2.f), (float)(Hl + 1));
            float x0f = floorf(px), y0f = floorf(py);
            float wx = px - x0f, wy = py - y0f;
            int x0 = (int)x0f, y0 = (int)y0f;
            bool xi0 = (unsigned)x0 < (unsigned)Wl, xi1 = (unsigned)(x0 + 1) < (unsigned)Wl;
            bool yi0 = (unsigned)y0 < (unsigned)Hl, yi1 = (unsigned)(y0 + 1) < (unsigned)Hl;
            if ((xi0 || xi1) && (yi0 || yi1)) {
                float wl = swl_s[p * 4 + l];
                float w00 = wl * (1.f - wx) * (1.f - wy) * (float)(xi0 && yi0);
                float w10 = wl * wx * (1.f - wy)         * (float)(xi1 && yi0);
                float w01 = wl * (1.f - wx) * wy         * (float)(xi0 && yi1);
                float w11 = wl * wx * wy                 * (float)(xi1 && yi1);
                int x0c = min(max(x0, 0), Wl - 1), x1c = min(max(x0 + 1, 0), Wl - 1);
                int y0c = min(max(y0, 0), Hl - 1), y1c = min(max(y0 + 1, 0), Hl - 1);
                int base = loff[l] + n * Hl * Wl * 128;
                int idx = atomicAdd(&cnt[p], 1);
                offs[p][idx][0] = (base + (y0c * Wl + x0c) * 128) * 2;
                offs[p][idx][1] = (base + (y0c * Wl + x1c) * 128) * 2;
                offs[p][idx][2] = (base + (y1c * Wl + x0c) * 128) * 2;
                offs[p][idx][3] = (base + (y1c * Wl + x1c) * 128) * 2;
                wts[p][idx][0] = w00; wts[p][idx][1] = w10;
                wts[p][idx][2] = w01; wts[p][idx][3] = w11;
            }
        }
    }
    __syncthreads();

    const char* fbase = (const char*)featT;
    int lane4 = lane * 4;
    #pragma unroll
    for (int i = 0; i < 2; i++) {
        int p = wv * 2 + i;
        int np = cnt[p];
        floatx2 a0 = acc[i];
        floatx2 a1 = {0.f, 0.f};
        floatx2 a2 = {0.f, 0.f};
        floatx2 a3 = {0.f, 0.f};
        int j = 0;
        #pragma unroll 1
        for (; j + 4 <= np; j += 4) {
            int4   oA = *(const int4*)&offs[p][j][0];
            float4 wA = *(const float4*)&wts[p][j][0];
            int4   oB = *(const int4*)&offs[p][j + 1][0];
            float4 wB = *(const float4*)&wts[p][j + 1][0];
            int4   oC = *(const int4*)&offs[p][j + 2][0];
            float4 wC = *(const float4*)&wts[p][j + 2][0];
            int4   oD = *(const int4*)&offs[p][j + 3][0];
            float4 wD = *(const float4*)&wts[p][j + 3][0];
            unsigned int v0 = *(const unsigned int*)(fbase + (unsigned)(oA.x + lane4));
            unsigned int v1 = *(const unsigned int*)(fbase + (unsigned)(oA.y + lane4));
            unsigned int v2 = *(const unsigned int*)(fbase + (unsigned)(oA.z + lane4));
            unsigned int v3 = *(const unsigned int*)(fbase + (unsigned)(oA.w + lane4));
            unsigned int v4 = *(const unsigned int*)(fbase + (unsigned)(oB.x + lane4));
            unsigned int v5 = *(const unsigned int*)(fbase + (unsigned)(oB.y + lane4));
            unsigned int v6 = *(const unsigned int*)(fbase + (unsigned)(oB.z + lane4));
            unsigned int v7 = *(const unsigned int*)(fbase + (unsigned)(oB.w + lane4));
            unsigned int v8 = *(const unsigned int*)(fbase + (unsigned)(oC.x + lane4));
            unsigned int v9 = *(const unsigned int*)(fbase + (unsigned)(oC.y + lane4));
            unsigned int vA_ = *(const unsigned int*)(fbase + (unsigned)(oC.z + lane4));
            unsigned int vB_ = *(const unsigned int*)(fbase + (unsigned)(oC.w + lane4));
            unsigned int vC_ = *(const unsigned int*)(fbase + (unsigned)(oD.x + lane4));
            unsigned int vD_ = *(const unsigned int*)(fbase + (unsigned)(oD.y + lane4));
            unsigned int vE_ = *(const unsigned int*)(fbase + (unsigned)(oD.z + lane4));
            unsigned int vF_ = *(const unsigned int*)(fbase + (unsigned)(oD.w + lane4));
            a0 += bf2x(v0) * wA.x;
            a0 += bf2x(v1) * wA.y;
            a0 += bf2x(v2) * wA.z;
            a0 += bf2x(v3) * wA.w;
            a1 += bf2x(v4) * wB.x;
            a1 += bf2x(v5) * wB.y;
            a1 += bf2x(v6) * wB.z;
            a1 += bf2x(v7) * wB.w;
            a2 += bf2x(v8) * wC.x;
            a2 += bf2x(v9) * wC.y;
            a2 += bf2x(vA_) * wC.z;
            a2 += bf2x(vB_) * wC.w;
            a3 += bf2x(vC_) * wD.x;
            a3 += bf2x(vD_) * wD.y;
            a3 += bf2x(vE_) * wD.z;
            a3 += bf2x(vF_) * wD.w;
        }
        if (j + 2 <= np) {
            int4   oA = *(const int4*)&offs[p][j][0];
            float4 wA = *(const float4*)&wts[p][j][0];
            int4   oB = *(const int4*)&offs[p][j + 1][0];
            float4 wB = *(const float4*)&wts[p][j + 1][0];
            unsigned int v0 = *(const unsigned int*)(fbase + (unsigned)(oA.x + lane4));
            unsigned int v1 = *(const unsigned int*)(fbase + (unsigned)(oA.y + lane4));
            unsigned int v2 = *(const unsigned int*)(fbase + (unsigned)(oA.z + lane4));
            unsigned int v3 = *(const unsigned int*)(fbase + (unsigned)(oA.w + lane4));
            unsigned int v4 = *(const unsigned int*)(fbase + (unsigned)(oB.x + lane4));
            unsigned int v5 = *(const unsigned int*)(fbase + (unsigned)(oB.y + lane4));
            unsigned int v6 = *(const unsigned int*)(fbase + (unsigned)(oB.z + lane4));
            unsigned int v7 = *(const unsigned int*)(fbase + (unsigned)(oB.w + lane4));
            a0 += bf2x(v0) * wA.x;
            a0 += bf2x(v1) * wA.y;
            a0 += bf2x(v2) * wA.z;
            a0 += bf2x(v3) * wA.w;
            a1 += bf2x(v4) * wB.x;
            a1 += bf2x(v5) * wB.y;
            a1 += bf2x(v6) * wB.z;
            a1 += bf2x(v7) * wB.w;
            j += 2;
        }
        if (j < np) {
            int4   o = *(const int4*)&offs[p][j][0];
            float4 w = *(const float4*)&wts[p][j][0];
            unsigned int v0 = *(const unsigned int*)(fbase + (unsigned)(o.x + lane4));
            unsigned int v1 = *(const unsigned int*)(fbase + (unsigned)(o.y + lane4));
            unsigned int v2 = *(const unsigned int*)(fbase + (unsigned)(o.z + lane4));
            unsigned int v3 = *(const unsigned int*)(fbase + (unsigned)(o.w + lane4));
            a0 += bf2x(v0) * w.x;
            a0 += bf2x(v1) * w.y;
            a0 += bf2x(v2) * w.z;
            a0 += bf2x(v3) * w.w;
        }
        acc[i] = (a0 + a1) + (a2 + a3);
    }
    #pragma unroll
    for (int i = 0; i < 2; i++) {
        union { __hip_bfloat16 h[2]; unsigned int u; } pk;
        pk.h[0] = __float2bfloat16(acc[i].x);
        pk.h[1] = __float2bfloat16(acc[i].y);
        *(unsigned int*)&sf[(size_t)pix * 1024 + (wv * 2 + i) * 128 + 2 * lane] = pk.u;
    }
}

extern "C" void kernel_launch(void* const* d_in, const int* in_sizes, int n_in,
                              void* d_out, int out_size, void* d_ws, size_t ws_size,
                              hipStream_t stream)
{
    const float* feat[4] = {(const float*)d_in[0], (const float*)d_in[1],
                            (const float*)d_in[2], (const float*)d_in[3]};
    const float* l2i       = (const float*)d_in[4];
    const float* bev_query = (const float*)d_in[5];
    const float* bev_pos   = (const float*)d_in[6];
    const float* in_w  = (const float*)d_in[7];  const float* in_b  = (const float*)d_in[8];
    const float* off_w = (const float*)d_in[9];  const float* off_b = (const float*)d_in[10];
    const float* sw_w  = (const float*)d_in[11]; const float* sw_b  = (const float*)d_in[12];
    const float* pe_w1 = (const float*)d_in[13]; const float* pe_b1 = (const float*)d_in[14];
    const float* pe_w2 = (const float*)d_in[15]; const float* pe_b2 = (const float*)d_in[16];
    const float* mid_w1 = (const float*)d_in[17]; const float* mid_b1 = (const float*)d_in[18];
    const float* mid_w2 = (const float*)d_in[19]; const float* mid_b2 = (const float*)d_in[20];
    const float* mid_w3 = (const float*)d_in[21]; const float* mid_b3 = (const float*)d_in[22];
    const float* out_w  = (const float*)d_in[23]; const float* out_b  = (const float*)d_in[24];

    float* ws = (float*)d_ws;
    float* fTf = ws;                    // 1,436,160 : transposed feats bf16
    __hip_bfloat16* fT = (__hip_bfloat16*)fTf;
    float* Bb  = fTf + 1436160;         // 2,097,152 : offsw raw / q1 raw (CHW)
    float* Cb  = Bb + 2097152;          // 2,097,152 : q0 raw (conv1 out, CHW)
    float* Gb  = Cb + 2097152;          // 2,097,152 : conv2 raw (CHW)
    float* Dp  = Gb + 2097152;          //   393,216 : pts
    float* Eb  = Dp + 393216;           //   524,288 : swn
    float* QTf = Eb + 524288;           // 1,081,600 : padded HWC bf16 (130*130*128)
    __hip_bfloat16* qT = (__hip_bfloat16*)QTf;
    float* SFf = QTf + 1081600;         // 8,388,608 : sf bf16 131072x128
    __hip_bfloat16* sfb = (__hip_bfloat16*)SFf;
    float* M1f = SFf + 8388608;         // 4,194,304 : m1 bf16
    __hip_bfloat16* m1b = (__hip_bfloat16*)M1f;
    float* M2f = M1f + 4194304;         // 4,194,304 : m2 bf16
    __hip_bfloat16* m2b = (__hip_bfloat16*)M2f;
    float* WC1 = M2f + 4194304;         //    73,728 : conv1 weights bf16
    __hip_bfloat16* Wcv1 = (__hip_bfloat16*)WC1;
    float* WC2 = WC1 + 73728;           //    73,728 : conv2 weights bf16
    __hip_bfloat16* Wcv2 = (__hip_bfloat16*)WC2;
    float* W1f = WC2 + 73728;           //   262,144
    __hip_bfloat16* Wb1 = (__hip_bfloat16*)W1f;
    float* W2f = W1f + 262144;          //   131,072
    __hip_bfloat16* Wb2 = (__hip_bfloat16*)W2f;
    float* W3f = W2f + 131072;          //    32,768
    __hip_bfloat16* Wb3 = (__hip_bfloat16*)W3f;
    float* WPf = W3f + 32768;           //    16,384 : pe_w2^T bf16
    __hip_bfloat16* Wpe = (__hip_bfloat16*)WPf;
    float* WOf = WPf + 16384;           //     8,192 : offsw packed weight bf16
    __hip_bfloat16* Wof = (__hip_bfloat16*)WOf;
    float* Bof = WOf + 8192;            //       128 : offsw packed bias fp32
    float* Stats = Bof + 128;           //       768 : 3 x 128 x {sum,sumsq}
    float* stats1 = Stats;
    float* stats2 = Stats + 256;
    float* stats3 = Stats + 512;

    float* q_out = (float*)d_out;
    float* h_out = q_out + 2097152;

    hipMemsetAsync(qT, 0, (size_t)130 * 130 * 128 * sizeof(__hip_bfloat16), stream);
    hipMemsetAsync(Stats, 0, 768 * sizeof(float), stream);

    feat_transpose_all_k<<<552, 256, 0, stream>>>(feat[0], feat[1], feat[2], feat[3], fT);
    prep_k<<<3840, 256, 0, stream>>>(mid_w1, mid_w2, mid_w3, pe_w2, off_w, off_b, sw_w, sw_b,
                                     in_w, out_w, Wb1, Wb2, Wb3, Wpe, Wof, Bof, Wcv1, Wcv2);

    // conv1: q0raw = bev_query + conv3x3(bev_query) -> Cb, stats1 accumulated in epilogue
    chw2hwc_pad_k<<<256, 256, 0, stream>>>(bev_query, nullptr, qT);
    bgemm_k<64, 64, 0, 1, 1><<<dim3(2, 256), 256, 0, stream>>>(
        qT, Wcv1, in_b, Cb, bev_query, nullptr, stats1, HW, 1152, 128);

    // offsets/sample-weights GEMM over center tap of normalized q0 + epilogue
    chw2hwc_pad_k<<<256, 256, 0, stream>>>(Cb, stats1, qT);   // applies inorm(q0raw)
    bgemm_k<64, 64, 0, 1, 1><<<dim3(2, 256), 256, 0, stream>>>(
        qT + 131 * 128, Wof, Bof, Bb, nullptr, nullptr, nullptr, HW, 128, 128);
    offpost_k<<<64, 256, 0, stream>>>(Bb, bev_pos, Dp, Eb, h_out);

    // fused PE (hidden on the fly + MFMA GEMM) -> sf
    pe_bgemm_k<<<1024, 256, 0, stream>>>(Dp, pe_w1, pe_b1, Wpe, pe_b2, sfb);

    // sampling accumulates taps onto sf
    sample_k<<<HW, 256, 0, stream>>>(fT, Dp, Eb, l2i, sfb);

    // mid MLP: 1024 -> 512 gelu -> 512 gelu -> 128 linear (+ normalized q0 residual)
    bgemm_k<128, 128, 1, 0, 0><<<dim3(4, 128), 256, 0, stream>>>(
        sfb, Wb1, mid_b1, m1b, nullptr, nullptr, nullptr, HW, 1024, 512);
    bgemm_k<128, 128, 1, 0, 0><<<dim3(4, 128), 256, 0, stream>>>(
        m1b, Wb2, mid_b2, m2b, nullptr, nullptr, nullptr, HW, 512, 512);
    bgemm_k<64, 64, 0, 1, 0><<<dim3(2, 256), 256, 0, stream>>>(
        m2b, Wb3, mid_b3, Bb, Cb, stats1, stats2, HW, 512, 128);   // q1raw -> Bb, stats2

    // conv2: q = inorm(q1n + conv3x3(q1n)); q1n applied on the fly from stats2
    chw2hwc_pad_k<<<256, 256, 0, stream>>>(Bb, stats2, qT);
    bgemm_k<64, 64, 0, 1, 1><<<dim3(2, 256), 256, 0, stream>>>(
        qT, Wcv2, out_b, Gb, Bb, stats2, stats3, HW, 1152, 128);   // conv2 raw -> Gb, stats3
    inorm_apply_k<<<1024, 256, 0, stream>>>(Gb, stats3, q_out);
}

// Round 6
// 378.365 us; speedup vs baseline: 1.0676x; 1.0397x over previous
//
#include <hip/hip_runtime.h>
#include <hip/hip_bf16.h>
#include <math.h>

#define HW 16384   // 128*128 bev pixels

typedef __attribute__((ext_vector_type(8))) short short8;
typedef __attribute__((ext_vector_type(4))) float floatx4;
typedef __attribute__((ext_vector_type(2))) float floatx2;

__device__ __forceinline__ float gelu_exact(float x){
    return 0.5f * x * (1.0f + erff(x * 0.7071067811865475f));
}

__device__ __forceinline__ floatx2 bf2x(unsigned int u){
    floatx2 r;
    r.x = __uint_as_float(u << 16);
    r.y = __uint_as_float(u & 0xffff0000u);
    return r;
}

// ---------------- feat transpose tile: (N,C,H,W) fp32 -> (N,H,W,C) bf16 ----------------
// LDS-tiled: coalesced reads along x, coalesced 16B HWC writes.
template<int CW, int HL, int WL>
__device__ __forceinline__ void ft_tile(
    float* tile, const float* __restrict__ in, __hip_bfloat16* __restrict__ out,
    int n, int y, int x0, int base, int t)
{
    const float* src = in + ((size_t)n * 128 * HL + y) * WL + x0;
    constexpr int NE = 128 * CW;
    for (int idx = t; idx < NE; idx += 256) {
        int c = idx / CW, x = idx - c * CW;
        tile[c * 45 + x] = src[(size_t)c * (HL * WL) + x];
    }
    __syncthreads();
    __hip_bfloat16* dst = out + base + ((size_t)(n * HL + y) * WL + x0) * 128;
    constexpr int NO = CW * 16;
    for (int idx = t; idx < NO; idx += 256) {
        int x = idx >> 4, g = idx & 15;
        union { __hip_bfloat16 h[8]; uint4 u; } pk;
        #pragma unroll
        for (int jj = 0; jj < 8; jj++)
            pk.h[jj] = __float2bfloat16(tile[(g * 8 + jj) * 45 + x]);
        *(uint4*)&dst[(size_t)x * 128 + g * 8] = pk.u;
    }
}

// ---------------- unified setup: feat transpose + weight prep + qT border zero + stats zero ----
__global__ __launch_bounds__(256) void setup_k(
    const float* __restrict__ f0, const float* __restrict__ f1,
    const float* __restrict__ f2, const float* __restrict__ f3,
    __hip_bfloat16* __restrict__ fT,
    const float* __restrict__ mid_w1, const float* __restrict__ mid_w2,
    const float* __restrict__ mid_w3, const float* __restrict__ pe_w2,
    const float* __restrict__ off_w,  const float* __restrict__ off_b,
    const float* __restrict__ sw_w,   const float* __restrict__ sw_b,
    const float* __restrict__ in_w,   const float* __restrict__ out_w,
    __hip_bfloat16* __restrict__ Wb1, __hip_bfloat16* __restrict__ Wb2,
    __hip_bfloat16* __restrict__ Wb3, __hip_bfloat16* __restrict__ Wpe,
    __hip_bfloat16* __restrict__ Wof, float* __restrict__ Bof,
    __hip_bfloat16* __restrict__ Wcv1, __hip_bfloat16* __restrict__ Wcv2,
    __hip_bfloat16* __restrict__ qTo, float* __restrict__ Stats)
{
    __shared__ float tile[128 * 45];
    int b = blockIdx.x, t = threadIdx.x;
    if (b < 384) {            // feat l0: 6 cams * 32 y * 2 xchunks
        int n = b >> 6, q = b & 63, y = q >> 1, x0 = (q & 1) * 44;
        ft_tile<44, 32, 88>(tile, f0, fT, n, y, x0, 0, t);
    } else if (b < 480) {     // feat l1: 6 * 16
        int r = b - 384, n = r >> 4, y = r & 15;
        ft_tile<44, 16, 44>(tile, f1, fT, n, y, 0, 2162688, t);
    } else if (b < 528) {     // feat l2: 6 * 8
        int r = b - 480, n = r >> 3, y = r & 7;
        ft_tile<22, 8, 22>(tile, f2, fT, n, y, 0, 2703360, t);
    } else if (b < 552) {     // feat l3: 6 * 4
        int r = b - 528, n = r >> 2, y = r & 3;
        ft_tile<11, 4, 11>(tile, f3, fT, n, y, 0, 2838528, t);
    } else if (b < 2600) {
        int i = (b - 552) * 256 + t; Wb1[i] = __float2bfloat16(mid_w1[i]);
    } else if (b < 3624) {
        int i = (b - 2600) * 256 + t; Wb2[i] = __float2bfloat16(mid_w2[i]);
    } else if (b < 3880) {
        int i = (b - 3624) * 256 + t; Wb3[i] = __float2bfloat16(mid_w3[i]);
    } else if (b < 4008) {
        int n = b - 3880; Wpe[n * 256 + t] = __float2bfloat16(pe_w2[t * 128 + n]);
    } else if (b < 4136) {
        int n = b - 4008;
        if (t < 128) {
            float w = 0.f;
            if (n < 24)      w = off_w[n * 128 + t];
            else if (n < 56) w = sw_w[(n - 24) * 128 + t];
            Wof[n * 128 + t] = __float2bfloat16(w);
            if (t == 0) Bof[n] = (n < 24) ? off_b[n] : ((n < 56) ? sw_b[n - 24] : 0.f);
        }
    } else if (b < 4264) {
        int o = b - 4136;
        for (int idx = t; idx < 1152; idx += 256) {
            int s = idx >> 7, i = idx & 127;
            Wcv1[o * 1152 + idx] = __float2bfloat16(in_w[(o * 128 + i) * 9 + s]);
        }
    } else if (b < 4392) {
        int o = b - 4264;
        for (int idx = t; idx < 1152; idx += 256) {
            int s = idx >> 7, i = idx & 127;
            Wcv2[o * 1152 + idx] = __float2bfloat16(out_w[(o * 128 + i) * 9 + s]);
        }
    } else if (b < 4425) {    // qT border zero: 516 border pixels x 16 uint4
        int g = (b - 4392) * 256 + t;
        if (g < 8256) {
            int pixi = g >> 4, part = g & 15;
            int row, col;
            if (pixi < 130)      { row = 0;   col = pixi; }
            else if (pixi < 260) { row = 129; col = pixi - 130; }
            else {
                int r = pixi - 260;
                row = 1 + (r & 127);
                col = (r < 128) ? 0 : 129;
            }
            uint4 z = {0u, 0u, 0u, 0u};
            *(uint4*)&qTo[((size_t)row * 130 + col) * 128 + part * 8] = z;
        }
    } else {                  // stats zero: 768 floats
        Stats[t] = 0.f; Stats[256 + t] = 0.f; Stats[512 + t] = 0.f;
    }
}

// ---------------- CHW fp32 [128][128^2] -> padded HWC bf16 [130][130][128] (interior) ----------------
// stats (optional): per-channel {sum, sumsq}; applies instance-norm while packing.
__global__ __launch_bounds__(256) void chw2hwc_pad_k(
    const float* __restrict__ q, const float* __restrict__ stats,
    __hip_bfloat16* __restrict__ out)
{
    __shared__ float tile[128][65];
    __shared__ float sm[128], sr[128];
    int t = threadIdx.x;
    if (t < 128) {
        if (stats) {
            float s = stats[2 * t], s2 = stats[2 * t + 1];
            float mean = s * (1.0f / HW);
            sm[t] = mean;
            sr[t] = rsqrtf(s2 * (1.0f / HW) - mean * mean + 1e-5f);
        } else {
            sm[t] = 0.f; sr[t] = 1.f;
        }
    }
    int b = blockIdx.x;            // 256 blocks: y = b>>1, x0 = (b&1)*64
    int y = b >> 1, x0 = (b & 1) * 64;
    int xi = t & 63, c0 = t >> 6;
    for (int c = c0; c < 128; c += 4)
        tile[c][xi] = q[c * HW + y * 128 + x0 + xi];
    __syncthreads();
    int xp = t >> 2, cg = (t & 3) * 32;
    __hip_bfloat16* dst = out + ((size_t)(y + 1) * 130 + (x0 + 1 + xp)) * 128;
    #pragma unroll
    for (int g = 0; g < 4; g++) {
        int c = cg + g * 8;
        union { __hip_bfloat16 h[8]; uint4 u; } pk;
        #pragma unroll
        for (int j = 0; j < 8; j++)
            pk.h[j] = __float2bfloat16((tile[c + j][xp] - sm[c + j]) * sr[c + j]);
        *(uint4*)&dst[c] = pk.u;
    }
}

// ---------------- bf16 MFMA GEMM: out[m][n] = act(bias[n] + sum_k X[m][k] W[n][k]) ----------------
// OUTT: 0 -> bf16 [M][N]; 1 -> fp32 [N][M] (CHW, + optional residual res[n][m]).
// CONV: X is padded HWC bf16 [130][130][128]; k = s*128+c.
// rstats: normalize residual with {sum,sumsq}; ostats: accumulate output {sum,sumsq} (OUTT==1 only).
// K-loop: NBUF-deep LDS pipeline with counted vmcnt (never 0 in steady state) + raw s_barrier.
// LDS XOR-swizzle (both-sides): global source chunk permuted on stage, ds_read slot permuted to match.
template<int BM, int BN, int ACT, int OUTT, int CONV>
__global__ __launch_bounds__(256) void bgemm_k(
    const __hip_bfloat16* __restrict__ X, const __hip_bfloat16* __restrict__ W,
    const float* __restrict__ bias, void* __restrict__ outp,
    const float* __restrict__ res,
    const float* __restrict__ rstats, float* __restrict__ ostats,
    int M, int K, int N)
{
    constexpr int ROWS = BM + BN;
    constexpr int ITERS = (ROWS * 4) / 256;       // global_load_lds per lane per stage
    constexpr int BUFE  = ROWS * 32;              // bf16 elements per buffer
    constexpr int NBUF  = (ITERS == 2) ? 4 : 3;   // 32 KB / 48 KB LDS
    __shared__ __align__(16) __hip_bfloat16 SH[NBUF * BUFE];
    int t = threadIdx.x;
    int w = t >> 6, lane = t & 63;
    int mb = blockIdx.y * BM, nb = blockIdx.x * BN;
    int cy = mb >> 7, cx = mb & 127;   // conv tile coords (CONV only)
    constexpr int WM = BM / 2;
    constexpr int MI = WM / 16;
    constexpr int NJ = BN / 32;
    int wm = (w & 1) * WM, wn = (w >> 1) * (BN / 2);
    int lm = lane & 15, lq = lane >> 4;
    int sl = (lq ^ ((lm >> 1) & 3)) * 8;          // swizzled k-slot for ds_read
    floatx4 zero = {0.f, 0.f, 0.f, 0.f};
    floatx4 acc[MI][NJ];
    #pragma unroll
    for (int i = 0; i < MI; i++)
        #pragma unroll
        for (int j = 0; j < NJ; j++) acc[i][j] = zero;

    const int nsteps = K >> 5;

    auto STAGE = [&](int bufi, int tk2) {
        int kb_ = tk2 * 32;
        int s_ = kb_ >> 7;
        int dyi_ = s_ / 3, dxi_ = s_ - dyi_ * 3;   // tap indices (CONV only)
        #pragma unroll
        for (int it = 0; it < ITERS; it++) {
            int chunk = it * 256 + t;
            int row = chunk >> 2;
            int ko = ((chunk & 3) ^ ((row >> 1) & 3)) * 8;   // source-side swizzle
            const __hip_bfloat16* src;
            if (row < BM) {
                if (CONV)
                    src = X + (((size_t)(cy + dyi_) * 130) + (cx + dxi_ + row)) * 128 + (kb_ & 127) + ko;
                else
                    src = X + (size_t)(mb + row) * K + kb_ + ko;
            } else {
                src = W + (size_t)(nb + row - BM) * K + kb_ + ko;
            }
            __builtin_amdgcn_global_load_lds(
                (const __attribute__((address_space(1))) void*)src,
                (__attribute__((address_space(3))) void*)&SH[bufi * BUFE + (it * 256 + (t & ~63)) * 8],
                16, 0, 0);
        }
    };

    #pragma unroll
    for (int pi = 0; pi < NBUF - 1; pi++)
        if (pi < nsteps) STAGE(pi, pi);

    for (int tk = 0; tk < nsteps; ++tk) {
        int rem = nsteps - 1 - tk;
        if constexpr (ITERS == 2) {                // NBUF=4: up to 2 stages beyond current
            if (rem >= 2)      asm volatile("s_waitcnt vmcnt(4)" ::: "memory");
            else if (rem == 1) asm volatile("s_waitcnt vmcnt(2)" ::: "memory");
            else               asm volatile("s_waitcnt vmcnt(0)" ::: "memory");
        } else {                                   // NBUF=3: up to 1 stage beyond current
            if (rem >= 1)      asm volatile("s_waitcnt vmcnt(4)" ::: "memory");
            else               asm volatile("s_waitcnt vmcnt(0)" ::: "memory");
        }
        __builtin_amdgcn_s_barrier();
        int tkn = tk + NBUF - 1;
        if (tkn < nsteps) STAGE(tkn % NBUF, tkn);

        const __hip_bfloat16* As = SH + (tk % NBUF) * BUFE;
        const __hip_bfloat16* Bs = As + BM * 32;
        short8 af[MI], bf[NJ];
        #pragma unroll
        for (int i = 0; i < MI; i++)
            af[i] = *(const short8*)&As[(wm + i * 16 + lm) * 32 + sl];
        #pragma unroll
        for (int j = 0; j < NJ; j++)
            bf[j] = *(const short8*)&Bs[(wn + j * 16 + lm) * 32 + sl];
        #pragma unroll
        for (int i = 0; i < MI; i++)
            #pragma unroll
            for (int j = 0; j < NJ; j++)
                acc[i][j] = __builtin_amdgcn_mfma_f32_16x16x32_bf16(af[i], bf[j], acc[i][j], 0, 0, 0);
    }

    float invM = 1.0f / (float)M;
    #pragma unroll
    for (int j = 0; j < NJ; j++) {
        int n = nb + wn + j * 16 + lm;
        float bv = bias[n];
        float rmean = 0.f, rrstd = 0.f;
        if (OUTT == 1 && res && rstats) {
            float s = rstats[2 * n], s2 = rstats[2 * n + 1];
            rmean = s * invM;
            rrstd = rsqrtf(s2 * invM - rmean * rmean + 1e-5f);
        }
        float ss = 0.f, ss2 = 0.f;
        #pragma unroll
        for (int i = 0; i < MI; i++) {
            #pragma unroll
            for (int r = 0; r < 4; r++) {
                int m = mb + wm + i * 16 + lq * 4 + r;
                float v = acc[i][j][r] + bv;
                if (ACT) v = gelu_exact(v);
                if (OUTT == 0) {
                    ((__hip_bfloat16*)outp)[(size_t)m * N + n] = __float2bfloat16(v);
                } else {
                    if (res) {
                        float rv = res[(size_t)n * M + m];
                        v += rstats ? (rv - rmean) * rrstd : rv;
                    }
                    ((float*)outp)[(size_t)n * M + m] = v;
                    ss += v; ss2 += v * v;
                }
            }
        }
        if (OUTT == 1 && ostats) {
            ss  += __shfl_xor(ss, 16);  ss  += __shfl_xor(ss, 32);
            ss2 += __shfl_xor(ss2, 16); ss2 += __shfl_xor(ss2, 32);
            if (lq == 0) {
                atomicAdd(&ostats[2 * n], ss);
                atomicAdd(&ostats[2 * n + 1], ss2);
            }
        }
    }
}

// ---------------- fused PE: hidden = relu(rn @ w1 + b1) on the fly, GEMM vs Wpe ----------------
__global__ __launch_bounds__(256) void pe_bgemm_k(
    const float* __restrict__ pts, const float* __restrict__ pe_w1,
    const float* __restrict__ pe_b1, const __hip_bfloat16* __restrict__ W,
    const float* __restrict__ bias, __hip_bfloat16* __restrict__ out)
{
    __shared__ __align__(16) __hip_bfloat16 As[128 * 32];
    __shared__ __align__(16) __hip_bfloat16 Bs[128 * 32];
    __shared__ __align__(16) float wps[4][256];   // [b1, w1_x, w1_y, w1_z][256]
    int t = threadIdx.x;
    int w = t >> 6, lane = t & 63;
    int mb = blockIdx.x * 128;
    {
        int d = t >> 6, c = (t & 63) * 4;
        float4 v;
        if (d == 0) v = *(const float4*)&pe_b1[c];
        else        v = *(const float4*)&pe_w1[(d - 1) * 256 + c];
        *(float4*)&wps[d][c] = v;
    }
    int cg = t & 3;
    int r0 = t >> 2;
    float rn[2][3];
    #pragma unroll
    for (int h = 0; h < 2; h++) {
        int r = mb + r0 + h * 64;
        rn[h][0] = (pts[(size_t)r * 3 + 0] + 50.f) * 0.01f;
        rn[h][1] = (pts[(size_t)r * 3 + 1] + 50.f) * 0.01f;
        rn[h][2] = (pts[(size_t)r * 3 + 2] + 4.f) * 0.125f;
    }
    int wm = (w & 1) * 64, wn = (w >> 1) * 64;
    int lm = lane & 15, lq = lane >> 4;
    floatx4 zero = {0.f, 0.f, 0.f, 0.f};
    floatx4 acc[4][4];
    #pragma unroll
    for (int i = 0; i < 4; i++)
        #pragma unroll
        for (int j = 0; j < 4; j++) acc[i][j] = zero;
    for (int kb = 0; kb < 256; kb += 32) {
        __syncthreads();
        #pragma unroll
        for (int it = 0; it < 2; it++) {
            int chunk = it * 256 + t;
            int brow = chunk >> 2, ko = (chunk & 3) * 8;
            const __hip_bfloat16* src = W + (size_t)brow * 256 + kb + ko;
            __builtin_amdgcn_global_load_lds(
                (const __attribute__((address_space(1))) void*)src,
                (__attribute__((address_space(3))) void*)&Bs[(size_t)(it * 256 + (t & ~63)) * 8],
                16, 0, 0);
        }
        int c0 = kb + cg * 8;
        float4 bva = *(const float4*)&wps[0][c0], bvb = *(const float4*)&wps[0][c0 + 4];
        float4 wxa = *(const float4*)&wps[1][c0], wxb = *(const float4*)&wps[1][c0 + 4];
        float4 wya = *(const float4*)&wps[2][c0], wyb = *(const float4*)&wps[2][c0 + 4];
        float4 wza = *(const float4*)&wps[3][c0], wzb = *(const float4*)&wps[3][c0 + 4];
        #pragma unroll
        for (int h = 0; h < 2; h++) {
            const float* bv = (const float*)&bva;
            const float* wx = (const float*)&wxa;
            const float* wy = (const float*)&wya;
            const float* wz = (const float*)&wza;
            union { __hip_bfloat16 hh[8]; uint4 u; } pk;
            #pragma unroll
            for (int j = 0; j < 4; j++) {
                float v = bv[j] + rn[h][0] * wx[j] + rn[h][1] * wy[j] + rn[h][2] * wz[j];
                pk.hh[j] = __float2bfloat16(fmaxf(v, 0.f));
            }
            bv = (const float*)&bvb; wx = (const float*)&wxb;
            wy = (const float*)&wyb; wz = (const float*)&wzb;
            #pragma unroll
            for (int j = 0; j < 4; j++) {
                float v = bv[j] + rn[h][0] * wx[j] + rn[h][1] * wy[j] + rn[h][2] * wz[j];
                pk.hh[4 + j] = __float2bfloat16(fmaxf(v, 0.f));
            }
            *(uint4*)&As[(r0 + h * 64) * 32 + cg * 8] = pk.u;
        }
        __syncthreads();
        short8 af[4], bf[4];
        #pragma unroll
        for (int i = 0; i < 4; i++)
            af[i] = *(const short8*)&As[(wm + i * 16 + lm) * 32 + lq * 8];
        #pragma unroll
        for (int j = 0; j < 4; j++)
            bf[j] = *(const short8*)&Bs[(wn + j * 16 + lm) * 32 + lq * 8];
        #pragma unroll
        for (int i = 0; i < 4; i++)
            #pragma unroll
            for (int j = 0; j < 4; j++)
                acc[i][j] = __builtin_amdgcn_mfma_f32_16x16x32_bf16(af[i], bf[j], acc[i][j], 0, 0, 0);
    }
    #pragma unroll
    for (int i = 0; i < 4; i++) {
        #pragma unroll
        for (int j = 0; j < 4; j++) {
            int n = wn + j * 16 + lm;
            float bv = bias[n];
            #pragma unroll
            for (int r = 0; r < 4; r++) {
                int m = mb + wm + i * 16 + lq * 4 + r;
                out[(size_t)m * 128 + n] = __float2bfloat16(acc[i][j][r] + bv);
            }
        }
    }
}

// ---------------- final instance norm apply (stats precomputed in producer epilogue) ----------------
__global__ __launch_bounds__(256) void inorm_apply_k(
    const float* __restrict__ in, const float* __restrict__ stats, float* __restrict__ out)
{
    int b = blockIdx.x;           // 1024 blocks: c = b>>3, seg = b&7 (2048 floats each)
    int c = b >> 3, seg = b & 7;
    float s = stats[2 * c], s2 = stats[2 * c + 1];
    float mean = s * (1.0f / HW);
    float rstd = rsqrtf(s2 * (1.0f / HW) - mean * mean + 1e-5f);
    const float4* pi = (const float4*)(in + (size_t)c * HW + seg * 2048);
    float4*       po = (float4*)(out + (size_t)c * HW + seg * 2048);
    int t = threadIdx.x;
    #pragma unroll
    for (int k = 0; k < 2; k++) {
        float4 v = pi[t + k * 256];
        v.x = (v.x - mean) * rstd; v.y = (v.y - mean) * rstd;
        v.z = (v.z - mean) * rstd; v.w = (v.w - mean) * rstd;
        po[t + k * 256] = v;
    }
}

// ---------------- offsw epilogue: raw [n][16384] fp32 -> pts/swn/height ----------------
// 256 blocks: pixel block = b&63, p-group = b>>6 (2 p each).
__global__ __launch_bounds__(256) void offpost_k(
    const float* __restrict__ raw, const float* __restrict__ bev_pos,
    float* __restrict__ pts, float* __restrict__ swn, float* __restrict__ height_out)
{
    int b = blockIdx.x;
    int pix = (b & 63) * 256 + threadIdx.x;
    int p0 = (b >> 6) * 2;
    const float pcmin[3] = {-50.f, -50.f, -4.f};
    const float rng[3]   = {100.f, 100.f, 8.f};
    float bp[3];
    #pragma unroll
    for (int d = 0; d < 3; d++) bp[d] = bev_pos[pix * 3 + d];
    #pragma unroll
    for (int pi = 0; pi < 2; pi++) {
        int p = p0 + pi;
        #pragma unroll
        for (int d = 0; d < 3; d++) {
            float acc = raw[(p * 3 + d) * HW + pix];
            float sv = 1.f / (1.f + expf(-acc));
            float lim = (d == 2) ? (4.0f + 1e-6f) : (0.25f + 1e-6f);
            float offv = sv * 2.f * lim - lim;
            float refv = bp[d] * rng[d] + pcmin[d];
            pts[pix * 24 + p * 3 + d] = refv + offv;
            if (d == 2) height_out[p * HW + pix] = offv;
        }
        float r[4], m = -1e30f;
        #pragma unroll
        for (int l = 0; l < 4; l++) {
            r[l] = raw[(24 + p * 4 + l) * HW + pix];
            m = fmaxf(m, r[l]);
        }
        float sum = 0.f;
        #pragma unroll
        for (int l = 0; l < 4; l++) { r[l] = expf(r[l] - m); sum += r[l]; }
        float inv = 1.f / sum;
        #pragma unroll
        for (int l = 0; l < 4; l++) swn[pix * 32 + p * 4 + l] = r[l] * inv;
    }
}

// ---------------- sampling: phase-1 projection + cull, phase-2 bf16 packed gather ----------------
// 256 threads = 4 waves; wave wv owns p = wv*2 + {0,1}; offsets stored as BYTE offsets;
// main loop processes 2 taps/iter with split accumulators (8 loads in flight).
__global__ __launch_bounds__(256) void sample_k(
    const __hip_bfloat16* __restrict__ featT, const float* __restrict__ pts,
    const float* __restrict__ swn,   const float* __restrict__ l2i,
    __hip_bfloat16* __restrict__ sf)
{
    int pix = blockIdx.x;
    int t = threadIdx.x;
    int lane = t & 63, wv = t >> 6;
    __shared__ float pts_s[24];
    __shared__ float swl_s[32];
    __shared__ float M[96];
    __shared__ __align__(16) int   offs[8][24][4];   // byte offsets into featT
    __shared__ __align__(16) float wts[8][24][4];
    __shared__ int cnt[8];
    if (t < 96) M[t] = l2i[t];
    if (t < 24) pts_s[t] = pts[pix * 24 + t];
    if (t < 32) swl_s[t] = swn[pix * 32 + t];
    if (t < 8)  cnt[t] = 0;
    __syncthreads();

    floatx2 acc[2];
    #pragma unroll
    for (int i = 0; i < 2; i++) {
        unsigned int u = *(const unsigned int*)&sf[(size_t)pix * 1024 + (wv * 2 + i) * 128 + 2 * lane];
        acc[i] = bf2x(u);
    }

    const int lHt[4] = {32, 16, 8, 4}, lWt[4] = {88, 44, 22, 11};
    const int loff[4] = {0, 2162688, 2703360, 2838528};
    if (t < 192) {
        int p = t / 24;
        int rr = t - p * 24;
        int n = rr >> 2, l = rr & 3;
        float X = pts_s[p * 3], Y = pts_s[p * 3 + 1], Z = pts_s[p * 3 + 2];
        const float* Mn = &M[n * 16];
        float zc = Mn[8] * X + Mn[9] * Y + Mn[10] * Z + Mn[11];
        if (zc > 1e-5f) {
            float inv = 1.f / zc;
            float xn = (Mn[0] * X + Mn[1] * Y + Mn[2] * Z + Mn[3]) * inv * (1.f / 704.f);
            float yn = (Mn[4] * X + Mn[5] * Y + Mn[6] * Z + Mn[7]) * inv * (1.f / 256.f);
            int Wl = lWt[l], Hl = lHt[l];
            float px = xn * Wl - 0.5f, py = yn * Hl - 0.5f;
            px = fminf(fmaxf(px, -2.f), (float)(Wl + 1));
            py = fminf(fmaxf(py, -2.f), (float)(Hl + 1));
            float x0f = floorf(px), y0f = floorf(py);
            float wx = px - x0f, wy = py - y0f;
            int x0 = (int)x0f, y0 = (int)y0f;
            bool xi0 = (unsigned)x0 < (unsigned)Wl, xi1 = (unsigned)(x0 + 1) < (unsigned)Wl;
            bool yi0 = (unsigned)y0 < (unsigned)Hl, yi1 = (unsigned)(y0 + 1) < (unsigned)Hl;
            if ((xi0 || xi1) && (yi0 || yi1)) {
                float wl = swl_s[p * 4 + l];
                float w00 = wl * (1.f - wx) * (1.f - wy) * (float)(xi0 && yi0);
                float w10 = wl * wx * (1.f - wy)         * (float)(xi1 && yi0);
                float w01 = wl * (1.f - wx) * wy         * (float)(xi0 && yi1);
                float w11 = wl * wx * wy                 * (float)(xi1 && yi1);
                int x0c = min(max(x0, 0), Wl - 1), x1c = min(max(x0 + 1, 0), Wl - 1);
                int y0c = min(max(y0, 0), Hl - 1), y1c = min(max(y0 + 1, 0), Hl - 1);
                int base = loff[l] + n * Hl * Wl * 128;
                int idx = atomicAdd(&cnt[p], 1);
                offs[p][idx][0] = (base + (y0c * Wl + x0c) * 128) * 2;
                offs[p][idx][1] = (base + (y0c * Wl + x1c) * 128) * 2;
                offs[p][idx][2] = (base + (y1c * Wl + x0c) * 128) * 2;
                offs[p][idx][3] = (base + (y1c * Wl + x1c) * 128) * 2;
                wts[p][idx][0] = w00; wts[p][idx][1] = w10;
                wts[p][idx][2] = w01; wts[p][idx][3] = w11;
            }
        }
    }
    __syncthreads();

    const char* fbase = (const char*)featT;
    int lane4 = lane * 4;
    #pragma unroll
    for (int i = 0; i < 2; i++) {
        int p = wv * 2 + i;
        int np = cnt[p];
        floatx2 a0 = acc[i];
        floatx2 a1 = {0.f, 0.f};
        int j = 0;
        #pragma unroll 1
        for (; j + 2 <= np; j += 2) {
            int4   oA = *(const int4*)&offs[p][j][0];
            float4 wA = *(const float4*)&wts[p][j][0];
            int4   oB = *(const int4*)&offs[p][j + 1][0];
            float4 wB = *(const float4*)&wts[p][j + 1][0];
            unsigned int v0 = *(const unsigned int*)(fbase + (unsigned)(oA.x + lane4));
            unsigned int v1 = *(const unsigned int*)(fbase + (unsigned)(oA.y + lane4));
            unsigned int v2 = *(const unsigned int*)(fbase + (unsigned)(oA.z + lane4));
            unsigned int v3 = *(const unsigned int*)(fbase + (unsigned)(oA.w + lane4));
            unsigned int v4 = *(const unsigned int*)(fbase + (unsigned)(oB.x + lane4));
            unsigned int v5 = *(const unsigned int*)(fbase + (unsigned)(oB.y + lane4));
            unsigned int v6 = *(const unsigned int*)(fbase + (unsigned)(oB.z + lane4));
            unsigned int v7 = *(const unsigned int*)(fbase + (unsigned)(oB.w + lane4));
            a0 += bf2x(v0) * wA.x;
            a0 += bf2x(v1) * wA.y;
            a0 += bf2x(v2) * wA.z;
            a0 += bf2x(v3) * wA.w;
            a1 += bf2x(v4) * wB.x;
            a1 += bf2x(v5) * wB.y;
            a1 += bf2x(v6) * wB.z;
            a1 += bf2x(v7) * wB.w;
        }
        if (j < np) {
            int4   o = *(const int4*)&offs[p][j][0];
            float4 w = *(const float4*)&wts[p][j][0];
            unsigned int v0 = *(const unsigned int*)(fbase + (unsigned)(o.x + lane4));
            unsigned int v1 = *(const unsigned int*)(fbase + (unsigned)(o.y + lane4));
            unsigned int v2 = *(const unsigned int*)(fbase + (unsigned)(o.z + lane4));
            unsigned int v3 = *(const unsigned int*)(fbase + (unsigned)(o.w + lane4));
            a0 += bf2x(v0) * w.x;
            a0 += bf2x(v1) * w.y;
            a0 += bf2x(v2) * w.z;
            a0 += bf2x(v3) * w.w;
        }
        acc[i] = a0 + a1;
    }
    #pragma unroll
    for (int i = 0; i < 2; i++) {
        union { __hip_bfloat16 h[2]; unsigned int u; } pk;
        pk.h[0] = __float2bfloat16(acc[i].x);
        pk.h[1] = __float2bfloat16(acc[i].y);
        *(unsigned int*)&sf[(size_t)pix * 1024 + (wv * 2 + i) * 128 + 2 * lane] = pk.u;
    }
}

extern "C" void kernel_launch(void* const* d_in, const int* in_sizes, int n_in,
                              void* d_out, int out_size, void* d_ws, size_t ws_size,
                              hipStream_t stream)
{
    const float* feat[4] = {(const float*)d_in[0], (const float*)d_in[1],
                            (const float*)d_in[2], (const float*)d_in[3]};
    const float* l2i       = (const float*)d_in[4];
    const float* bev_query = (const float*)d_in[5];
    const float* bev_pos   = (const float*)d_in[6];
    const float* in_w  = (const float*)d_in[7];  const float* in_b  = (const float*)d_in[8];
    const float* off_w = (const float*)d_in[9];  const float* off_b = (const float*)d_in[10];
    const float* sw_w  = (const float*)d_in[11]; const float* sw_b  = (const float*)d_in[12];
    const float* pe_w1 = (const float*)d_in[13]; const float* pe_b1 = (const float*)d_in[14];
    const float* pe_w2 = (const float*)d_in[15]; const float* pe_b2 = (const float*)d_in[16];
    const float* mid_w1 = (const float*)d_in[17]; const float* mid_b1 = (const float*)d_in[18];
    const float* mid_w2 = (const float*)d_in[19]; const float* mid_b2 = (const float*)d_in[20];
    const float* mid_w3 = (const float*)d_in[21]; const float* mid_b3 = (const float*)d_in[22];
    const float* out_w  = (const float*)d_in[23]; const float* out_b  = (const float*)d_in[24];

    float* ws = (float*)d_ws;
    float* fTf = ws;                    // 1,436,160 : transposed feats bf16
    __hip_bfloat16* fT = (__hip_bfloat16*)fTf;
    float* Bb  = fTf + 1436160;         // 2,097,152 : offsw raw / q1 raw (CHW)
    float* Cb  = Bb + 2097152;          // 2,097,152 : q0 raw (conv1 out, CHW)
    float* Gb  = Cb + 2097152;          // 2,097,152 : conv2 raw (CHW)
    float* Dp  = Gb + 2097152;          //   393,216 : pts
    float* Eb  = Dp + 393216;           //   524,288 : swn
    float* QTf = Eb + 524288;           // 1,081,600 : padded HWC bf16 (130*130*128)
    __hip_bfloat16* qT = (__hip_bfloat16*)QTf;
    float* SFf = QTf + 1081600;         // 8,388,608 : sf bf16 131072x128
    __hip_bfloat16* sfb = (__hip_bfloat16*)SFf;
    float* M1f = SFf + 8388608;         // 4,194,304 : m1 bf16
    __hip_bfloat16* m1b = (__hip_bfloat16*)M1f;
    float* M2f = M1f + 4194304;         // 4,194,304 : m2 bf16
    __hip_bfloat16* m2b = (__hip_bfloat16*)M2f;
    float* WC1 = M2f + 4194304;         //    73,728 : conv1 weights bf16
    __hip_bfloat16* Wcv1 = (__hip_bfloat16*)WC1;
    float* WC2 = WC1 + 73728;           //    73,728 : conv2 weights bf16
    __hip_bfloat16* Wcv2 = (__hip_bfloat16*)WC2;
    float* W1f = WC2 + 73728;           //   262,144
    __hip_bfloat16* Wb1 = (__hip_bfloat16*)W1f;
    float* W2f = W1f + 262144;          //   131,072
    __hip_bfloat16* Wb2 = (__hip_bfloat16*)W2f;
    float* W3f = W2f + 131072;          //    32,768
    __hip_bfloat16* Wb3 = (__hip_bfloat16*)W3f;
    float* WPf = W3f + 32768;           //    16,384 : pe_w2^T bf16
    __hip_bfloat16* Wpe = (__hip_bfloat16*)WPf;
    float* WOf = WPf + 16384;           //     8,192 : offsw packed weight bf16
    __hip_bfloat16* Wof = (__hip_bfloat16*)WOf;
    float* Bof = WOf + 8192;            //       128 : offsw packed bias fp32
    float* Stats = Bof + 128;           //       768 : 3 x 128 x {sum,sumsq}
    float* stats1 = Stats;
    float* stats2 = Stats + 256;
    float* stats3 = Stats + 512;

    float* q_out = (float*)d_out;
    float* h_out = q_out + 2097152;

    // setup: feat transpose + weight prep + qT border zero + stats zero (no memsets)
    setup_k<<<4426, 256, 0, stream>>>(feat[0], feat[1], feat[2], feat[3], fT,
                                      mid_w1, mid_w2, mid_w3, pe_w2, off_w, off_b, sw_w, sw_b,
                                      in_w, out_w, Wb1, Wb2, Wb3, Wpe, Wof, Bof, Wcv1, Wcv2,
                                      qT, Stats);

    // conv1: q0raw = bev_query + conv3x3(bev_query) -> Cb, stats1 accumulated in epilogue
    chw2hwc_pad_k<<<256, 256, 0, stream>>>(bev_query, nullptr, qT);
    bgemm_k<64, 64, 0, 1, 1><<<dim3(2, 256), 256, 0, stream>>>(
        qT, Wcv1, in_b, Cb, bev_query, nullptr, stats1, HW, 1152, 128);

    // offsets/sample-weights GEMM over center tap of normalized q0 + epilogue
    chw2hwc_pad_k<<<256, 256, 0, stream>>>(Cb, stats1, qT);   // applies inorm(q0raw)
    bgemm_k<64, 64, 0, 1, 1><<<dim3(2, 256), 256, 0, stream>>>(
        qT + 131 * 128, Wof, Bof, Bb, nullptr, nullptr, nullptr, HW, 128, 128);
    offpost_k<<<256, 256, 0, stream>>>(Bb, bev_pos, Dp, Eb, h_out);

    // fused PE (hidden on the fly + MFMA GEMM) -> sf
    pe_bgemm_k<<<1024, 256, 0, stream>>>(Dp, pe_w1, pe_b1, Wpe, pe_b2, sfb);

    // sampling accumulates taps onto sf
    sample_k<<<HW, 256, 0, stream>>>(fT, Dp, Eb, l2i, sfb);

    // mid MLP: 1024 -> 512 gelu -> 512 gelu -> 128 linear (+ normalized q0 residual)
    bgemm_k<128, 128, 1, 0, 0><<<dim3(4, 128), 256, 0, stream>>>(
        sfb, Wb1, mid_b1, m1b, nullptr, nullptr, nullptr, HW, 1024, 512);
    bgemm_k<128, 128, 1, 0, 0><<<dim3(4, 128), 256, 0, stream>>>(
        m1b, Wb2, mid_b2, m2b, nullptr, nullptr, nullptr, HW, 512, 512);
    bgemm_k<64, 64, 0, 1, 0><<<dim3(2, 256), 256, 0, stream>>>(
        m2b, Wb3, mid_b3, Bb, Cb, stats1, stats2, HW, 512, 128);   // q1raw -> Bb, stats2

    // conv2: q = inorm(q1n + conv3x3(q1n)); q1n applied on the fly from stats2
    chw2hwc_pad_k<<<256, 256, 0, stream>>>(Bb, stats2, qT);
    bgemm_k<64, 64, 0, 1, 1><<<dim3(2, 256), 256, 0, stream>>>(
        qT, Wcv2, out_b, Gb, Bb, stats2, stats3, HW, 1152, 128);   // conv2 raw -> Gb, stats3
    inorm_apply_k<<<1024, 256, 0, stream>>>(Gb, stats3, q_out);
}

// Round 7
// 375.582 us; speedup vs baseline: 1.0755x; 1.0074x over previous
//
#include <hip/hip_runtime.h>
#include <hip/hip_bf16.h>
#include <math.h>

#define HW 16384   // 128*128 bev pixels

typedef __attribute__((ext_vector_type(8))) short short8;
typedef __attribute__((ext_vector_type(4))) float floatx4;
typedef __attribute__((ext_vector_type(2))) float floatx2;

__device__ __forceinline__ float gelu_exact(float x){
    return 0.5f * x * (1.0f + erff(x * 0.7071067811865475f));
}

__device__ __forceinline__ floatx2 bf2x(unsigned int u){
    floatx2 r;
    r.x = __uint_as_float(u << 16);
    r.y = __uint_as_float(u & 0xffff0000u);
    return r;
}

// ---------------- feat transpose tile: (N,C,H,W) fp32 -> (N,H,W,C) bf16 ----------------
// LDS-tiled: coalesced reads along x, coalesced 16B HWC writes.
template<int CW, int HL, int WL>
__device__ __forceinline__ void ft_tile(
    float* tile, const float* __restrict__ in, __hip_bfloat16* __restrict__ out,
    int n, int y, int x0, int base, int t)
{
    const float* src = in + ((size_t)n * 128 * HL + y) * WL + x0;
    constexpr int NE = 128 * CW;
    for (int idx = t; idx < NE; idx += 256) {
        int c = idx / CW, x = idx - c * CW;
        tile[c * 45 + x] = src[(size_t)c * (HL * WL) + x];
    }
    __syncthreads();
    __hip_bfloat16* dst = out + base + ((size_t)(n * HL + y) * WL + x0) * 128;
    constexpr int NO = CW * 16;
    for (int idx = t; idx < NO; idx += 256) {
        int x = idx >> 4, g = idx & 15;
        union { __hip_bfloat16 h[8]; uint4 u; } pk;
        #pragma unroll
        for (int jj = 0; jj < 8; jj++)
            pk.h[jj] = __float2bfloat16(tile[(g * 8 + jj) * 45 + x]);
        *(uint4*)&dst[(size_t)x * 128 + g * 8] = pk.u;
    }
}

// ---------------- unified setup: feat transpose + weight prep + qT border zero + stats zero
// ---------------- + first CHW->padded-HWC pack of bev_query (no stats) ----------------
__global__ __launch_bounds__(256) void setup_k(
    const float* __restrict__ f0, const float* __restrict__ f1,
    const float* __restrict__ f2, const float* __restrict__ f3,
    __hip_bfloat16* __restrict__ fT,
    const float* __restrict__ mid_w1, const float* __restrict__ mid_w2,
    const float* __restrict__ mid_w3, const float* __restrict__ pe_w2,
    const float* __restrict__ off_w,  const float* __restrict__ off_b,
    const float* __restrict__ sw_w,   const float* __restrict__ sw_b,
    const float* __restrict__ in_w,   const float* __restrict__ out_w,
    const float* __restrict__ bev_query,
    __hip_bfloat16* __restrict__ Wb1, __hip_bfloat16* __restrict__ Wb2,
    __hip_bfloat16* __restrict__ Wb3, __hip_bfloat16* __restrict__ Wpe,
    __hip_bfloat16* __restrict__ Wof, float* __restrict__ Bof,
    __hip_bfloat16* __restrict__ Wcv1, __hip_bfloat16* __restrict__ Wcv2,
    __hip_bfloat16* __restrict__ qTo, float* __restrict__ Stats)
{
    __shared__ float tile[128 * 65];
    int b = blockIdx.x, t = threadIdx.x;
    if (b < 384) {            // feat l0: 6 cams * 32 y * 2 xchunks
        int n = b >> 6, q = b & 63, y = q >> 1, x0 = (q & 1) * 44;
        ft_tile<44, 32, 88>(tile, f0, fT, n, y, x0, 0, t);
    } else if (b < 480) {     // feat l1: 6 * 16
        int r = b - 384, n = r >> 4, y = r & 15;
        ft_tile<44, 16, 44>(tile, f1, fT, n, y, 0, 2162688, t);
    } else if (b < 528) {     // feat l2: 6 * 8
        int r = b - 480, n = r >> 3, y = r & 7;
        ft_tile<22, 8, 22>(tile, f2, fT, n, y, 0, 2703360, t);
    } else if (b < 552) {     // feat l3: 6 * 4
        int r = b - 528, n = r >> 2, y = r & 3;
        ft_tile<11, 4, 11>(tile, f3, fT, n, y, 0, 2838528, t);
    } else if (b < 2600) {
        int i = (b - 552) * 256 + t; Wb1[i] = __float2bfloat16(mid_w1[i]);
    } else if (b < 3624) {
        int i = (b - 2600) * 256 + t; Wb2[i] = __float2bfloat16(mid_w2[i]);
    } else if (b < 3880) {
        int i = (b - 3624) * 256 + t; Wb3[i] = __float2bfloat16(mid_w3[i]);
    } else if (b < 4008) {
        int n = b - 3880; Wpe[n * 256 + t] = __float2bfloat16(pe_w2[t * 128 + n]);
    } else if (b < 4072) {    // packed offsw weight: 64 rows (24 off + 32 sw + 8 zero)
        int n = b - 4008;
        if (t < 128) {
            float w = 0.f;
            if (n < 24)      w = off_w[n * 128 + t];
            else if (n < 56) w = sw_w[(n - 24) * 128 + t];
            Wof[n * 128 + t] = __float2bfloat16(w);
            if (t == 0) Bof[n] = (n < 24) ? off_b[n] : ((n < 56) ? sw_b[n - 24] : 0.f);
        }
    } else if (b < 4200) {
        int o = b - 4072;
        for (int idx = t; idx < 1152; idx += 256) {
            int s = idx >> 7, i = idx & 127;
            Wcv1[o * 1152 + idx] = __float2bfloat16(in_w[(o * 128 + i) * 9 + s]);
        }
    } else if (b < 4328) {
        int o = b - 4200;
        for (int idx = t; idx < 1152; idx += 256) {
            int s = idx >> 7, i = idx & 127;
            Wcv2[o * 1152 + idx] = __float2bfloat16(out_w[(o * 128 + i) * 9 + s]);
        }
    } else if (b < 4361) {    // qT border zero: 516 border pixels x 16 uint4
        int g = (b - 4328) * 256 + t;
        if (g < 8256) {
            int pixi = g >> 4, part = g & 15;
            int row, col;
            if (pixi < 130)      { row = 0;   col = pixi; }
            else if (pixi < 260) { row = 129; col = pixi - 130; }
            else {
                int r = pixi - 260;
                row = 1 + (r & 127);
                col = (r < 128) ? 0 : 129;
            }
            uint4 z = {0u, 0u, 0u, 0u};
            *(uint4*)&qTo[((size_t)row * 130 + col) * 128 + part * 8] = z;
        }
    } else if (b < 4362) {    // stats zero: 768 floats
        Stats[t] = 0.f; Stats[256 + t] = 0.f; Stats[512 + t] = 0.f;
    } else {                  // bev_query CHW -> padded HWC bf16 interior (256 blocks)
        int rel = b - 4362;
        int y = rel >> 1, x0 = (rel & 1) * 64;
        int xi = t & 63, c0 = t >> 6;
        for (int c = c0; c < 128; c += 4)
            tile[c * 65 + xi] = bev_query[c * HW + y * 128 + x0 + xi];
        __syncthreads();
        int xp = t >> 2, cg = (t & 3) * 32;
        __hip_bfloat16* dst = qTo + ((size_t)(y + 1) * 130 + (x0 + 1 + xp)) * 128;
        #pragma unroll
        for (int g = 0; g < 4; g++) {
            int c = cg + g * 8;
            union { __hip_bfloat16 h[8]; uint4 u; } pk;
            #pragma unroll
            for (int j = 0; j < 8; j++)
                pk.h[j] = __float2bfloat16(tile[(c + j) * 65 + xp]);
            *(uint4*)&dst[c] = pk.u;
        }
    }
}

// ---------------- CHW fp32 [128][128^2] -> padded HWC bf16 [130][130][128] (interior) ----------------
// stats (optional): per-channel {sum, sumsq}; applies instance-norm while packing.
__global__ __launch_bounds__(256) void chw2hwc_pad_k(
    const float* __restrict__ q, const float* __restrict__ stats,
    __hip_bfloat16* __restrict__ out)
{
    __shared__ float tile[128][65];
    __shared__ float sm[128], sr[128];
    int t = threadIdx.x;
    if (t < 128) {
        if (stats) {
            float s = stats[2 * t], s2 = stats[2 * t + 1];
            float mean = s * (1.0f / HW);
            sm[t] = mean;
            sr[t] = rsqrtf(s2 * (1.0f / HW) - mean * mean + 1e-5f);
        } else {
            sm[t] = 0.f; sr[t] = 1.f;
        }
    }
    int b = blockIdx.x;            // 256 blocks: y = b>>1, x0 = (b&1)*64
    int y = b >> 1, x0 = (b & 1) * 64;
    int xi = t & 63, c0 = t >> 6;
    for (int c = c0; c < 128; c += 4)
        tile[c][xi] = q[c * HW + y * 128 + x0 + xi];
    __syncthreads();
    int xp = t >> 2, cg = (t & 3) * 32;
    __hip_bfloat16* dst = out + ((size_t)(y + 1) * 130 + (x0 + 1 + xp)) * 128;
    #pragma unroll
    for (int g = 0; g < 4; g++) {
        int c = cg + g * 8;
        union { __hip_bfloat16 h[8]; uint4 u; } pk;
        #pragma unroll
        for (int j = 0; j < 8; j++)
            pk.h[j] = __float2bfloat16((tile[c + j][xp] - sm[c + j]) * sr[c + j]);
        *(uint4*)&dst[c] = pk.u;
    }
}

// ---------------- bf16 MFMA GEMM: out[m][n] = act(bias[n] + sum_k X[m][k] W[n][k]) ----------------
// OUTT: 0 -> bf16 [M][N]; 1 -> fp32 [N][M] (CHW, + optional residual res[n][m]).
// CONV: X is padded HWC bf16 [130][130][128]; k = s*128+c.
// rstats: normalize residual with {sum,sumsq}; ostats: accumulate output {sum,sumsq} (OUTT==1 only).
// K-loop: NBUF-deep LDS pipeline with counted vmcnt (never 0 in steady state) + raw s_barrier.
// LDS XOR-swizzle (both-sides): global source chunk permuted on stage, ds_read slot permuted to match.
template<int BM, int BN, int ACT, int OUTT, int CONV>
__global__ __launch_bounds__(256) void bgemm_k(
    const __hip_bfloat16* __restrict__ X, const __hip_bfloat16* __restrict__ W,
    const float* __restrict__ bias, void* __restrict__ outp,
    const float* __restrict__ res,
    const float* __restrict__ rstats, float* __restrict__ ostats,
    int M, int K, int N)
{
    constexpr int ROWS = BM + BN;
    constexpr int ITERS = (ROWS * 4) / 256;       // global_load_lds per lane per stage
    constexpr int BUFE  = ROWS * 32;              // bf16 elements per buffer
    constexpr int NBUF  = (ITERS == 2) ? 4 : 3;   // 32 KB / 48 KB LDS
    __shared__ __align__(16) __hip_bfloat16 SH[NBUF * BUFE];
    int t = threadIdx.x;
    int w = t >> 6, lane = t & 63;
    int mb = blockIdx.y * BM, nb = blockIdx.x * BN;
    int cy = mb >> 7, cx = mb & 127;   // conv tile coords (CONV only)
    constexpr int WM = BM / 2;
    constexpr int MI = WM / 16;
    constexpr int NJ = BN / 32;
    int wm = (w & 1) * WM, wn = (w >> 1) * (BN / 2);
    int lm = lane & 15, lq = lane >> 4;
    int sl = (lq ^ ((lm >> 1) & 3)) * 8;          // swizzled k-slot for ds_read
    floatx4 zero = {0.f, 0.f, 0.f, 0.f};
    floatx4 acc[MI][NJ];
    #pragma unroll
    for (int i = 0; i < MI; i++)
        #pragma unroll
        for (int j = 0; j < NJ; j++) acc[i][j] = zero;

    const int nsteps = K >> 5;

    auto STAGE = [&](int bufi, int tk2) {
        int kb_ = tk2 * 32;
        int s_ = kb_ >> 7;
        int dyi_ = s_ / 3, dxi_ = s_ - dyi_ * 3;   // tap indices (CONV only)
        #pragma unroll
        for (int it = 0; it < ITERS; it++) {
            int chunk = it * 256 + t;
            int row = chunk >> 2;
            int ko = ((chunk & 3) ^ ((row >> 1) & 3)) * 8;   // source-side swizzle
            const __hip_bfloat16* src;
            if (row < BM) {
                if (CONV)
                    src = X + (((size_t)(cy + dyi_) * 130) + (cx + dxi_ + row)) * 128 + (kb_ & 127) + ko;
                else
                    src = X + (size_t)(mb + row) * K + kb_ + ko;
            } else {
                src = W + (size_t)(nb + row - BM) * K + kb_ + ko;
            }
            __builtin_amdgcn_global_load_lds(
                (const __attribute__((address_space(1))) void*)src,
                (__attribute__((address_space(3))) void*)&SH[bufi * BUFE + (it * 256 + (t & ~63)) * 8],
                16, 0, 0);
        }
    };

    #pragma unroll
    for (int pi = 0; pi < NBUF - 1; pi++)
        if (pi < nsteps) STAGE(pi, pi);

    for (int tk = 0; tk < nsteps; ++tk) {
        int rem = nsteps - 1 - tk;
        if constexpr (ITERS == 2) {                // NBUF=4: up to 2 stages beyond current
            if (rem >= 2)      asm volatile("s_waitcnt vmcnt(4)" ::: "memory");
            else if (rem == 1) asm volatile("s_waitcnt vmcnt(2)" ::: "memory");
            else               asm volatile("s_waitcnt vmcnt(0)" ::: "memory");
        } else {                                   // NBUF=3: up to 1 stage beyond current
            if (rem >= 1)      asm volatile("s_waitcnt vmcnt(4)" ::: "memory");
            else               asm volatile("s_waitcnt vmcnt(0)" ::: "memory");
        }
        __builtin_amdgcn_s_barrier();
        int tkn = tk + NBUF - 1;
        if (tkn < nsteps) STAGE(tkn % NBUF, tkn);

        const __hip_bfloat16* As = SH + (tk % NBUF) * BUFE;
        const __hip_bfloat16* Bs = As + BM * 32;
        short8 af[MI], bf[NJ];
        #pragma unroll
        for (int i = 0; i < MI; i++)
            af[i] = *(const short8*)&As[(wm + i * 16 + lm) * 32 + sl];
        #pragma unroll
        for (int j = 0; j < NJ; j++)
            bf[j] = *(const short8*)&Bs[(wn + j * 16 + lm) * 32 + sl];
        #pragma unroll
        for (int i = 0; i < MI; i++)
            #pragma unroll
            for (int j = 0; j < NJ; j++)
                acc[i][j] = __builtin_amdgcn_mfma_f32_16x16x32_bf16(af[i], bf[j], acc[i][j], 0, 0, 0);
    }

    float invM = 1.0f / (float)M;
    #pragma unroll
    for (int j = 0; j < NJ; j++) {
        int n = nb + wn + j * 16 + lm;
        float bv = bias[n];
        float rmean = 0.f, rrstd = 0.f;
        if (OUTT == 1 && res && rstats) {
            float s = rstats[2 * n], s2 = rstats[2 * n + 1];
            rmean = s * invM;
            rrstd = rsqrtf(s2 * invM - rmean * rmean + 1e-5f);
        }
        float ss = 0.f, ss2 = 0.f;
        #pragma unroll
        for (int i = 0; i < MI; i++) {
            #pragma unroll
            for (int r = 0; r < 4; r++) {
                int m = mb + wm + i * 16 + lq * 4 + r;
                float v = acc[i][j][r] + bv;
                if (ACT) v = gelu_exact(v);
                if (OUTT == 0) {
                    ((__hip_bfloat16*)outp)[(size_t)m * N + n] = __float2bfloat16(v);
                } else {
                    if (res) {
                        float rv = res[(size_t)n * M + m];
                        v += rstats ? (rv - rmean) * rrstd : rv;
                    }
                    ((float*)outp)[(size_t)n * M + m] = v;
                    ss += v; ss2 += v * v;
                }
            }
        }
        if (OUTT == 1 && ostats) {
            ss  += __shfl_xor(ss, 16);  ss  += __shfl_xor(ss, 32);
            ss2 += __shfl_xor(ss2, 16); ss2 += __shfl_xor(ss2, 32);
            if (lq == 0) {
                atomicAdd(&ostats[2 * n], ss);
                atomicAdd(&ostats[2 * n + 1], ss2);
            }
        }
    }
}

// ---------------- fused PE: hidden = relu(rn @ w1 + b1) on the fly, GEMM vs Wpe ----------------
__global__ __launch_bounds__(256) void pe_bgemm_k(
    const float* __restrict__ pts, const float* __restrict__ pe_w1,
    const float* __restrict__ pe_b1, const __hip_bfloat16* __restrict__ W,
    const float* __restrict__ bias, __hip_bfloat16* __restrict__ out)
{
    __shared__ __align__(16) __hip_bfloat16 As[128 * 32];
    __shared__ __align__(16) __hip_bfloat16 Bs[128 * 32];
    __shared__ __align__(16) float wps[4][256];   // [b1, w1_x, w1_y, w1_z][256]
    int t = threadIdx.x;
    int w = t >> 6, lane = t & 63;
    int mb = blockIdx.x * 128;
    {
        int d = t >> 6, c = (t & 63) * 4;
        float4 v;
        if (d == 0) v = *(const float4*)&pe_b1[c];
        else        v = *(const float4*)&pe_w1[(d - 1) * 256 + c];
        *(float4*)&wps[d][c] = v;
    }
    int cg = t & 3;
    int r0 = t >> 2;
    float rn[2][3];
    #pragma unroll
    for (int h = 0; h < 2; h++) {
        int r = mb + r0 + h * 64;
        rn[h][0] = (pts[(size_t)r * 3 + 0] + 50.f) * 0.01f;
        rn[h][1] = (pts[(size_t)r * 3 + 1] + 50.f) * 0.01f;
        rn[h][2] = (pts[(size_t)r * 3 + 2] + 4.f) * 0.125f;
    }
    int wm = (w & 1) * 64, wn = (w >> 1) * 64;
    int lm = lane & 15, lq = lane >> 4;
    floatx4 zero = {0.f, 0.f, 0.f, 0.f};
    floatx4 acc[4][4];
    #pragma unroll
    for (int i = 0; i < 4; i++)
        #pragma unroll
        for (int j = 0; j < 4; j++) acc[i][j] = zero;
    for (int kb = 0; kb < 256; kb += 32) {
        __syncthreads();
        #pragma unroll
        for (int it = 0; it < 2; it++) {
            int chunk = it * 256 + t;
            int brow = chunk >> 2, ko = (chunk & 3) * 8;
            const __hip_bfloat16* src = W + (size_t)brow * 256 + kb + ko;
            __builtin_amdgcn_global_load_lds(
                (const __attribute__((address_space(1))) void*)src,
                (__attribute__((address_space(3))) void*)&Bs[(size_t)(it * 256 + (t & ~63)) * 8],
                16, 0, 0);
        }
        int c0 = kb + cg * 8;
        float4 bva = *(const float4*)&wps[0][c0], bvb = *(const float4*)&wps[0][c0 + 4];
        float4 wxa = *(const float4*)&wps[1][c0], wxb = *(const float4*)&wps[1][c0 + 4];
        float4 wya = *(const float4*)&wps[2][c0], wyb = *(const float4*)&wps[2][c0 + 4];
        float4 wza = *(const float4*)&wps[3][c0], wzb = *(const float4*)&wps[3][c0 + 4];
        #pragma unroll
        for (int h = 0; h < 2; h++) {
            const float* bv = (const float*)&bva;
            const float* wx = (const float*)&wxa;
            const float* wy = (const float*)&wya;
            const float* wz = (const float*)&wza;
            union { __hip_bfloat16 hh[8]; uint4 u; } pk;
            #pragma unroll
            for (int j = 0; j < 4; j++) {
                float v = bv[j] + rn[h][0] * wx[j] + rn[h][1] * wy[j] + rn[h][2] * wz[j];
                pk.hh[j] = __float2bfloat16(fmaxf(v, 0.f));
            }
            bv = (const float*)&bvb; wx = (const float*)&wxb;
            wy = (const float*)&wyb; wz = (const float*)&wzb;
            #pragma unroll
            for (int j = 0; j < 4; j++) {
                float v = bv[j] + rn[h][0] * wx[j] + rn[h][1] * wy[j] + rn[h][2] * wz[j];
                pk.hh[4 + j] = __float2bfloat16(fmaxf(v, 0.f));
            }
            *(uint4*)&As[(r0 + h * 64) * 32 + cg * 8] = pk.u;
        }
        __syncthreads();
        short8 af[4], bf[4];
        #pragma unroll
        for (int i = 0; i < 4; i++)
            af[i] = *(const short8*)&As[(wm + i * 16 + lm) * 32 + lq * 8];
        #pragma unroll
        for (int j = 0; j < 4; j++)
            bf[j] = *(const short8*)&Bs[(wn + j * 16 + lm) * 32 + lq * 8];
        #pragma unroll
        for (int i = 0; i < 4; i++)
            #pragma unroll
            for (int j = 0; j < 4; j++)
                acc[i][j] = __builtin_amdgcn_mfma_f32_16x16x32_bf16(af[i], bf[j], acc[i][j], 0, 0, 0);
    }
    #pragma unroll
    for (int i = 0; i < 4; i++) {
        #pragma unroll
        for (int j = 0; j < 4; j++) {
            int n = wn + j * 16 + lm;
            float bv = bias[n];
            #pragma unroll
            for (int r = 0; r < 4; r++) {
                int m = mb + wm + i * 16 + lq * 4 + r;
                out[(size_t)m * 128 + n] = __float2bfloat16(acc[i][j][r] + bv);
            }
        }
    }
}

// ---------------- final instance norm apply (stats precomputed in producer epilogue) ----------------
__global__ __launch_bounds__(256) void inorm_apply_k(
    const float* __restrict__ in, const float* __restrict__ stats, float* __restrict__ out)
{
    int b = blockIdx.x;           // 1024 blocks: c = b>>3, seg = b&7 (2048 floats each)
    int c = b >> 3, seg = b & 7;
    float s = stats[2 * c], s2 = stats[2 * c + 1];
    float mean = s * (1.0f / HW);
    float rstd = rsqrtf(s2 * (1.0f / HW) - mean * mean + 1e-5f);
    const float4* pi = (const float4*)(in + (size_t)c * HW + seg * 2048);
    float4*       po = (float4*)(out + (size_t)c * HW + seg * 2048);
    int t = threadIdx.x;
    #pragma unroll
    for (int k = 0; k < 2; k++) {
        float4 v = pi[t + k * 256];
        v.x = (v.x - mean) * rstd; v.y = (v.y - mean) * rstd;
        v.z = (v.z - mean) * rstd; v.w = (v.w - mean) * rstd;
        po[t + k * 256] = v;
    }
}

// ---------------- offsw epilogue: raw [n][16384] fp32 -> pts/swn/height ----------------
// 256 blocks: pixel block = b&63, p-group = b>>6 (2 p each).
__global__ __launch_bounds__(256) void offpost_k(
    const float* __restrict__ raw, const float* __restrict__ bev_pos,
    float* __restrict__ pts, float* __restrict__ swn, float* __restrict__ height_out)
{
    int b = blockIdx.x;
    int pix = (b & 63) * 256 + threadIdx.x;
    int p0 = (b >> 6) * 2;
    const float pcmin[3] = {-50.f, -50.f, -4.f};
    const float rng[3]   = {100.f, 100.f, 8.f};
    float bp[3];
    #pragma unroll
    for (int d = 0; d < 3; d++) bp[d] = bev_pos[pix * 3 + d];
    #pragma unroll
    for (int pi = 0; pi < 2; pi++) {
        int p = p0 + pi;
        #pragma unroll
        for (int d = 0; d < 3; d++) {
            float acc = raw[(p * 3 + d) * HW + pix];
            float sv = 1.f / (1.f + expf(-acc));
            float lim = (d == 2) ? (4.0f + 1e-6f) : (0.25f + 1e-6f);
            float offv = sv * 2.f * lim - lim;
            float refv = bp[d] * rng[d] + pcmin[d];
            pts[pix * 24 + p * 3 + d] = refv + offv;
            if (d == 2) height_out[p * HW + pix] = offv;
        }
        float r[4], m = -1e30f;
        #pragma unroll
        for (int l = 0; l < 4; l++) {
            r[l] = raw[(24 + p * 4 + l) * HW + pix];
            m = fmaxf(m, r[l]);
        }
        float sum = 0.f;
        #pragma unroll
        for (int l = 0; l < 4; l++) { r[l] = expf(r[l] - m); sum += r[l]; }
        float inv = 1.f / sum;
        #pragma unroll
        for (int l = 0; l < 4; l++) swn[pix * 32 + p * 4 + l] = r[l] * inv;
    }
}

// ---------------- sampling: phase-1 projection + cull, phase-2 bf16 packed gather ----------------
// 256 threads = 4 waves; wave wv owns p = wv*2 + {0,1}; offsets stored as BYTE offsets;
// main loop processes 2 taps/iter with split accumulators (8 loads in flight).
__global__ __launch_bounds__(256) void sample_k(
    const __hip_bfloat16* __restrict__ featT, const float* __restrict__ pts,
    const float* __restrict__ swn,   const float* __restrict__ l2i,
    __hip_bfloat16* __restrict__ sf)
{
    int pix = blockIdx.x;
    int t = threadIdx.x;
    int lane = t & 63, wv = t >> 6;
    __shared__ float pts_s[24];
    __shared__ float swl_s[32];
    __shared__ float M[96];
    __shared__ __align__(16) int   offs[8][24][4];   // byte offsets into featT
    __shared__ __align__(16) float wts[8][24][4];
    __shared__ int cnt[8];
    if (t < 96) M[t] = l2i[t];
    if (t < 24) pts_s[t] = pts[pix * 24 + t];
    if (t < 32) swl_s[t] = swn[pix * 32 + t];
    if (t < 8)  cnt[t] = 0;
    __syncthreads();

    floatx2 acc[2];
    #pragma unroll
    for (int i = 0; i < 2; i++) {
        unsigned int u = *(const unsigned int*)&sf[(size_t)pix * 1024 + (wv * 2 + i) * 128 + 2 * lane];
        acc[i] = bf2x(u);
    }

    const int lHt[4] = {32, 16, 8, 4}, lWt[4] = {88, 44, 22, 11};
    const int loff[4] = {0, 2162688, 2703360, 2838528};
    if (t < 192) {
        int p = t / 24;
        int rr = t - p * 24;
        int n = rr >> 2, l = rr & 3;
        float X = pts_s[p * 3], Y = pts_s[p * 3 + 1], Z = pts_s[p * 3 + 2];
        const float* Mn = &M[n * 16];
        float zc = Mn[8] * X + Mn[9] * Y + Mn[10] * Z + Mn[11];
        if (zc > 1e-5f) {
            float inv = 1.f / zc;
            float xn = (Mn[0] * X + Mn[1] * Y + Mn[2] * Z + Mn[3]) * inv * (1.f / 704.f);
            float yn = (Mn[4] * X + Mn[5] * Y + Mn[6] * Z + Mn[7]) * inv * (1.f / 256.f);
            int Wl = lWt[l], Hl = lHt[l];
            float px = xn * Wl - 0.5f, py = yn * Hl - 0.5f;
            px = fminf(fmaxf(px, -2.f), (float)(Wl + 1));
            py = fminf(fmaxf(py, -2.f), (float)(Hl + 1));
            float x0f = floorf(px), y0f = floorf(py);
            float wx = px - x0f, wy = py - y0f;
            int x0 = (int)x0f, y0 = (int)y0f;
            bool xi0 = (unsigned)x0 < (unsigned)Wl, xi1 = (unsigned)(x0 + 1) < (unsigned)Wl;
            bool yi0 = (unsigned)y0 < (unsigned)Hl, yi1 = (unsigned)(y0 + 1) < (unsigned)Hl;
            if ((xi0 || xi1) && (yi0 || yi1)) {
                float wl = swl_s[p * 4 + l];
                float w00 = wl * (1.f - wx) * (1.f - wy) * (float)(xi0 && yi0);
                float w10 = wl * wx * (1.f - wy)         * (float)(xi1 && yi0);
                float w01 = wl * (1.f - wx) * wy         * (float)(xi0 && yi1);
                float w11 = wl * wx * wy                 * (float)(xi1 && yi1);
                int x0c = min(max(x0, 0), Wl - 1), x1c = min(max(x0 + 1, 0), Wl - 1);
                int y0c = min(max(y0, 0), Hl - 1), y1c = min(max(y0 + 1, 0), Hl - 1);
                int base = loff[l] + n * Hl * Wl * 128;
                int idx = atomicAdd(&cnt[p], 1);
                offs[p][idx][0] = (base + (y0c * Wl + x0c) * 128) * 2;
                offs[p][idx][1] = (base + (y0c * Wl + x1c) * 128) * 2;
                offs[p][idx][2] = (base + (y1c * Wl + x0c) * 128) * 2;
                offs[p][idx][3] = (base + (y1c * Wl + x1c) * 128) * 2;
                wts[p][idx][0] = w00; wts[p][idx][1] = w10;
                wts[p][idx][2] = w01; wts[p][idx][3] = w11;
            }
        }
    }
    __syncthreads();

    const char* fbase = (const char*)featT;
    int lane4 = lane * 4;
    #pragma unroll
    for (int i = 0; i < 2; i++) {
        int p = wv * 2 + i;
        int np = cnt[p];
        floatx2 a0 = acc[i];
        floatx2 a1 = {0.f, 0.f};
        int j = 0;
        #pragma unroll 1
        for (; j + 2 <= np; j += 2) {
            int4   oA = *(const int4*)&offs[p][j][0];
            float4 wA = *(const float4*)&wts[p][j][0];
            int4   oB = *(const int4*)&offs[p][j + 1][0];
            float4 wB = *(const float4*)&wts[p][j + 1][0];
            unsigned int v0 = *(const unsigned int*)(fbase + (unsigned)(oA.x + lane4));
            unsigned int v1 = *(const unsigned int*)(fbase + (unsigned)(oA.y + lane4));
            unsigned int v2 = *(const unsigned int*)(fbase + (unsigned)(oA.z + lane4));
            unsigned int v3 = *(const unsigned int*)(fbase + (unsigned)(oA.w + lane4));
            unsigned int v4 = *(const unsigned int*)(fbase + (unsigned)(oB.x + lane4));
            unsigned int v5 = *(const unsigned int*)(fbase + (unsigned)(oB.y + lane4));
            unsigned int v6 = *(const unsigned int*)(fbase + (unsigned)(oB.z + lane4));
            unsigned int v7 = *(const unsigned int*)(fbase + (unsigned)(oB.w + lane4));
            a0 += bf2x(v0) * wA.x;
            a0 += bf2x(v1) * wA.y;
            a0 += bf2x(v2) * wA.z;
            a0 += bf2x(v3) * wA.w;
            a1 += bf2x(v4) * wB.x;
            a1 += bf2x(v5) * wB.y;
            a1 += bf2x(v6) * wB.z;
            a1 += bf2x(v7) * wB.w;
        }
        if (j < np) {
            int4   o = *(const int4*)&offs[p][j][0];
            float4 w = *(const float4*)&wts[p][j][0];
            unsigned int v0 = *(const unsigned int*)(fbase + (unsigned)(o.x + lane4));
            unsigned int v1 = *(const unsigned int*)(fbase + (unsigned)(o.y + lane4));
            unsigned int v2 = *(const unsigned int*)(fbase + (unsigned)(o.z + lane4));
            unsigned int v3 = *(const unsigned int*)(fbase + (unsigned)(o.w + lane4));
            a0 += bf2x(v0) * w.x;
            a0 += bf2x(v1) * w.y;
            a0 += bf2x(v2) * w.z;
            a0 += bf2x(v3) * w.w;
        }
        acc[i] = a0 + a1;
    }
    #pragma unroll
    for (int i = 0; i < 2; i++) {
        union { __hip_bfloat16 h[2]; unsigned int u; } pk;
        pk.h[0] = __float2bfloat16(acc[i].x);
        pk.h[1] = __float2bfloat16(acc[i].y);
        *(unsigned int*)&sf[(size_t)pix * 1024 + (wv * 2 + i) * 128 + 2 * lane] = pk.u;
    }
}

extern "C" void kernel_launch(void* const* d_in, const int* in_sizes, int n_in,
                              void* d_out, int out_size, void* d_ws, size_t ws_size,
                              hipStream_t stream)
{
    const float* feat[4] = {(const float*)d_in[0], (const float*)d_in[1],
                            (const float*)d_in[2], (const float*)d_in[3]};
    const float* l2i       = (const float*)d_in[4];
    const float* bev_query = (const float*)d_in[5];
    const float* bev_pos   = (const float*)d_in[6];
    const float* in_w  = (const float*)d_in[7];  const float* in_b  = (const float*)d_in[8];
    const float* off_w = (const float*)d_in[9];  const float* off_b = (const float*)d_in[10];
    const float* sw_w  = (const float*)d_in[11]; const float* sw_b  = (const float*)d_in[12];
    const float* pe_w1 = (const float*)d_in[13]; const float* pe_b1 = (const float*)d_in[14];
    const float* pe_w2 = (const float*)d_in[15]; const float* pe_b2 = (const float*)d_in[16];
    const float* mid_w1 = (const float*)d_in[17]; const float* mid_b1 = (const float*)d_in[18];
    const float* mid_w2 = (const float*)d_in[19]; const float* mid_b2 = (const float*)d_in[20];
    const float* mid_w3 = (const float*)d_in[21]; const float* mid_b3 = (const float*)d_in[22];
    const float* out_w  = (const float*)d_in[23]; const float* out_b  = (const float*)d_in[24];

    float* ws = (float*)d_ws;
    float* fTf = ws;                    // 1,436,160 : transposed feats bf16
    __hip_bfloat16* fT = (__hip_bfloat16*)fTf;
    float* Bb  = fTf + 1436160;         // 2,097,152 : offsw raw / q1 raw (CHW)
    float* Cb  = Bb + 2097152;          // 2,097,152 : q0 raw (conv1 out, CHW)
    float* Gb  = Cb + 2097152;          // 2,097,152 : conv2 raw (CHW)
    float* Dp  = Gb + 2097152;          //   393,216 : pts
    float* Eb  = Dp + 393216;           //   524,288 : swn
    float* QTf = Eb + 524288;           // 1,081,600 : padded HWC bf16 (130*130*128)
    __hip_bfloat16* qT = (__hip_bfloat16*)QTf;
    float* SFf = QTf + 1081600;         // 8,388,608 : sf bf16 131072x128
    __hip_bfloat16* sfb = (__hip_bfloat16*)SFf;
    float* M1f = SFf + 8388608;         // 4,194,304 : m1 bf16
    __hip_bfloat16* m1b = (__hip_bfloat16*)M1f;
    float* M2f = M1f + 4194304;         // 4,194,304 : m2 bf16
    __hip_bfloat16* m2b = (__hip_bfloat16*)M2f;
    float* WC1 = M2f + 4194304;         //    73,728 : conv1 weights bf16
    __hip_bfloat16* Wcv1 = (__hip_bfloat16*)WC1;
    float* WC2 = WC1 + 73728;           //    73,728 : conv2 weights bf16
    __hip_bfloat16* Wcv2 = (__hip_bfloat16*)WC2;
    float* W1f = WC2 + 73728;           //   262,144
    __hip_bfloat16* Wb1 = (__hip_bfloat16*)W1f;
    float* W2f = W1f + 262144;          //   131,072
    __hip_bfloat16* Wb2 = (__hip_bfloat16*)W2f;
    float* W3f = W2f + 131072;          //    32,768
    __hip_bfloat16* Wb3 = (__hip_bfloat16*)W3f;
    float* WPf = W3f + 32768;           //    16,384 : pe_w2^T bf16
    __hip_bfloat16* Wpe = (__hip_bfloat16*)WPf;
    float* WOf = WPf + 16384;           //     8,192 : offsw packed weight bf16 (64x128 used)
    __hip_bfloat16* Wof = (__hip_bfloat16*)WOf;
    float* Bof = WOf + 8192;            //       128 : offsw packed bias fp32 (64 used)
    float* Stats = Bof + 128;           //       768 : 3 x 128 x {sum,sumsq}
    float* stats1 = Stats;
    float* stats2 = Stats + 256;
    float* stats3 = Stats + 512;

    float* q_out = (float*)d_out;
    float* h_out = q_out + 2097152;

    // setup: feat transpose + weight prep + qT border zero + stats zero + bev_query pad
    setup_k<<<4618, 256, 0, stream>>>(feat[0], feat[1], feat[2], feat[3], fT,
                                      mid_w1, mid_w2, mid_w3, pe_w2, off_w, off_b, sw_w, sw_b,
                                      in_w, out_w, bev_query,
                                      Wb1, Wb2, Wb3, Wpe, Wof, Bof, Wcv1, Wcv2,
                                      qT, Stats);

    // conv1: q0raw = bev_query + conv3x3(bev_query) -> Cb, stats1 accumulated in epilogue
    bgemm_k<64, 64, 0, 1, 1><<<dim3(2, 256), 256, 0, stream>>>(
        qT, Wcv1, in_b, Cb, bev_query, nullptr, stats1, HW, 1152, 128);

    // offsets/sample-weights GEMM (N=64) over center tap of normalized q0 + epilogue
    chw2hwc_pad_k<<<256, 256, 0, stream>>>(Cb, stats1, qT);   // applies inorm(q0raw)
    bgemm_k<64, 64, 0, 1, 1><<<dim3(1, 256), 256, 0, stream>>>(
        qT + 131 * 128, Wof, Bof, Bb, nullptr, nullptr, nullptr, HW, 128, 64);
    offpost_k<<<256, 256, 0, stream>>>(Bb, bev_pos, Dp, Eb, h_out);

    // fused PE (hidden on the fly + MFMA GEMM) -> sf
    pe_bgemm_k<<<1024, 256, 0, stream>>>(Dp, pe_w1, pe_b1, Wpe, pe_b2, sfb);

    // sampling accumulates taps onto sf
    sample_k<<<HW, 256, 0, stream>>>(fT, Dp, Eb, l2i, sfb);

    // mid MLP: 1024 -> 512 gelu -> 512 gelu -> 128 linear (+ normalized q0 residual)
    bgemm_k<128, 128, 1, 0, 0><<<dim3(4, 128), 256, 0, stream>>>(
        sfb, Wb1, mid_b1, m1b, nullptr, nullptr, nullptr, HW, 1024, 512);
    bgemm_k<128, 128, 1, 0, 0><<<dim3(4, 128), 256, 0, stream>>>(
        m1b, Wb2, mid_b2, m2b, nullptr, nullptr, nullptr, HW, 512, 512);
    bgemm_k<64, 64, 0, 1, 0><<<dim3(2, 256), 256, 0, stream>>>(
        m2b, Wb3, mid_b3, Bb, Cb, stats1, stats2, HW, 512, 128);   // q1raw -> Bb, stats2

    // conv2: q = inorm(q1n + conv3x3(q1n)); q1n applied on the fly from stats2
    chw2hwc_pad_k<<<256, 256, 0, stream>>>(Bb, stats2, qT);
    bgemm_k<64, 64, 0, 1, 1><<<dim3(2, 256), 256, 0, stream>>>(
        qT, Wcv2, out_b, Gb, Bb, stats2, stats3, HW, 1152, 128);   // conv2 raw -> Gb, stats3
    inorm_apply_k<<<1024, 256, 0, stream>>>(Gb, stats3, q_out);
}

// Round 8
// 375.176 us; speedup vs baseline: 1.0767x; 1.0011x over previous
//
#include <hip/hip_runtime.h>
#include <hip/hip_bf16.h>
#include <math.h>

#define HW 16384   // 128*128 bev pixels

typedef __attribute__((ext_vector_type(8))) short short8;
typedef __attribute__((ext_vector_type(4))) float floatx4;
typedef __attribute__((ext_vector_type(2))) float floatx2;

__device__ __forceinline__ float gelu_exact(float x){
    return 0.5f * x * (1.0f + erff(x * 0.7071067811865475f));
}

__device__ __forceinline__ floatx2 bf2x(unsigned int u){
    floatx2 r;
    r.x = __uint_as_float(u << 16);
    r.y = __uint_as_float(u & 0xffff0000u);
    return r;
}

// ---------------- feat transpose tile: (N,C,H,W) fp32 -> (N,H,W,C) bf16 ----------------
// LDS-tiled: coalesced reads along x, coalesced 16B HWC writes.
template<int CW, int HL, int WL>
__device__ __forceinline__ void ft_tile(
    float* tile, const float* __restrict__ in, __hip_bfloat16* __restrict__ out,
    int n, int y, int x0, int base, int t)
{
    const float* src = in + ((size_t)n * 128 * HL + y) * WL + x0;
    constexpr int NE = 128 * CW;
    for (int idx = t; idx < NE; idx += 256) {
        int c = idx / CW, x = idx - c * CW;
        tile[c * 45 + x] = src[(size_t)c * (HL * WL) + x];
    }
    __syncthreads();
    __hip_bfloat16* dst = out + base + ((size_t)(n * HL + y) * WL + x0) * 128;
    constexpr int NO = CW * 16;
    for (int idx = t; idx < NO; idx += 256) {
        int x = idx >> 4, g = idx & 15;
        union { __hip_bfloat16 h[8]; uint4 u; } pk;
        #pragma unroll
        for (int jj = 0; jj < 8; jj++)
            pk.h[jj] = __float2bfloat16(tile[(g * 8 + jj) * 45 + x]);
        *(uint4*)&dst[(size_t)x * 128 + g * 8] = pk.u;
    }
}

// ---------------- unified setup: feat transpose + weight prep + qT border zero + stats zero
// ---------------- + first CHW->padded-HWC pack of bev_query (no stats) ----------------
__global__ __launch_bounds__(256) void setup_k(
    const float* __restrict__ f0, const float* __restrict__ f1,
    const float* __restrict__ f2, const float* __restrict__ f3,
    __hip_bfloat16* __restrict__ fT,
    const float* __restrict__ mid_w1, const float* __restrict__ mid_w2,
    const float* __restrict__ mid_w3, const float* __restrict__ pe_w2,
    const float* __restrict__ off_w,  const float* __restrict__ off_b,
    const float* __restrict__ sw_w,   const float* __restrict__ sw_b,
    const float* __restrict__ in_w,   const float* __restrict__ out_w,
    const float* __restrict__ bev_query,
    __hip_bfloat16* __restrict__ Wb1, __hip_bfloat16* __restrict__ Wb2,
    __hip_bfloat16* __restrict__ Wb3, __hip_bfloat16* __restrict__ Wpe,
    __hip_bfloat16* __restrict__ Wof, float* __restrict__ Bof,
    __hip_bfloat16* __restrict__ Wcv1, __hip_bfloat16* __restrict__ Wcv2,
    __hip_bfloat16* __restrict__ qTo, float* __restrict__ Stats)
{
    __shared__ float tile[128 * 65];
    int b = blockIdx.x, t = threadIdx.x;
    if (b < 384) {            // feat l0: 6 cams * 32 y * 2 xchunks
        int n = b >> 6, q = b & 63, y = q >> 1, x0 = (q & 1) * 44;
        ft_tile<44, 32, 88>(tile, f0, fT, n, y, x0, 0, t);
    } else if (b < 480) {     // feat l1: 6 * 16
        int r = b - 384, n = r >> 4, y = r & 15;
        ft_tile<44, 16, 44>(tile, f1, fT, n, y, 0, 2162688, t);
    } else if (b < 528) {     // feat l2: 6 * 8
        int r = b - 480, n = r >> 3, y = r & 7;
        ft_tile<22, 8, 22>(tile, f2, fT, n, y, 0, 2703360, t);
    } else if (b < 552) {     // feat l3: 6 * 4
        int r = b - 528, n = r >> 2, y = r & 3;
        ft_tile<11, 4, 11>(tile, f3, fT, n, y, 0, 2838528, t);
    } else if (b < 2600) {
        int i = (b - 552) * 256 + t; Wb1[i] = __float2bfloat16(mid_w1[i]);
    } else if (b < 3624) {
        int i = (b - 2600) * 256 + t; Wb2[i] = __float2bfloat16(mid_w2[i]);
    } else if (b < 3880) {
        int i = (b - 3624) * 256 + t; Wb3[i] = __float2bfloat16(mid_w3[i]);
    } else if (b < 4008) {
        int n = b - 3880; Wpe[n * 256 + t] = __float2bfloat16(pe_w2[t * 128 + n]);
    } else if (b < 4072) {    // packed offsw weight: 64 rows (24 off + 32 sw + 8 zero)
        int n = b - 4008;
        if (t < 128) {
            float w = 0.f;
            if (n < 24)      w = off_w[n * 128 + t];
            else if (n < 56) w = sw_w[(n - 24) * 128 + t];
            Wof[n * 128 + t] = __float2bfloat16(w);
            if (t == 0) Bof[n] = (n < 24) ? off_b[n] : ((n < 56) ? sw_b[n - 24] : 0.f);
        }
    } else if (b < 4200) {
        int o = b - 4072;
        for (int idx = t; idx < 1152; idx += 256) {
            int s = idx >> 7, i = idx & 127;
            Wcv1[o * 1152 + idx] = __float2bfloat16(in_w[(o * 128 + i) * 9 + s]);
        }
    } else if (b < 4328) {
        int o = b - 4200;
        for (int idx = t; idx < 1152; idx += 256) {
            int s = idx >> 7, i = idx & 127;
            Wcv2[o * 1152 + idx] = __float2bfloat16(out_w[(o * 128 + i) * 9 + s]);
        }
    } else if (b < 4361) {    // qT border zero: 516 border pixels x 16 uint4
        int g = (b - 4328) * 256 + t;
        if (g < 8256) {
            int pixi = g >> 4, part = g & 15;
            int row, col;
            if (pixi < 130)      { row = 0;   col = pixi; }
            else if (pixi < 260) { row = 129; col = pixi - 130; }
            else {
                int r = pixi - 260;
                row = 1 + (r & 127);
                col = (r < 128) ? 0 : 129;
            }
            uint4 z = {0u, 0u, 0u, 0u};
            *(uint4*)&qTo[((size_t)row * 130 + col) * 128 + part * 8] = z;
        }
    } else if (b < 4362) {    // stats zero: 768 floats
        Stats[t] = 0.f; Stats[256 + t] = 0.f; Stats[512 + t] = 0.f;
    } else {                  // bev_query CHW -> padded HWC bf16 interior (256 blocks)
        int rel = b - 4362;
        int y = rel >> 1, x0 = (rel & 1) * 64;
        int xi = t & 63, c0 = t >> 6;
        for (int c = c0; c < 128; c += 4)
            tile[c * 65 + xi] = bev_query[c * HW + y * 128 + x0 + xi];
        __syncthreads();
        int xp = t >> 2, cg = (t & 3) * 32;
        __hip_bfloat16* dst = qTo + ((size_t)(y + 1) * 130 + (x0 + 1 + xp)) * 128;
        #pragma unroll
        for (int g = 0; g < 4; g++) {
            int c = cg + g * 8;
            union { __hip_bfloat16 h[8]; uint4 u; } pk;
            #pragma unroll
            for (int j = 0; j < 8; j++)
                pk.h[j] = __float2bfloat16(tile[(c + j) * 65 + xp]);
            *(uint4*)&dst[c] = pk.u;
        }
    }
}

// ---------------- CHW fp32 [128][128^2] -> padded HWC bf16 [130][130][128] (interior) ----------------
// stats (optional): per-channel {sum, sumsq}; applies instance-norm while packing.
__global__ __launch_bounds__(256) void chw2hwc_pad_k(
    const float* __restrict__ q, const float* __restrict__ stats,
    __hip_bfloat16* __restrict__ out)
{
    __shared__ float tile[128][65];
    __shared__ float sm[128], sr[128];
    int t = threadIdx.x;
    if (t < 128) {
        if (stats) {
            float s = stats[2 * t], s2 = stats[2 * t + 1];
            float mean = s * (1.0f / HW);
            sm[t] = mean;
            sr[t] = rsqrtf(s2 * (1.0f / HW) - mean * mean + 1e-5f);
        } else {
            sm[t] = 0.f; sr[t] = 1.f;
        }
    }
    int b = blockIdx.x;            // 256 blocks: y = b>>1, x0 = (b&1)*64
    int y = b >> 1, x0 = (b & 1) * 64;
    int xi = t & 63, c0 = t >> 6;
    for (int c = c0; c < 128; c += 4)
        tile[c][xi] = q[c * HW + y * 128 + x0 + xi];
    __syncthreads();
    int xp = t >> 2, cg = (t & 3) * 32;
    __hip_bfloat16* dst = out + ((size_t)(y + 1) * 130 + (x0 + 1 + xp)) * 128;
    #pragma unroll
    for (int g = 0; g < 4; g++) {
        int c = cg + g * 8;
        union { __hip_bfloat16 h[8]; uint4 u; } pk;
        #pragma unroll
        for (int j = 0; j < 8; j++)
            pk.h[j] = __float2bfloat16((tile[c + j][xp] - sm[c + j]) * sr[c + j]);
        *(uint4*)&dst[c] = pk.u;
    }
}

// ---------------- bf16 MFMA GEMM: out[m][n] = act(bias[n] + sum_k X[m][k] W[n][k]) ----------------
// OUTT: 0 -> bf16 [M][N]; 1 -> fp32 [N][M] (CHW, + optional residual res[n][m]).
// CONV: X is padded HWC bf16 [130][130][128]; k = s*128+c.
// rstats: normalize residual with {sum,sumsq}; ostats: accumulate output {sum,sumsq} (OUTT==1 only).
// K-loop: NBUF-deep LDS pipeline with counted vmcnt (never 0 in steady state) + raw s_barrier.
// LDS XOR-swizzle (both-sides): global source chunk permuted on stage, ds_read slot permuted to match.
template<int BM, int BN, int ACT, int OUTT, int CONV>
__global__ __launch_bounds__(256) void bgemm_k(
    const __hip_bfloat16* __restrict__ X, const __hip_bfloat16* __restrict__ W,
    const float* __restrict__ bias, void* __restrict__ outp,
    const float* __restrict__ res,
    const float* __restrict__ rstats, float* __restrict__ ostats,
    int M, int K, int N)
{
    constexpr int ROWS = BM + BN;
    constexpr int ITERS = (ROWS * 4) / 256;       // global_load_lds per lane per stage
    constexpr int BUFE  = ROWS * 32;              // bf16 elements per buffer
    constexpr int NBUF  = (ITERS == 2) ? 4 : 3;   // 32 KB / 48 KB LDS
    __shared__ __align__(16) __hip_bfloat16 SH[NBUF * BUFE];
    int t = threadIdx.x;
    int w = t >> 6, lane = t & 63;
    int mb = blockIdx.y * BM, nb = blockIdx.x * BN;
    int cy = mb >> 7, cx = mb & 127;   // conv tile coords (CONV only)
    constexpr int WM = BM / 2;
    constexpr int MI = WM / 16;
    constexpr int NJ = BN / 32;
    int wm = (w & 1) * WM, wn = (w >> 1) * (BN / 2);
    int lm = lane & 15, lq = lane >> 4;
    int sl = (lq ^ ((lm >> 1) & 3)) * 8;          // swizzled k-slot for ds_read
    floatx4 zero = {0.f, 0.f, 0.f, 0.f};
    floatx4 acc[MI][NJ];
    #pragma unroll
    for (int i = 0; i < MI; i++)
        #pragma unroll
        for (int j = 0; j < NJ; j++) acc[i][j] = zero;

    const int nsteps = K >> 5;

    auto STAGE = [&](int bufi, int tk2) {
        int kb_ = tk2 * 32;
        int s_ = kb_ >> 7;
        int dyi_ = s_ / 3, dxi_ = s_ - dyi_ * 3;   // tap indices (CONV only)
        #pragma unroll
        for (int it = 0; it < ITERS; it++) {
            int chunk = it * 256 + t;
            int row = chunk >> 2;
            int ko = ((chunk & 3) ^ ((row >> 1) & 3)) * 8;   // source-side swizzle
            const __hip_bfloat16* src;
            if (row < BM) {
                if (CONV)
                    src = X + (((size_t)(cy + dyi_) * 130) + (cx + dxi_ + row)) * 128 + (kb_ & 127) + ko;
                else
                    src = X + (size_t)(mb + row) * K + kb_ + ko;
            } else {
                src = W + (size_t)(nb + row - BM) * K + kb_ + ko;
            }
            __builtin_amdgcn_global_load_lds(
                (const __attribute__((address_space(1))) void*)src,
                (__attribute__((address_space(3))) void*)&SH[bufi * BUFE + (it * 256 + (t & ~63)) * 8],
                16, 0, 0);
        }
    };

    #pragma unroll
    for (int pi = 0; pi < NBUF - 1; pi++)
        if (pi < nsteps) STAGE(pi, pi);

    for (int tk = 0; tk < nsteps; ++tk) {
        int rem = nsteps - 1 - tk;
        if constexpr (ITERS == 2) {                // NBUF=4: up to 2 stages beyond current
            if (rem >= 2)      asm volatile("s_waitcnt vmcnt(4)" ::: "memory");
            else if (rem == 1) asm volatile("s_waitcnt vmcnt(2)" ::: "memory");
            else               asm volatile("s_waitcnt vmcnt(0)" ::: "memory");
        } else {                                   // NBUF=3: up to 1 stage beyond current
            if (rem >= 1)      asm volatile("s_waitcnt vmcnt(4)" ::: "memory");
            else               asm volatile("s_waitcnt vmcnt(0)" ::: "memory");
        }
        __builtin_amdgcn_s_barrier();
        int tkn = tk + NBUF - 1;
        if (tkn < nsteps) STAGE(tkn % NBUF, tkn);

        const __hip_bfloat16* As = SH + (tk % NBUF) * BUFE;
        const __hip_bfloat16* Bs = As + BM * 32;
        short8 af[MI], bf[NJ];
        #pragma unroll
        for (int i = 0; i < MI; i++)
            af[i] = *(const short8*)&As[(wm + i * 16 + lm) * 32 + sl];
        #pragma unroll
        for (int j = 0; j < NJ; j++)
            bf[j] = *(const short8*)&Bs[(wn + j * 16 + lm) * 32 + sl];
        #pragma unroll
        for (int i = 0; i < MI; i++)
            #pragma unroll
            for (int j = 0; j < NJ; j++)
                acc[i][j] = __builtin_amdgcn_mfma_f32_16x16x32_bf16(af[i], bf[j], acc[i][j], 0, 0, 0);
    }

    float invM = 1.0f / (float)M;
    #pragma unroll
    for (int j = 0; j < NJ; j++) {
        int n = nb + wn + j * 16 + lm;
        float bv = bias[n];
        float rmean = 0.f, rrstd = 0.f;
        if (OUTT == 1 && res && rstats) {
            float s = rstats[2 * n], s2 = rstats[2 * n + 1];
            rmean = s * invM;
            rrstd = rsqrtf(s2 * invM - rmean * rmean + 1e-5f);
        }
        float ss = 0.f, ss2 = 0.f;
        #pragma unroll
        for (int i = 0; i < MI; i++) {
            #pragma unroll
            for (int r = 0; r < 4; r++) {
                int m = mb + wm + i * 16 + lq * 4 + r;
                float v = acc[i][j][r] + bv;
                if (ACT) v = gelu_exact(v);
                if (OUTT == 0) {
                    ((__hip_bfloat16*)outp)[(size_t)m * N + n] = __float2bfloat16(v);
                } else {
                    if (res) {
                        float rv = res[(size_t)n * M + m];
                        v += rstats ? (rv - rmean) * rrstd : rv;
                    }
                    ((float*)outp)[(size_t)n * M + m] = v;
                    ss += v; ss2 += v * v;
                }
            }
        }
        if (OUTT == 1 && ostats) {
            ss  += __shfl_xor(ss, 16);  ss  += __shfl_xor(ss, 32);
            ss2 += __shfl_xor(ss2, 16); ss2 += __shfl_xor(ss2, 32);
            if (lq == 0) {
                atomicAdd(&ostats[2 * n], ss);
                atomicAdd(&ostats[2 * n + 1], ss2);
            }
        }
    }
}

// ---------------- fused offsets/sample-weights GEMM + epilogue ----------------
// BM=BN=64, K=128, CONV-style X addressing (center tap of padded normalized q0).
// Block (1D grid, 256 blocks) holds ALL 64 channels for its 64 pixels, so the
// offpost math (sigmoid->pts/height, 4-way softmax->swn) runs in-register.
// Softmax group (l = n&3) = 4 adjacent lanes -> shfl_xor(1)+shfl_xor(2).
__global__ __launch_bounds__(256) void offgemm_k(
    const __hip_bfloat16* __restrict__ X, const __hip_bfloat16* __restrict__ W,
    const float* __restrict__ bias, const float* __restrict__ bev_pos,
    float* __restrict__ pts, float* __restrict__ swn, float* __restrict__ height_out)
{
    constexpr int BUFE = 128 * 32;
    __shared__ __align__(16) __hip_bfloat16 SH[4 * BUFE];
    int t = threadIdx.x;
    int w = t >> 6, lane = t & 63;
    int mb = blockIdx.x * 64;
    int cy = mb >> 7, cx = mb & 127;
    int wm = (w & 1) * 32, wn = (w >> 1) * 32;
    int lm = lane & 15, lq = lane >> 4;
    int sl = (lq ^ ((lm >> 1) & 3)) * 8;
    floatx4 zero = {0.f, 0.f, 0.f, 0.f};
    floatx4 acc[2][2];
    acc[0][0] = zero; acc[0][1] = zero; acc[1][0] = zero; acc[1][1] = zero;

    auto STAGE = [&](int bufi, int tk2) {
        int kb_ = tk2 * 32;
        #pragma unroll
        for (int it = 0; it < 2; it++) {
            int chunk = it * 256 + t;
            int row = chunk >> 2;
            int ko = ((chunk & 3) ^ ((row >> 1) & 3)) * 8;
            const __hip_bfloat16* src;
            if (row < 64) src = X + ((size_t)cy * 130 + cx + row) * 128 + kb_ + ko;
            else          src = W + (size_t)(row - 64) * 128 + kb_ + ko;
            __builtin_amdgcn_global_load_lds(
                (const __attribute__((address_space(1))) void*)src,
                (__attribute__((address_space(3))) void*)&SH[bufi * BUFE + (it * 256 + (t & ~63)) * 8],
                16, 0, 0);
        }
    };

    STAGE(0, 0); STAGE(1, 1); STAGE(2, 2);
    for (int tk = 0; tk < 4; ++tk) {
        int rem = 3 - tk;
        if (rem >= 2)      asm volatile("s_waitcnt vmcnt(4)" ::: "memory");
        else if (rem == 1) asm volatile("s_waitcnt vmcnt(2)" ::: "memory");
        else               asm volatile("s_waitcnt vmcnt(0)" ::: "memory");
        __builtin_amdgcn_s_barrier();
        if (tk + 3 < 4) STAGE((tk + 3) & 3, tk + 3);
        const __hip_bfloat16* As = SH + (tk & 3) * BUFE;
        const __hip_bfloat16* Bs = As + 64 * 32;
        short8 af[2], bf[2];
        #pragma unroll
        for (int i = 0; i < 2; i++)
            af[i] = *(const short8*)&As[(wm + i * 16 + lm) * 32 + sl];
        #pragma unroll
        for (int j = 0; j < 2; j++)
            bf[j] = *(const short8*)&Bs[(wn + j * 16 + lm) * 32 + sl];
        #pragma unroll
        for (int i = 0; i < 2; i++)
            #pragma unroll
            for (int j = 0; j < 2; j++)
                acc[i][j] = __builtin_amdgcn_mfma_f32_16x16x32_bf16(af[i], bf[j], acc[i][j], 0, 0, 0);
    }

    const float rngv[3]  = {100.f, 100.f, 8.f};
    const float pcm[3]   = {-50.f, -50.f, -4.f};
    #pragma unroll
    for (int j = 0; j < 2; j++) {
        int n = wn + j * 16 + lm;
        float bv = bias[n];
        int p3 = n / 3, d3 = n - p3 * 3;                 // off path (n<24)
        float lim = (d3 == 2) ? (4.0f + 1e-6f) : (0.25f + 1e-6f);
        #pragma unroll
        for (int i = 0; i < 2; i++) {
            #pragma unroll
            for (int r = 0; r < 4; r++) {
                int m = mb + wm + i * 16 + lq * 4 + r;
                float v = acc[i][j][r] + bv;
                // softmax over 4-lane groups, executed by all lanes (writes predicated)
                float mm = fmaxf(v, __shfl_xor(v, 1));
                mm = fmaxf(mm, __shfl_xor(mm, 2));
                float e = expf(v - mm);
                float s = e + __shfl_xor(e, 1);
                s += __shfl_xor(s, 2);
                if (n < 24) {
                    float sv = 1.f / (1.f + expf(-v));
                    float offv = sv * 2.f * lim - lim;
                    float refv = bev_pos[m * 3 + d3] * rngv[d3] + pcm[d3];
                    pts[m * 24 + n] = refv + offv;
                    if (d3 == 2) height_out[p3 * HW + m] = offv;
                } else if (n < 56) {
                    swn[m * 32 + (n - 24)] = e / s;
                }
            }
        }
    }
}

// ---------------- fused PE: hidden = relu(rn @ w1 + b1) on the fly, GEMM vs Wpe ----------------
__global__ __launch_bounds__(256) void pe_bgemm_k(
    const float* __restrict__ pts, const float* __restrict__ pe_w1,
    const float* __restrict__ pe_b1, const __hip_bfloat16* __restrict__ W,
    const float* __restrict__ bias, __hip_bfloat16* __restrict__ out)
{
    __shared__ __align__(16) __hip_bfloat16 As[128 * 32];
    __shared__ __align__(16) __hip_bfloat16 Bs[128 * 32];
    __shared__ __align__(16) float wps[4][256];   // [b1, w1_x, w1_y, w1_z][256]
    int t = threadIdx.x;
    int w = t >> 6, lane = t & 63;
    int mb = blockIdx.x * 128;
    {
        int d = t >> 6, c = (t & 63) * 4;
        float4 v;
        if (d == 0) v = *(const float4*)&pe_b1[c];
        else        v = *(const float4*)&pe_w1[(d - 1) * 256 + c];
        *(float4*)&wps[d][c] = v;
    }
    int cg = t & 3;
    int r0 = t >> 2;
    float rn[2][3];
    #pragma unroll
    for (int h = 0; h < 2; h++) {
        int r = mb + r0 + h * 64;
        rn[h][0] = (pts[(size_t)r * 3 + 0] + 50.f) * 0.01f;
        rn[h][1] = (pts[(size_t)r * 3 + 1] + 50.f) * 0.01f;
        rn[h][2] = (pts[(size_t)r * 3 + 2] + 4.f) * 0.125f;
    }
    int wm = (w & 1) * 64, wn = (w >> 1) * 64;
    int lm = lane & 15, lq = lane >> 4;
    floatx4 zero = {0.f, 0.f, 0.f, 0.f};
    floatx4 acc[4][4];
    #pragma unroll
    for (int i = 0; i < 4; i++)
        #pragma unroll
        for (int j = 0; j < 4; j++) acc[i][j] = zero;
    for (int kb = 0; kb < 256; kb += 32) {
        __syncthreads();
        #pragma unroll
        for (int it = 0; it < 2; it++) {
            int chunk = it * 256 + t;
            int brow = chunk >> 2, ko = (chunk & 3) * 8;
            const __hip_bfloat16* src = W + (size_t)brow * 256 + kb + ko;
            __builtin_amdgcn_global_load_lds(
                (const __attribute__((address_space(1))) void*)src,
                (__attribute__((address_space(3))) void*)&Bs[(size_t)(it * 256 + (t & ~63)) * 8],
                16, 0, 0);
        }
        int c0 = kb + cg * 8;
        float4 bva = *(const float4*)&wps[0][c0], bvb = *(const float4*)&wps[0][c0 + 4];
        float4 wxa = *(const float4*)&wps[1][c0], wxb = *(const float4*)&wps[1][c0 + 4];
        float4 wya = *(const float4*)&wps[2][c0], wyb = *(const float4*)&wps[2][c0 + 4];
        float4 wza = *(const float4*)&wps[3][c0], wzb = *(const float4*)&wps[3][c0 + 4];
        #pragma unroll
        for (int h = 0; h < 2; h++) {
            const float* bv = (const float*)&bva;
            const float* wx = (const float*)&wxa;
            const float* wy = (const float*)&wya;
            const float* wz = (const float*)&wza;
            union { __hip_bfloat16 hh[8]; uint4 u; } pk;
            #pragma unroll
            for (int j = 0; j < 4; j++) {
                float v = bv[j] + rn[h][0] * wx[j] + rn[h][1] * wy[j] + rn[h][2] * wz[j];
                pk.hh[j] = __float2bfloat16(fmaxf(v, 0.f));
            }
            bv = (const float*)&bvb; wx = (const float*)&wxb;
            wy = (const float*)&wyb; wz = (const float*)&wzb;
            #pragma unroll
            for (int j = 0; j < 4; j++) {
                float v = bv[j] + rn[h][0] * wx[j] + rn[h][1] * wy[j] + rn[h][2] * wz[j];
                pk.hh[4 + j] = __float2bfloat16(fmaxf(v, 0.f));
            }
            *(uint4*)&As[(r0 + h * 64) * 32 + cg * 8] = pk.u;
        }
        __syncthreads();
        short8 af[4], bf[4];
        #pragma unroll
        for (int i = 0; i < 4; i++)
            af[i] = *(const short8*)&As[(wm + i * 16 + lm) * 32 + lq * 8];
        #pragma unroll
        for (int j = 0; j < 4; j++)
            bf[j] = *(const short8*)&Bs[(wn + j * 16 + lm) * 32 + lq * 8];
        #pragma unroll
        for (int i = 0; i < 4; i++)
            #pragma unroll
            for (int j = 0; j < 4; j++)
                acc[i][j] = __builtin_amdgcn_mfma_f32_16x16x32_bf16(af[i], bf[j], acc[i][j], 0, 0, 0);
    }
    #pragma unroll
    for (int i = 0; i < 4; i++) {
        #pragma unroll
        for (int j = 0; j < 4; j++) {
            int n = wn + j * 16 + lm;
            float bv = bias[n];
            #pragma unroll
            for (int r = 0; r < 4; r++) {
                int m = mb + wm + i * 16 + lq * 4 + r;
                out[(size_t)m * 128 + n] = __float2bfloat16(acc[i][j][r] + bv);
            }
        }
    }
}

// ---------------- final instance norm apply (stats precomputed in producer epilogue) ----------------
__global__ __launch_bounds__(256) void inorm_apply_k(
    const float* __restrict__ in, const float* __restrict__ stats, float* __restrict__ out)
{
    int b = blockIdx.x;           // 1024 blocks: c = b>>3, seg = b&7 (2048 floats each)
    int c = b >> 3, seg = b & 7;
    float s = stats[2 * c], s2 = stats[2 * c + 1];
    float mean = s * (1.0f / HW);
    float rstd = rsqrtf(s2 * (1.0f / HW) - mean * mean + 1e-5f);
    const float4* pi = (const float4*)(in + (size_t)c * HW + seg * 2048);
    float4*       po = (float4*)(out + (size_t)c * HW + seg * 2048);
    int t = threadIdx.x;
    #pragma unroll
    for (int k = 0; k < 2; k++) {
        float4 v = pi[t + k * 256];
        v.x = (v.x - mean) * rstd; v.y = (v.y - mean) * rstd;
        v.z = (v.z - mean) * rstd; v.w = (v.w - mean) * rstd;
        po[t + k * 256] = v;
    }
}

// ---------------- sampling: phase-1 projection + cull, phase-2 bf16 packed gather ----------------
// 256 threads = 4 waves; wave wv owns p = wv*2 + {0,1}; offsets stored as BYTE offsets;
// main loop processes 2 taps/iter with split accumulators (8 loads in flight).
__global__ __launch_bounds__(256) void sample_k(
    const __hip_bfloat16* __restrict__ featT, const float* __restrict__ pts,
    const float* __restrict__ swn,   const float* __restrict__ l2i,
    __hip_bfloat16* __restrict__ sf)
{
    int pix = blockIdx.x;
    int t = threadIdx.x;
    int lane = t & 63, wv = t >> 6;
    __shared__ float pts_s[24];
    __shared__ float swl_s[32];
    __shared__ float M[96];
    __shared__ __align__(16) int   offs[8][24][4];   // byte offsets into featT
    __shared__ __align__(16) float wts[8][24][4];
    __shared__ int cnt[8];
    if (t < 96) M[t] = l2i[t];
    if (t < 24) pts_s[t] = pts[pix * 24 + t];
    if (t < 32) swl_s[t] = swn[pix * 32 + t];
    if (t < 8)  cnt[t] = 0;
    __syncthreads();

    floatx2 acc[2];
    #pragma unroll
    for (int i = 0; i < 2; i++) {
        unsigned int u = *(const unsigned int*)&sf[(size_t)pix * 1024 + (wv * 2 + i) * 128 + 2 * lane];
        acc[i] = bf2x(u);
    }

    const int lHt[4] = {32, 16, 8, 4}, lWt[4] = {88, 44, 22, 11};
    const int loff[4] = {0, 2162688, 2703360, 2838528};
    if (t < 192) {
        int p = t / 24;
        int rr = t - p * 24;
        int n = rr >> 2, l = rr & 3;
        float X = pts_s[p * 3], Y = pts_s[p * 3 + 1], Z = pts_s[p * 3 + 2];
        const float* Mn = &M[n * 16];
        float zc = Mn[8] * X + Mn[9] * Y + Mn[10] * Z + Mn[11];
        if (zc > 1e-5f) {
            float inv = 1.f / zc;
            float xn = (Mn[0] * X + Mn[1] * Y + Mn[2] * Z + Mn[3]) * inv * (1.f / 704.f);
            float yn = (Mn[4] * X + Mn[5] * Y + Mn[6] * Z + Mn[7]) * inv * (1.f / 256.f);
            int Wl = lWt[l], Hl = lHt[l];
            float px = xn * Wl - 0.5f, py = yn * Hl - 0.5f;
            px = fminf(fmaxf(px, -2.f), (float)(Wl + 1));
            py = fminf(fmaxf(py, -2.f), (float)(Hl + 1));
            float x0f = floorf(px), y0f = floorf(py);
            float wx = px - x0f, wy = py - y0f;
            int x0 = (int)x0f, y0 = (int)y0f;
            bool xi0 = (unsigned)x0 < (unsigned)Wl, xi1 = (unsigned)(x0 + 1) < (unsigned)Wl;
            bool yi0 = (unsigned)y0 < (unsigned)Hl, yi1 = (unsigned)(y0 + 1) < (unsigned)Hl;
            if ((xi0 || xi1) && (yi0 || yi1)) {
                float wl = swl_s[p * 4 + l];
                float w00 = wl * (1.f - wx) * (1.f - wy) * (float)(xi0 && yi0);
                float w10 = wl * wx * (1.f - wy)         * (float)(xi1 && yi0);
                float w01 = wl * (1.f - wx) * wy         * (float)(xi0 && yi1);
                float w11 = wl * wx * wy                 * (float)(xi1 && yi1);
                int x0c = min(max(x0, 0), Wl - 1), x1c = min(max(x0 + 1, 0), Wl - 1);
                int y0c = min(max(y0, 0), Hl - 1), y1c = min(max(y0 + 1, 0), Hl - 1);
                int base = loff[l] + n * Hl * Wl * 128;
                int idx = atomicAdd(&cnt[p], 1);
                offs[p][idx][0] = (base + (y0c * Wl + x0c) * 128) * 2;
                offs[p][idx][1] = (base + (y0c * Wl + x1c) * 128) * 2;
                offs[p][idx][2] = (base + (y1c * Wl + x0c) * 128) * 2;
                offs[p][idx][3] = (base + (y1c * Wl + x1c) * 128) * 2;
                wts[p][idx][0] = w00; wts[p][idx][1] = w10;
                wts[p][idx][2] = w01; wts[p][idx][3] = w11;
            }
        }
    }
    __syncthreads();

    const char* fbase = (const char*)featT;
    int lane4 = lane * 4;
    #pragma unroll
    for (int i = 0; i < 2; i++) {
        int p = wv * 2 + i;
        int np = cnt[p];
        floatx2 a0 = acc[i];
        floatx2 a1 = {0.f, 0.f};
        int j = 0;
        #pragma unroll 1
        for (; j + 2 <= np; j += 2) {
            int4   oA = *(const int4*)&offs[p][j][0];
            float4 wA = *(const float4*)&wts[p][j][0];
            int4   oB = *(const int4*)&offs[p][j + 1][0];
            float4 wB = *(const float4*)&wts[p][j + 1][0];
            unsigned int v0 = *(const unsigned int*)(fbase + (unsigned)(oA.x + lane4));
            unsigned int v1 = *(const unsigned int*)(fbase + (unsigned)(oA.y + lane4));
            unsigned int v2 = *(const unsigned int*)(fbase + (unsigned)(oA.z + lane4));
            unsigned int v3 = *(const unsigned int*)(fbase + (unsigned)(oA.w + lane4));
            unsigned int v4 = *(const unsigned int*)(fbase + (unsigned)(oB.x + lane4));
            unsigned int v5 = *(const unsigned int*)(fbase + (unsigned)(oB.y + lane4));
            unsigned int v6 = *(const unsigned int*)(fbase + (unsigned)(oB.z + lane4));
            unsigned int v7 = *(const unsigned int*)(fbase + (unsigned)(oB.w + lane4));
            a0 += bf2x(v0) * wA.x;
            a0 += bf2x(v1) * wA.y;
            a0 += bf2x(v2) * wA.z;
            a0 += bf2x(v3) * wA.w;
            a1 += bf2x(v4) * wB.x;
            a1 += bf2x(v5) * wB.y;
            a1 += bf2x(v6) * wB.z;
            a1 += bf2x(v7) * wB.w;
        }
        if (j < np) {
            int4   o = *(const int4*)&offs[p][j][0];
            float4 w = *(const float4*)&wts[p][j][0];
            unsigned int v0 = *(const unsigned int*)(fbase + (unsigned)(o.x + lane4));
            unsigned int v1 = *(const unsigned int*)(fbase + (unsigned)(o.y + lane4));
            unsigned int v2 = *(const unsigned int*)(fbase + (unsigned)(o.z + lane4));
            unsigned int v3 = *(const unsigned int*)(fbase + (unsigned)(o.w + lane4));
            a0 += bf2x(v0) * w.x;
            a0 += bf2x(v1) * w.y;
            a0 += bf2x(v2) * w.z;
            a0 += bf2x(v3) * w.w;
        }
        acc[i] = a0 + a1;
    }
    #pragma unroll
    for (int i = 0; i < 2; i++) {
        union { __hip_bfloat16 h[2]; unsigned int u; } pk;
        pk.h[0] = __float2bfloat16(acc[i].x);
        pk.h[1] = __float2bfloat16(acc[i].y);
        *(unsigned int*)&sf[(size_t)pix * 1024 + (wv * 2 + i) * 128 + 2 * lane] = pk.u;
    }
}

extern "C" void kernel_launch(void* const* d_in, const int* in_sizes, int n_in,
                              void* d_out, int out_size, void* d_ws, size_t ws_size,
                              hipStream_t stream)
{
    const float* feat[4] = {(const float*)d_in[0], (const float*)d_in[1],
                            (const float*)d_in[2], (const float*)d_in[3]};
    const float* l2i       = (const float*)d_in[4];
    const float* bev_query = (const float*)d_in[5];
    const float* bev_pos   = (const float*)d_in[6];
    const float* in_w  = (const float*)d_in[7];  const float* in_b  = (const float*)d_in[8];
    const float* off_w = (const float*)d_in[9];  const float* off_b = (const float*)d_in[10];
    const float* sw_w  = (const float*)d_in[11]; const float* sw_b  = (const float*)d_in[12];
    const float* pe_w1 = (const float*)d_in[13]; const float* pe_b1 = (const float*)d_in[14];
    const float* pe_w2 = (const float*)d_in[15]; const float* pe_b2 = (const float*)d_in[16];
    const float* mid_w1 = (const float*)d_in[17]; const float* mid_b1 = (const float*)d_in[18];
    const float* mid_w2 = (const float*)d_in[19]; const float* mid_b2 = (const float*)d_in[20];
    const float* mid_w3 = (const float*)d_in[21]; const float* mid_b3 = (const float*)d_in[22];
    const float* out_w  = (const float*)d_in[23]; const float* out_b  = (const float*)d_in[24];

    float* ws = (float*)d_ws;
    float* fTf = ws;                    // 1,436,160 : transposed feats bf16
    __hip_bfloat16* fT = (__hip_bfloat16*)fTf;
    float* Bb  = fTf + 1436160;         // 2,097,152 : q1 raw (CHW)
    float* Cb  = Bb + 2097152;          // 2,097,152 : q0 raw (conv1 out, CHW)
    float* Gb  = Cb + 2097152;          // 2,097,152 : conv2 raw (CHW)
    float* Dp  = Gb + 2097152;          //   393,216 : pts
    float* Eb  = Dp + 393216;           //   524,288 : swn
    float* QTf = Eb + 524288;           // 1,081,600 : padded HWC bf16 (130*130*128)
    __hip_bfloat16* qT = (__hip_bfloat16*)QTf;
    float* SFf = QTf + 1081600;         // 8,388,608 : sf bf16 131072x128
    __hip_bfloat16* sfb = (__hip_bfloat16*)SFf;
    float* M1f = SFf + 8388608;         // 4,194,304 : m1 bf16
    __hip_bfloat16* m1b = (__hip_bfloat16*)M1f;
    float* M2f = M1f + 4194304;         // 4,194,304 : m2 bf16
    __hip_bfloat16* m2b = (__hip_bfloat16*)M2f;
    float* WC1 = M2f + 4194304;         //    73,728 : conv1 weights bf16
    __hip_bfloat16* Wcv1 = (__hip_bfloat16*)WC1;
    float* WC2 = WC1 + 73728;           //    73,728 : conv2 weights bf16
    __hip_bfloat16* Wcv2 = (__hip_bfloat16*)WC2;
    float* W1f = WC2 + 73728;           //   262,144
    __hip_bfloat16* Wb1 = (__hip_bfloat16*)W1f;
    float* W2f = W1f + 262144;          //   131,072
    __hip_bfloat16* Wb2 = (__hip_bfloat16*)W2f;
    float* W3f = W2f + 131072;          //    32,768
    __hip_bfloat16* Wb3 = (__hip_bfloat16*)W3f;
    float* WPf = W3f + 32768;           //    16,384 : pe_w2^T bf16
    __hip_bfloat16* Wpe = (__hip_bfloat16*)WPf;
    float* WOf = WPf + 16384;           //     8,192 : offsw packed weight bf16 (64x128 used)
    __hip_bfloat16* Wof = (__hip_bfloat16*)WOf;
    float* Bof = WOf + 8192;            //       128 : offsw packed bias fp32 (64 used)
    float* Stats = Bof + 128;           //       768 : 3 x 128 x {sum,sumsq}
    float* stats1 = Stats;
    float* stats2 = Stats + 256;
    float* stats3 = Stats + 512;

    float* q_out = (float*)d_out;
    float* h_out = q_out + 2097152;

    // setup: feat transpose + weight prep + qT border zero + stats zero + bev_query pad
    setup_k<<<4618, 256, 0, stream>>>(feat[0], feat[1], feat[2], feat[3], fT,
                                      mid_w1, mid_w2, mid_w3, pe_w2, off_w, off_b, sw_w, sw_b,
                                      in_w, out_w, bev_query,
                                      Wb1, Wb2, Wb3, Wpe, Wof, Bof, Wcv1, Wcv2,
                                      qT, Stats);

    // conv1: q0raw = bev_query + conv3x3(bev_query) -> Cb, stats1 accumulated in epilogue
    bgemm_k<64, 64, 0, 1, 1><<<dim3(2, 256), 256, 0, stream>>>(
        qT, Wcv1, in_b, Cb, bev_query, nullptr, stats1, HW, 1152, 128);

    // offsets/sample-weights: normalized-q0 pack, then fused GEMM+epilogue -> pts/swn/height
    chw2hwc_pad_k<<<256, 256, 0, stream>>>(Cb, stats1, qT);   // applies inorm(q0raw)
    offgemm_k<<<256, 256, 0, stream>>>(qT + 131 * 128, Wof, Bof, bev_pos, Dp, Eb, h_out);

    // fused PE (hidden on the fly + MFMA GEMM) -> sf
    pe_bgemm_k<<<1024, 256, 0, stream>>>(Dp, pe_w1, pe_b1, Wpe, pe_b2, sfb);

    // sampling accumulates taps onto sf
    sample_k<<<HW, 256, 0, stream>>>(fT, Dp, Eb, l2i, sfb);

    // mid MLP: 1024 -> 512 gelu -> 512 gelu -> 128 linear (+ normalized q0 residual)
    bgemm_k<128, 128, 1, 0, 0><<<dim3(4, 128), 256, 0, stream>>>(
        sfb, Wb1, mid_b1, m1b, nullptr, nullptr, nullptr, HW, 1024, 512);
    bgemm_k<128, 128, 1, 0, 0><<<dim3(4, 128), 256, 0, stream>>>(
        m1b, Wb2, mid_b2, m2b, nullptr, nullptr, nullptr, HW, 512, 512);
    bgemm_k<64, 64, 0, 1, 0><<<dim3(2, 256), 256, 0, stream>>>(
        m2b, Wb3, mid_b3, Bb, Cb, stats1, stats2, HW, 512, 128);   // q1raw -> Bb, stats2

    // conv2: q = inorm(q1n + conv3x3(q1n)); q1n applied on the fly from stats2
    chw2hwc_pad_k<<<256, 256, 0, stream>>>(Bb, stats2, qT);
    bgemm_k<64, 64, 0, 1, 1><<<dim3(2, 256), 256, 0, stream>>>(
        qT, Wcv2, out_b, Gb, Bb, stats2, stats3, HW, 1152, 128);   // conv2 raw -> Gb, stats3
    inorm_apply_k<<<1024, 256, 0, stream>>>(Gb, stats3, q_out);
}

// Round 9
// 368.710 us; speedup vs baseline: 1.0956x; 1.0175x over previous
//
#include <hip/hip_runtime.h>
#include <hip/hip_bf16.h>
#include <math.h>

#define HW 16384   // 128*128 bev pixels

typedef __attribute__((ext_vector_type(8))) short short8;
typedef __attribute__((ext_vector_type(4))) float floatx4;
typedef __attribute__((ext_vector_type(2))) float floatx2;

__device__ __forceinline__ float gelu_exact(float x){
    return 0.5f * x * (1.0f + erff(x * 0.7071067811865475f));
}

__device__ __forceinline__ floatx2 bf2x(unsigned int u){
    floatx2 r;
    r.x = __uint_as_float(u << 16);
    r.y = __uint_as_float(u & 0xffff0000u);
    return r;
}

// ---------------- feat transpose tile: (N,C,H,W) fp32 -> (N,H,W,C) bf16 ----------------
// LDS-tiled: coalesced reads along x, coalesced 16B HWC writes.
template<int CW, int HL, int WL>
__device__ __forceinline__ void ft_tile(
    float* tile, const float* __restrict__ in, __hip_bfloat16* __restrict__ out,
    int n, int y, int x0, int base, int t)
{
    const float* src = in + ((size_t)n * 128 * HL + y) * WL + x0;
    constexpr int NE = 128 * CW;
    for (int idx = t; idx < NE; idx += 256) {
        int c = idx / CW, x = idx - c * CW;
        tile[c * 45 + x] = src[(size_t)c * (HL * WL) + x];
    }
    __syncthreads();
    __hip_bfloat16* dst = out + base + ((size_t)(n * HL + y) * WL + x0) * 128;
    constexpr int NO = CW * 16;
    for (int idx = t; idx < NO; idx += 256) {
        int x = idx >> 4, g = idx & 15;
        union { __hip_bfloat16 h[8]; uint4 u; } pk;
        #pragma unroll
        for (int jj = 0; jj < 8; jj++)
            pk.h[jj] = __float2bfloat16(tile[(g * 8 + jj) * 45 + x]);
        *(uint4*)&dst[(size_t)x * 128 + g * 8] = pk.u;
    }
}

// ---------------- unified setup: feat transpose + weight prep + qT border zero + stats zero
// ---------------- + first CHW->padded-HWC pack of bev_query (no stats) ----------------
__global__ __launch_bounds__(256) void setup_k(
    const float* __restrict__ f0, const float* __restrict__ f1,
    const float* __restrict__ f2, const float* __restrict__ f3,
    __hip_bfloat16* __restrict__ fT,
    const float* __restrict__ mid_w1, const float* __restrict__ mid_w2,
    const float* __restrict__ mid_w3, const float* __restrict__ pe_w2,
    const float* __restrict__ off_w,  const float* __restrict__ off_b,
    const float* __restrict__ sw_w,   const float* __restrict__ sw_b,
    const float* __restrict__ in_w,   const float* __restrict__ out_w,
    const float* __restrict__ bev_query,
    __hip_bfloat16* __restrict__ Wb1, __hip_bfloat16* __restrict__ Wb2,
    __hip_bfloat16* __restrict__ Wb3, __hip_bfloat16* __restrict__ Wpe,
    __hip_bfloat16* __restrict__ Wof, float* __restrict__ Bof,
    __hip_bfloat16* __restrict__ Wcv1, __hip_bfloat16* __restrict__ Wcv2,
    __hip_bfloat16* __restrict__ qTo, float* __restrict__ Stats)
{
    __shared__ float tile[128 * 65];
    int b = blockIdx.x, t = threadIdx.x;
    if (b < 384) {            // feat l0: 6 cams * 32 y * 2 xchunks
        int n = b >> 6, q = b & 63, y = q >> 1, x0 = (q & 1) * 44;
        ft_tile<44, 32, 88>(tile, f0, fT, n, y, x0, 0, t);
    } else if (b < 480) {     // feat l1: 6 * 16
        int r = b - 384, n = r >> 4, y = r & 15;
        ft_tile<44, 16, 44>(tile, f1, fT, n, y, 0, 2162688, t);
    } else if (b < 528) {     // feat l2: 6 * 8
        int r = b - 480, n = r >> 3, y = r & 7;
        ft_tile<22, 8, 22>(tile, f2, fT, n, y, 0, 2703360, t);
    } else if (b < 552) {     // feat l3: 6 * 4
        int r = b - 528, n = r >> 2, y = r & 3;
        ft_tile<11, 4, 11>(tile, f3, fT, n, y, 0, 2838528, t);
    } else if (b < 2600) {
        int i = (b - 552) * 256 + t; Wb1[i] = __float2bfloat16(mid_w1[i]);
    } else if (b < 3624) {
        int i = (b - 2600) * 256 + t; Wb2[i] = __float2bfloat16(mid_w2[i]);
    } else if (b < 3880) {
        int i = (b - 3624) * 256 + t; Wb3[i] = __float2bfloat16(mid_w3[i]);
    } else if (b < 4008) {
        int n = b - 3880; Wpe[n * 256 + t] = __float2bfloat16(pe_w2[t * 128 + n]);
    } else if (b < 4072) {    // packed offsw weight: 64 rows (24 off + 32 sw + 8 zero)
        int n = b - 4008;
        if (t < 128) {
            float w = 0.f;
            if (n < 24)      w = off_w[n * 128 + t];
            else if (n < 56) w = sw_w[(n - 24) * 128 + t];
            Wof[n * 128 + t] = __float2bfloat16(w);
            if (t == 0) Bof[n] = (n < 24) ? off_b[n] : ((n < 56) ? sw_b[n - 24] : 0.f);
        }
    } else if (b < 4200) {
        int o = b - 4072;
        for (int idx = t; idx < 1152; idx += 256) {
            int s = idx >> 7, i = idx & 127;
            Wcv1[o * 1152 + idx] = __float2bfloat16(in_w[(o * 128 + i) * 9 + s]);
        }
    } else if (b < 4328) {
        int o = b - 4200;
        for (int idx = t; idx < 1152; idx += 256) {
            int s = idx >> 7, i = idx & 127;
            Wcv2[o * 1152 + idx] = __float2bfloat16(out_w[(o * 128 + i) * 9 + s]);
        }
    } else if (b < 4361) {    // qT border zero: 516 border pixels x 16 uint4
        int g = (b - 4328) * 256 + t;
        if (g < 8256) {
            int pixi = g >> 4, part = g & 15;
            int row, col;
            if (pixi < 130)      { row = 0;   col = pixi; }
            else if (pixi < 260) { row = 129; col = pixi - 130; }
            else {
                int r = pixi - 260;
                row = 1 + (r & 127);
                col = (r < 128) ? 0 : 129;
            }
            uint4 z = {0u, 0u, 0u, 0u};
            *(uint4*)&qTo[((size_t)row * 130 + col) * 128 + part * 8] = z;
        }
    } else if (b < 4362) {    // stats zero: 768 floats
        Stats[t] = 0.f; Stats[256 + t] = 0.f; Stats[512 + t] = 0.f;
    } else {                  // bev_query CHW -> padded HWC bf16 interior (256 blocks)
        int rel = b - 4362;
        int y = rel >> 1, x0 = (rel & 1) * 64;
        int xi = t & 63, c0 = t >> 6;
        for (int c = c0; c < 128; c += 4)
            tile[c * 65 + xi] = bev_query[c * HW + y * 128 + x0 + xi];
        __syncthreads();
        int xp = t >> 2, cg = (t & 3) * 32;
        __hip_bfloat16* dst = qTo + ((size_t)(y + 1) * 130 + (x0 + 1 + xp)) * 128;
        #pragma unroll
        for (int g = 0; g < 4; g++) {
            int c = cg + g * 8;
            union { __hip_bfloat16 h[8]; uint4 u; } pk;
            #pragma unroll
            for (int j = 0; j < 8; j++)
                pk.h[j] = __float2bfloat16(tile[(c + j) * 65 + xp]);
            *(uint4*)&dst[c] = pk.u;
        }
    }
}

// ---------------- CHW fp32 [128][128^2] -> padded HWC bf16 [130][130][128] (interior) ----------------
// stats (optional): per-channel {sum, sumsq}; applies instance-norm while packing.
__global__ __launch_bounds__(256) void chw2hwc_pad_k(
    const float* __restrict__ q, const float* __restrict__ stats,
    __hip_bfloat16* __restrict__ out)
{
    __shared__ float tile[128][65];
    __shared__ float sm[128], sr[128];
    int t = threadIdx.x;
    if (t < 128) {
        if (stats) {
            float s = stats[2 * t], s2 = stats[2 * t + 1];
            float mean = s * (1.0f / HW);
            sm[t] = mean;
            sr[t] = rsqrtf(s2 * (1.0f / HW) - mean * mean + 1e-5f);
        } else {
            sm[t] = 0.f; sr[t] = 1.f;
        }
    }
    int b = blockIdx.x;            // 256 blocks: y = b>>1, x0 = (b&1)*64
    int y = b >> 1, x0 = (b & 1) * 64;
    int xi = t & 63, c0 = t >> 6;
    for (int c = c0; c < 128; c += 4)
        tile[c][xi] = q[c * HW + y * 128 + x0 + xi];
    __syncthreads();
    int xp = t >> 2, cg = (t & 3) * 32;
    __hip_bfloat16* dst = out + ((size_t)(y + 1) * 130 + (x0 + 1 + xp)) * 128;
    #pragma unroll
    for (int g = 0; g < 4; g++) {
        int c = cg + g * 8;
        union { __hip_bfloat16 h[8]; uint4 u; } pk;
        #pragma unroll
        for (int j = 0; j < 8; j++)
            pk.h[j] = __float2bfloat16((tile[c + j][xp] - sm[c + j]) * sr[c + j]);
        *(uint4*)&dst[c] = pk.u;
    }
}

// ---------------- bf16 MFMA GEMM: out[m][n] = act(bias[n] + sum_k X[m][k] W[n][k]) ----------------
// OUTT: 0 -> bf16 [M][N]; 1 -> fp32 [N][M] (CHW, + optional residual res[n][m]).
// CONV: X is padded HWC bf16 [130][130][128]; k = s*128+c.
// rstats: normalize residual with {sum,sumsq}; ostats: accumulate output {sum,sumsq} (OUTT==1 only).
// K-loop: NBUF-deep LDS pipeline with counted vmcnt (never 0 in steady state) + raw s_barrier.
// LDS XOR-swizzle (both-sides): global source chunk permuted on stage, ds_read slot permuted to match.
// BK: 32 (original path) or 64 (halved barrier count; 8-slot swizzle, 2 MFMA frags/step).
template<int BM, int BN, int BK, int ACT, int OUTT, int CONV>
__global__ __launch_bounds__(256) void bgemm_k(
    const __hip_bfloat16* __restrict__ X, const __hip_bfloat16* __restrict__ W,
    const float* __restrict__ bias, void* __restrict__ outp,
    const float* __restrict__ res,
    const float* __restrict__ rstats, float* __restrict__ ostats,
    int M, int K, int N)
{
    constexpr int ROWS = BM + BN;
    constexpr int CPR  = BK / 8;                       // 16B chunks per row
    constexpr int ITERS = (ROWS * CPR) / 256;          // global_load_lds per lane per stage
    constexpr int BUFE  = ROWS * BK;                   // bf16 elements per buffer
    constexpr int NBUF  = (BK == 64) ? 4 : ((ITERS == 2) ? 4 : 3);
    __shared__ __align__(16) __hip_bfloat16 SH[NBUF * BUFE];
    int t = threadIdx.x;
    int w = t >> 6, lane = t & 63;
    int mb = blockIdx.y * BM, nb = blockIdx.x * BN;
    int cy = mb >> 7, cx = mb & 127;   // conv tile coords (CONV only)
    constexpr int WM = BM / 2;
    constexpr int MI = WM / 16;
    constexpr int NJ = BN / 32;
    int wm = (w & 1) * WM, wn = (w >> 1) * (BN / 2);
    int lm = lane & 15, lq = lane >> 4;
    int sl = (lq ^ ((lm >> 1) & 3)) * 8;               // BK=32 swizzled k-slot
    floatx4 zero = {0.f, 0.f, 0.f, 0.f};
    floatx4 acc[MI][NJ];
    #pragma unroll
    for (int i = 0; i < MI; i++)
        #pragma unroll
        for (int j = 0; j < NJ; j++) acc[i][j] = zero;

    const int nsteps = K / BK;

    auto STAGE = [&](int bufi, int tk2) {
        int kb_ = tk2 * BK;
        int s_ = kb_ >> 7;
        int dyi_ = s_ / 3, dxi_ = s_ - dyi_ * 3;       // tap indices (CONV only)
        #pragma unroll
        for (int it = 0; it < ITERS; it++) {
            int chunk = it * 256 + t;
            int row, ko;
            if constexpr (BK == 32) {
                row = chunk >> 2;
                ko = ((chunk & 3) ^ ((row >> 1) & 3)) * 8;
            } else {
                row = chunk >> 3;
                ko = ((chunk & 7) ^ (row & 7)) * 8;
            }
            const __hip_bfloat16* src;
            if (row < BM) {
                if (CONV)
                    src = X + (((size_t)(cy + dyi_) * 130) + (cx + dxi_ + row)) * 128 + (kb_ & 127) + ko;
                else
                    src = X + (size_t)(mb + row) * K + kb_ + ko;
            } else {
                src = W + (size_t)(nb + row - BM) * K + kb_ + ko;
            }
            __builtin_amdgcn_global_load_lds(
                (const __attribute__((address_space(1))) void*)src,
                (__attribute__((address_space(3))) void*)&SH[bufi * BUFE + (it * 256 + (t & ~63)) * 8],
                16, 0, 0);
        }
    };

    #pragma unroll
    for (int pi = 0; pi < NBUF - 1; pi++)
        if (pi < nsteps) STAGE(pi, pi);

    for (int tk = 0; tk < nsteps; ++tk) {
        int rem = nsteps - 1 - tk;
        if constexpr (NBUF == 4 && ITERS == 2) {
            if (rem >= 2)      asm volatile("s_waitcnt vmcnt(4)" ::: "memory");
            else if (rem == 1) asm volatile("s_waitcnt vmcnt(2)" ::: "memory");
            else               asm volatile("s_waitcnt vmcnt(0)" ::: "memory");
        } else if constexpr (NBUF == 4) {              // ITERS == 4 (BK=64)
            if (rem >= 2)      asm volatile("s_waitcnt vmcnt(8)" ::: "memory");
            else if (rem == 1) asm volatile("s_waitcnt vmcnt(4)" ::: "memory");
            else               asm volatile("s_waitcnt vmcnt(0)" ::: "memory");
        } else {                                       // NBUF==3, ITERS==4
            if (rem >= 1)      asm volatile("s_waitcnt vmcnt(4)" ::: "memory");
            else               asm volatile("s_waitcnt vmcnt(0)" ::: "memory");
        }
        __builtin_amdgcn_s_barrier();
        int tkn = tk + NBUF - 1;
        if (tkn < nsteps) STAGE(tkn % NBUF, tkn);

        const __hip_bfloat16* As = SH + (tk % NBUF) * BUFE;
        const __hip_bfloat16* Bs = As + BM * BK;
        if constexpr (BK == 32) {
            short8 af[MI], bf[NJ];
            #pragma unroll
            for (int i = 0; i < MI; i++)
                af[i] = *(const short8*)&As[(wm + i * 16 + lm) * 32 + sl];
            #pragma unroll
            for (int j = 0; j < NJ; j++)
                bf[j] = *(const short8*)&Bs[(wn + j * 16 + lm) * 32 + sl];
            #pragma unroll
            for (int i = 0; i < MI; i++)
                #pragma unroll
                for (int j = 0; j < NJ; j++)
                    acc[i][j] = __builtin_amdgcn_mfma_f32_16x16x32_bf16(af[i], bf[j], acc[i][j], 0, 0, 0);
        } else {
            short8 af[MI][2], bf[NJ][2];
            #pragma unroll
            for (int i = 0; i < MI; i++) {
                int ra = wm + i * 16 + lm, sw = ra & 7;
                af[i][0] = *(const short8*)&As[ra * 64 + (lq ^ sw) * 8];
                af[i][1] = *(const short8*)&As[ra * 64 + ((4 | lq) ^ sw) * 8];
            }
            #pragma unroll
            for (int j = 0; j < NJ; j++) {
                int rb = wn + j * 16 + lm, sw = rb & 7;
                bf[j][0] = *(const short8*)&Bs[rb * 64 + (lq ^ sw) * 8];
                bf[j][1] = *(const short8*)&Bs[rb * 64 + ((4 | lq) ^ sw) * 8];
            }
            #pragma unroll
            for (int i = 0; i < MI; i++)
                #pragma unroll
                for (int j = 0; j < NJ; j++) {
                    acc[i][j] = __builtin_amdgcn_mfma_f32_16x16x32_bf16(af[i][0], bf[j][0], acc[i][j], 0, 0, 0);
                    acc[i][j] = __builtin_amdgcn_mfma_f32_16x16x32_bf16(af[i][1], bf[j][1], acc[i][j], 0, 0, 0);
                }
        }
    }

    float invM = 1.0f / (float)M;
    #pragma unroll
    for (int j = 0; j < NJ; j++) {
        int n = nb + wn + j * 16 + lm;
        float bv = bias[n];
        float rmean = 0.f, rrstd = 0.f;
        if (OUTT == 1 && res && rstats) {
            float s = rstats[2 * n], s2 = rstats[2 * n + 1];
            rmean = s * invM;
            rrstd = rsqrtf(s2 * invM - rmean * rmean + 1e-5f);
        }
        float ss = 0.f, ss2 = 0.f;
        #pragma unroll
        for (int i = 0; i < MI; i++) {
            #pragma unroll
            for (int r = 0; r < 4; r++) {
                int m = mb + wm + i * 16 + lq * 4 + r;
                float v = acc[i][j][r] + bv;
                if (ACT) v = gelu_exact(v);
                if (OUTT == 0) {
                    ((__hip_bfloat16*)outp)[(size_t)m * N + n] = __float2bfloat16(v);
                } else {
                    if (res) {
                        float rv = res[(size_t)n * M + m];
                        v += rstats ? (rv - rmean) * rrstd : rv;
                    }
                    ((float*)outp)[(size_t)n * M + m] = v;
                    ss += v; ss2 += v * v;
                }
            }
        }
        if (OUTT == 1 && ostats) {
            ss  += __shfl_xor(ss, 16);  ss  += __shfl_xor(ss, 32);
            ss2 += __shfl_xor(ss2, 16); ss2 += __shfl_xor(ss2, 32);
            if (lq == 0) {
                atomicAdd(&ostats[2 * n], ss);
                atomicAdd(&ostats[2 * n + 1], ss2);
            }
        }
    }
}

// ---------------- fused offsets/sample-weights GEMM + epilogue ----------------
// BM=BN=64, K=128, CONV-style X addressing (center tap of padded normalized q0).
// Block (1D grid, 256 blocks) holds ALL 64 channels for its 64 pixels, so the
// offpost math (sigmoid->pts/height, 4-way softmax->swn) runs in-register.
// Softmax group (l = n&3) = 4 adjacent lanes -> shfl_xor(1)+shfl_xor(2).
__global__ __launch_bounds__(256) void offgemm_k(
    const __hip_bfloat16* __restrict__ X, const __hip_bfloat16* __restrict__ W,
    const float* __restrict__ bias, const float* __restrict__ bev_pos,
    float* __restrict__ pts, float* __restrict__ swn, float* __restrict__ height_out)
{
    constexpr int BUFE = 128 * 32;
    __shared__ __align__(16) __hip_bfloat16 SH[4 * BUFE];
    int t = threadIdx.x;
    int w = t >> 6, lane = t & 63;
    int mb = blockIdx.x * 64;
    int cy = mb >> 7, cx = mb & 127;
    int wm = (w & 1) * 32, wn = (w >> 1) * 32;
    int lm = lane & 15, lq = lane >> 4;
    int sl = (lq ^ ((lm >> 1) & 3)) * 8;
    floatx4 zero = {0.f, 0.f, 0.f, 0.f};
    floatx4 acc[2][2];
    acc[0][0] = zero; acc[0][1] = zero; acc[1][0] = zero; acc[1][1] = zero;

    auto STAGE = [&](int bufi, int tk2) {
        int kb_ = tk2 * 32;
        #pragma unroll
        for (int it = 0; it < 2; it++) {
            int chunk = it * 256 + t;
            int row = chunk >> 2;
            int ko = ((chunk & 3) ^ ((row >> 1) & 3)) * 8;
            const __hip_bfloat16* src;
            if (row < 64) src = X + ((size_t)cy * 130 + cx + row) * 128 + kb_ + ko;
            else          src = W + (size_t)(row - 64) * 128 + kb_ + ko;
            __builtin_amdgcn_global_load_lds(
                (const __attribute__((address_space(1))) void*)src,
                (__attribute__((address_space(3))) void*)&SH[bufi * BUFE + (it * 256 + (t & ~63)) * 8],
                16, 0, 0);
        }
    };

    STAGE(0, 0); STAGE(1, 1); STAGE(2, 2);
    for (int tk = 0; tk < 4; ++tk) {
        int rem = 3 - tk;
        if (rem >= 2)      asm volatile("s_waitcnt vmcnt(4)" ::: "memory");
        else if (rem == 1) asm volatile("s_waitcnt vmcnt(2)" ::: "memory");
        else               asm volatile("s_waitcnt vmcnt(0)" ::: "memory");
        __builtin_amdgcn_s_barrier();
        if (tk + 3 < 4) STAGE((tk + 3) & 3, tk + 3);
        const __hip_bfloat16* As = SH + (tk & 3) * BUFE;
        const __hip_bfloat16* Bs = As + 64 * 32;
        short8 af[2], bf[2];
        #pragma unroll
        for (int i = 0; i < 2; i++)
            af[i] = *(const short8*)&As[(wm + i * 16 + lm) * 32 + sl];
        #pragma unroll
        for (int j = 0; j < 2; j++)
            bf[j] = *(const short8*)&Bs[(wn + j * 16 + lm) * 32 + sl];
        #pragma unroll
        for (int i = 0; i < 2; i++)
            #pragma unroll
            for (int j = 0; j < 2; j++)
                acc[i][j] = __builtin_amdgcn_mfma_f32_16x16x32_bf16(af[i], bf[j], acc[i][j], 0, 0, 0);
    }

    const float rngv[3]  = {100.f, 100.f, 8.f};
    const float pcm[3]   = {-50.f, -50.f, -4.f};
    #pragma unroll
    for (int j = 0; j < 2; j++) {
        int n = wn + j * 16 + lm;
        float bv = bias[n];
        int p3 = n / 3, d3 = n - p3 * 3;                 // off path (n<24)
        float lim = (d3 == 2) ? (4.0f + 1e-6f) : (0.25f + 1e-6f);
        #pragma unroll
        for (int i = 0; i < 2; i++) {
            #pragma unroll
            for (int r = 0; r < 4; r++) {
                int m = mb + wm + i * 16 + lq * 4 + r;
                float v = acc[i][j][r] + bv;
                // softmax over 4-lane groups, executed by all lanes (writes predicated)
                float mm = fmaxf(v, __shfl_xor(v, 1));
                mm = fmaxf(mm, __shfl_xor(mm, 2));
                float e = expf(v - mm);
                float s = e + __shfl_xor(e, 1);
                s += __shfl_xor(s, 2);
                if (n < 24) {
                    float sv = 1.f / (1.f + expf(-v));
                    float offv = sv * 2.f * lim - lim;
                    float refv = bev_pos[m * 3 + d3] * rngv[d3] + pcm[d3];
                    pts[m * 24 + n] = refv + offv;
                    if (d3 == 2) height_out[p3 * HW + m] = offv;
                } else if (n < 56) {
                    swn[m * 32 + (n - 24)] = e / s;
                }
            }
        }
    }
}

// ---------------- fused PE: hidden = relu(rn @ w1 + b1) on the fly, GEMM vs Wpe ----------------
__global__ __launch_bounds__(256) void pe_bgemm_k(
    const float* __restrict__ pts, const float* __restrict__ pe_w1,
    const float* __restrict__ pe_b1, const __hip_bfloat16* __restrict__ W,
    const float* __restrict__ bias, __hip_bfloat16* __restrict__ out)
{
    __shared__ __align__(16) __hip_bfloat16 As[128 * 32];
    __shared__ __align__(16) __hip_bfloat16 Bs[128 * 32];
    __shared__ __align__(16) float wps[4][256];   // [b1, w1_x, w1_y, w1_z][256]
    int t = threadIdx.x;
    int w = t >> 6, lane = t & 63;
    int mb = blockIdx.x * 128;
    {
        int d = t >> 6, c = (t & 63) * 4;
        float4 v;
        if (d == 0) v = *(const float4*)&pe_b1[c];
        else        v = *(const float4*)&pe_w1[(d - 1) * 256 + c];
        *(float4*)&wps[d][c] = v;
    }
    int cg = t & 3;
    int r0 = t >> 2;
    float rn[2][3];
    #pragma unroll
    for (int h = 0; h < 2; h++) {
        int r = mb + r0 + h * 64;
        rn[h][0] = (pts[(size_t)r * 3 + 0] + 50.f) * 0.01f;
        rn[h][1] = (pts[(size_t)r * 3 + 1] + 50.f) * 0.01f;
        rn[h][2] = (pts[(size_t)r * 3 + 2] + 4.f) * 0.125f;
    }
    int wm = (w & 1) * 64, wn = (w >> 1) * 64;
    int lm = lane & 15, lq = lane >> 4;
    floatx4 zero = {0.f, 0.f, 0.f, 0.f};
    floatx4 acc[4][4];
    #pragma unroll
    for (int i = 0; i < 4; i++)
        #pragma unroll
        for (int j = 0; j < 4; j++) acc[i][j] = zero;
    for (int kb = 0; kb < 256; kb += 32) {
        __syncthreads();
        #pragma unroll
        for (int it = 0; it < 2; it++) {
            int chunk = it * 256 + t;
            int brow = chunk >> 2, ko = (chunk & 3) * 8;
            const __hip_bfloat16* src = W + (size_t)brow * 256 + kb + ko;
            __builtin_amdgcn_global_load_lds(
                (const __attribute__((address_space(1))) void*)src,
                (__attribute__((address_space(3))) void*)&Bs[(size_t)(it * 256 + (t & ~63)) * 8],
                16, 0, 0);
        }
        int c0 = kb + cg * 8;
        float4 bva = *(const float4*)&wps[0][c0], bvb = *(const float4*)&wps[0][c0 + 4];
        float4 wxa = *(const float4*)&wps[1][c0], wxb = *(const float4*)&wps[1][c0 + 4];
        float4 wya = *(const float4*)&wps[2][c0], wyb = *(const float4*)&wps[2][c0 + 4];
        float4 wza = *(const float4*)&wps[3][c0], wzb = *(const float4*)&wps[3][c0 + 4];
        #pragma unroll
        for (int h = 0; h < 2; h++) {
            const float* bv = (const float*)&bva;
            const float* wx = (const float*)&wxa;
            const float* wy = (const float*)&wya;
            const float* wz = (const float*)&wza;
            union { __hip_bfloat16 hh[8]; uint4 u; } pk;
            #pragma unroll
            for (int j = 0; j < 4; j++) {
                float v = bv[j] + rn[h][0] * wx[j] + rn[h][1] * wy[j] + rn[h][2] * wz[j];
                pk.hh[j] = __float2bfloat16(fmaxf(v, 0.f));
            }
            bv = (const float*)&bvb; wx = (const float*)&wxb;
            wy = (const float*)&wyb; wz = (const float*)&wzb;
            #pragma unroll
            for (int j = 0; j < 4; j++) {
                float v = bv[j] + rn[h][0] * wx[j] + rn[h][1] * wy[j] + rn[h][2] * wz[j];
                pk.hh[4 + j] = __float2bfloat16(fmaxf(v, 0.f));
            }
            *(uint4*)&As[(r0 + h * 64) * 32 + cg * 8] = pk.u;
        }
        __syncthreads();
        short8 af[4], bf[4];
        #pragma unroll
        for (int i = 0; i < 4; i++)
            af[i] = *(const short8*)&As[(wm + i * 16 + lm) * 32 + lq * 8];
        #pragma unroll
        for (int j = 0; j < 4; j++)
            bf[j] = *(const short8*)&Bs[(wn + j * 16 + lm) * 32 + lq * 8];
        #pragma unroll
        for (int i = 0; i < 4; i++)
            #pragma unroll
            for (int j = 0; j < 4; j++)
                acc[i][j] = __builtin_amdgcn_mfma_f32_16x16x32_bf16(af[i], bf[j], acc[i][j], 0, 0, 0);
    }
    #pragma unroll
    for (int i = 0; i < 4; i++) {
        #pragma unroll
        for (int j = 0; j < 4; j++) {
            int n = wn + j * 16 + lm;
            float bv = bias[n];
            #pragma unroll
            for (int r = 0; r < 4; r++) {
                int m = mb + wm + i * 16 + lq * 4 + r;
                out[(size_t)m * 128 + n] = __float2bfloat16(acc[i][j][r] + bv);
            }
        }
    }
}

// ---------------- final instance norm apply (stats precomputed in producer epilogue) ----------------
__global__ __launch_bounds__(256) void inorm_apply_k(
    const float* __restrict__ in, const float* __restrict__ stats, float* __restrict__ out)
{
    int b = blockIdx.x;           // 1024 blocks: c = b>>3, seg = b&7 (2048 floats each)
    int c = b >> 3, seg = b & 7;
    float s = stats[2 * c], s2 = stats[2 * c + 1];
    float mean = s * (1.0f / HW);
    float rstd = rsqrtf(s2 * (1.0f / HW) - mean * mean + 1e-5f);
    const float4* pi = (const float4*)(in + (size_t)c * HW + seg * 2048);
    float4*       po = (float4*)(out + (size_t)c * HW + seg * 2048);
    int t = threadIdx.x;
    #pragma unroll
    for (int k = 0; k < 2; k++) {
        float4 v = pi[t + k * 256];
        v.x = (v.x - mean) * rstd; v.y = (v.y - mean) * rstd;
        v.z = (v.z - mean) * rstd; v.w = (v.w - mean) * rstd;
        po[t + k * 256] = v;
    }
}

// ---------------- sampling: phase-1 projection + cull, phase-2 bf16 packed gather ----------------
// 256 threads = 4 waves; wave wv owns p = wv*2 + {0,1}; offsets stored as BYTE offsets;
// main loop processes 2 taps/iter with split accumulators (8 loads in flight).
__global__ __launch_bounds__(256) void sample_k(
    const __hip_bfloat16* __restrict__ featT, const float* __restrict__ pts,
    const float* __restrict__ swn,   const float* __restrict__ l2i,
    __hip_bfloat16* __restrict__ sf)
{
    int pix = blockIdx.x;
    int t = threadIdx.x;
    int lane = t & 63, wv = t >> 6;
    __shared__ float pts_s[24];
    __shared__ float swl_s[32];
    __shared__ float M[96];
    __shared__ __align__(16) int   offs[8][24][4];   // byte offsets into featT
    __shared__ __align__(16) float wts[8][24][4];
    __shared__ int cnt[8];
    if (t < 96) M[t] = l2i[t];
    if (t < 24) pts_s[t] = pts[pix * 24 + t];
    if (t < 32) swl_s[t] = swn[pix * 32 + t];
    if (t < 8)  cnt[t] = 0;
    __syncthreads();

    floatx2 acc[2];
    #pragma unroll
    for (int i = 0; i < 2; i++) {
        unsigned int u = *(const unsigned int*)&sf[(size_t)pix * 1024 + (wv * 2 + i) * 128 + 2 * lane];
        acc[i] = bf2x(u);
    }

    const int lHt[4] = {32, 16, 8, 4}, lWt[4] = {88, 44, 22, 11};
    const int loff[4] = {0, 2162688, 2703360, 2838528};
    if (t < 192) {
        int p = t / 24;
        int rr = t - p * 24;
        int n = rr >> 2, l = rr & 3;
        float X = pts_s[p * 3], Y = pts_s[p * 3 + 1], Z = pts_s[p * 3 + 2];
        const float* Mn = &M[n * 16];
        float zc = Mn[8] * X + Mn[9] * Y + Mn[10] * Z + Mn[11];
        if (zc > 1e-5f) {
            float inv = 1.f / zc;
            float xn = (Mn[0] * X + Mn[1] * Y + Mn[2] * Z + Mn[3]) * inv * (1.f / 704.f);
            float yn = (Mn[4] * X + Mn[5] * Y + Mn[6] * Z + Mn[7]) * inv * (1.f / 256.f);
            int Wl = lWt[l], Hl = lHt[l];
            float px = xn * Wl - 0.5f, py = yn * Hl - 0.5f;
            px = fminf(fmaxf(px, -2.f), (float)(Wl + 1));
            py = fminf(fmaxf(py, -2.f), (float)(Hl + 1));
            float x0f = floorf(px), y0f = floorf(py);
            float wx = px - x0f, wy = py - y0f;
            int x0 = (int)x0f, y0 = (int)y0f;
            bool xi0 = (unsigned)x0 < (unsigned)Wl, xi1 = (unsigned)(x0 + 1) < (unsigned)Wl;
            bool yi0 = (unsigned)y0 < (unsigned)Hl, yi1 = (unsigned)(y0 + 1) < (unsigned)Hl;
            if ((xi0 || xi1) && (yi0 || yi1)) {
                float wl = swl_s[p * 4 + l];
                float w00 = wl * (1.f - wx) * (1.f - wy) * (float)(xi0 && yi0);
                float w10 = wl * wx * (1.f - wy)         * (float)(xi1 && yi0);
                float w01 = wl * (1.f - wx) * wy         * (float)(xi0 && yi1);
                float w11 = wl * wx * wy                 * (float)(xi1 && yi1);
                int x0c = min(max(x0, 0), Wl - 1), x1c = min(max(x0 + 1, 0), Wl - 1);
                int y0c = min(max(y0, 0), Hl - 1), y1c = min(max(y0 + 1, 0), Hl - 1);
                int base = loff[l] + n * Hl * Wl * 128;
                int idx = atomicAdd(&cnt[p], 1);
                offs[p][idx][0] = (base + (y0c * Wl + x0c) * 128) * 2;
                offs[p][idx][1] = (base + (y0c * Wl + x1c) * 128) * 2;
                offs[p][idx][2] = (base + (y1c * Wl + x0c) * 128) * 2;
                offs[p][idx][3] = (base + (y1c * Wl + x1c) * 128) * 2;
                wts[p][idx][0] = w00; wts[p][idx][1] = w10;
                wts[p][idx][2] = w01; wts[p][idx][3] = w11;
            }
        }
    }
    __syncthreads();

    const char* fbase = (const char*)featT;
    int lane4 = lane * 4;
    #pragma unroll
    for (int i = 0; i < 2; i++) {
        int p = wv * 2 + i;
        int np = cnt[p];
        floatx2 a0 = acc[i];
        floatx2 a1 = {0.f, 0.f};
        int j = 0;
        #pragma unroll 1
        for (; j + 2 <= np; j += 2) {
            int4   oA = *(const int4*)&offs[p][j][0];
            float4 wA = *(const float4*)&wts[p][j][0];
            int4   oB = *(const int4*)&offs[p][j + 1][0];
            float4 wB = *(const float4*)&wts[p][j + 1][0];
            unsigned int v0 = *(const unsigned int*)(fbase + (unsigned)(oA.x + lane4));
            unsigned int v1 = *(const unsigned int*)(fbase + (unsigned)(oA.y + lane4));
            unsigned int v2 = *(const unsigned int*)(fbase + (unsigned)(oA.z + lane4));
            unsigned int v3 = *(const unsigned int*)(fbase + (unsigned)(oA.w + lane4));
            unsigned int v4 = *(const unsigned int*)(fbase + (unsigned)(oB.x + lane4));
            unsigned int v5 = *(const unsigned int*)(fbase + (unsigned)(oB.y + lane4));
            unsigned int v6 = *(const unsigned int*)(fbase + (unsigned)(oB.z + lane4));
            unsigned int v7 = *(const unsigned int*)(fbase + (unsigned)(oB.w + lane4));
            a0 += bf2x(v0) * wA.x;
            a0 += bf2x(v1) * wA.y;
            a0 += bf2x(v2) * wA.z;
            a0 += bf2x(v3) * wA.w;
            a1 += bf2x(v4) * wB.x;
            a1 += bf2x(v5) * wB.y;
            a1 += bf2x(v6) * wB.z;
            a1 += bf2x(v7) * wB.w;
        }
        if (j < np) {
            int4   o = *(const int4*)&offs[p][j][0];
            float4 w = *(const float4*)&wts[p][j][0];
            unsigned int v0 = *(const unsigned int*)(fbase + (unsigned)(o.x + lane4));
            unsigned int v1 = *(const unsigned int*)(fbase + (unsigned)(o.y + lane4));
            unsigned int v2 = *(const unsigned int*)(fbase + (unsigned)(o.z + lane4));
            unsigned int v3 = *(const unsigned int*)(fbase + (unsigned)(o.w + lane4));
            a0 += bf2x(v0) * w.x;
            a0 += bf2x(v1) * w.y;
            a0 += bf2x(v2) * w.z;
            a0 += bf2x(v3) * w.w;
        }
        acc[i] = a0 + a1;
    }
    #pragma unroll
    for (int i = 0; i < 2; i++) {
        union { __hip_bfloat16 h[2]; unsigned int u; } pk;
        pk.h[0] = __float2bfloat16(acc[i].x);
        pk.h[1] = __float2bfloat16(acc[i].y);
        *(unsigned int*)&sf[(size_t)pix * 1024 + (wv * 2 + i) * 128 + 2 * lane] = pk.u;
    }
}

extern "C" void kernel_launch(void* const* d_in, const int* in_sizes, int n_in,
                              void* d_out, int out_size, void* d_ws, size_t ws_size,
                              hipStream_t stream)
{
    const float* feat[4] = {(const float*)d_in[0], (const float*)d_in[1],
                            (const float*)d_in[2], (const float*)d_in[3]};
    const float* l2i       = (const float*)d_in[4];
    const float* bev_query = (const float*)d_in[5];
    const float* bev_pos   = (const float*)d_in[6];
    const float* in_w  = (const float*)d_in[7];  const float* in_b  = (const float*)d_in[8];
    const float* off_w = (const float*)d_in[9];  const float* off_b = (const float*)d_in[10];
    const float* sw_w  = (const float*)d_in[11]; const float* sw_b  = (const float*)d_in[12];
    const float* pe_w1 = (const float*)d_in[13]; const float* pe_b1 = (const float*)d_in[14];
    const float* pe_w2 = (const float*)d_in[15]; const float* pe_b2 = (const float*)d_in[16];
    const float* mid_w1 = (const float*)d_in[17]; const float* mid_b1 = (const float*)d_in[18];
    const float* mid_w2 = (const float*)d_in[19]; const float* mid_b2 = (const float*)d_in[20];
    const float* mid_w3 = (const float*)d_in[21]; const float* mid_b3 = (const float*)d_in[22];
    const float* out_w  = (const float*)d_in[23]; const float* out_b  = (const float*)d_in[24];

    float* ws = (float*)d_ws;
    float* fTf = ws;                    // 1,436,160 : transposed feats bf16
    __hip_bfloat16* fT = (__hip_bfloat16*)fTf;
    float* Bb  = fTf + 1436160;         // 2,097,152 : q1 raw (CHW)
    float* Cb  = Bb + 2097152;          // 2,097,152 : q0 raw (conv1 out, CHW)
    float* Gb  = Cb + 2097152;          // 2,097,152 : conv2 raw (CHW)
    float* Dp  = Gb + 2097152;          //   393,216 : pts
    float* Eb  = Dp + 393216;           //   524,288 : swn
    float* QTf = Eb + 524288;           // 1,081,600 : padded HWC bf16 (130*130*128)
    __hip_bfloat16* qT = (__hip_bfloat16*)QTf;
    float* SFf = QTf + 1081600;         // 8,388,608 : sf bf16 131072x128
    __hip_bfloat16* sfb = (__hip_bfloat16*)SFf;
    float* M1f = SFf + 8388608;         // 4,194,304 : m1 bf16
    __hip_bfloat16* m1b = (__hip_bfloat16*)M1f;
    float* M2f = M1f + 4194304;         // 4,194,304 : m2 bf16
    __hip_bfloat16* m2b = (__hip_bfloat16*)M2f;
    float* WC1 = M2f + 4194304;         //    73,728 : conv1 weights bf16
    __hip_bfloat16* Wcv1 = (__hip_bfloat16*)WC1;
    float* WC2 = WC1 + 73728;           //    73,728 : conv2 weights bf16
    __hip_bfloat16* Wcv2 = (__hip_bfloat16*)WC2;
    float* W1f = WC2 + 73728;           //   262,144
    __hip_bfloat16* Wb1 = (__hip_bfloat16*)W1f;
    float* W2f = W1f + 262144;          //   131,072
    __hip_bfloat16* Wb2 = (__hip_bfloat16*)W2f;
    float* W3f = W2f + 131072;          //    32,768
    __hip_bfloat16* Wb3 = (__hip_bfloat16*)W3f;
    float* WPf = W3f + 32768;           //    16,384 : pe_w2^T bf16
    __hip_bfloat16* Wpe = (__hip_bfloat16*)WPf;
    float* WOf = WPf + 16384;           //     8,192 : offsw packed weight bf16 (64x128 used)
    __hip_bfloat16* Wof = (__hip_bfloat16*)WOf;
    float* Bof = WOf + 8192;            //       128 : offsw packed bias fp32 (64 used)
    float* Stats = Bof + 128;           //       768 : 3 x 128 x {sum,sumsq}
    float* stats1 = Stats;
    float* stats2 = Stats + 256;
    float* stats3 = Stats + 512;

    float* q_out = (float*)d_out;
    float* h_out = q_out + 2097152;

    // setup: feat transpose + weight prep + qT border zero + stats zero + bev_query pad
    setup_k<<<4618, 256, 0, stream>>>(feat[0], feat[1], feat[2], feat[3], fT,
                                      mid_w1, mid_w2, mid_w3, pe_w2, off_w, off_b, sw_w, sw_b,
                                      in_w, out_w, bev_query,
                                      Wb1, Wb2, Wb3, Wpe, Wof, Bof, Wcv1, Wcv2,
                                      qT, Stats);

    // conv1: q0raw = bev_query + conv3x3(bev_query) -> Cb, stats1 accumulated in epilogue
    bgemm_k<64, 64, 64, 0, 1, 1><<<dim3(2, 256), 256, 0, stream>>>(
        qT, Wcv1, in_b, Cb, bev_query, nullptr, stats1, HW, 1152, 128);

    // offsets/sample-weights: normalized-q0 pack, then fused GEMM+epilogue -> pts/swn/height
    chw2hwc_pad_k<<<256, 256, 0, stream>>>(Cb, stats1, qT);   // applies inorm(q0raw)
    offgemm_k<<<256, 256, 0, stream>>>(qT + 131 * 128, Wof, Bof, bev_pos, Dp, Eb, h_out);

    // fused PE (hidden on the fly + MFMA GEMM) -> sf
    pe_bgemm_k<<<1024, 256, 0, stream>>>(Dp, pe_w1, pe_b1, Wpe, pe_b2, sfb);

    // sampling accumulates taps onto sf
    sample_k<<<HW, 256, 0, stream>>>(fT, Dp, Eb, l2i, sfb);

    // mid MLP: 1024 -> 512 gelu -> 512 gelu -> 128 linear (+ normalized q0 residual)
    bgemm_k<128, 128, 32, 1, 0, 0><<<dim3(4, 128), 256, 0, stream>>>(
        sfb, Wb1, mid_b1, m1b, nullptr, nullptr, nullptr, HW, 1024, 512);
    bgemm_k<128, 128, 32, 1, 0, 0><<<dim3(4, 128), 256, 0, stream>>>(
        m1b, Wb2, mid_b2, m2b, nullptr, nullptr, nullptr, HW, 512, 512);
    bgemm_k<64, 64, 64, 0, 1, 0><<<dim3(2, 256), 256, 0, stream>>>(
        m2b, Wb3, mid_b3, Bb, Cb, stats1, stats2, HW, 512, 128);   // q1raw -> Bb, stats2

    // conv2: q = inorm(q1n + conv3x3(q1n)); q1n applied on the fly from stats2
    chw2hwc_pad_k<<<256, 256, 0, stream>>>(Bb, stats2, qT);
    bgemm_k<64, 64, 64, 0, 1, 1><<<dim3(2, 256), 256, 0, stream>>>(
        qT, Wcv2, out_b, Gb, Bb, stats2, stats3, HW, 1152, 128);   // conv2 raw -> Gb, stats3
    inorm_apply_k<<<1024, 256, 0, stream>>>(Gb, stats3, q_out);
}

// Round 10
// 362.533 us; speedup vs baseline: 1.1143x; 1.0170x over previous
//
#include <hip/hip_runtime.h>
#include <hip/hip_bf16.h>
#include <math.h>

#define HW 16384   // 128*128 bev pixels

typedef __attribute__((ext_vector_type(8))) short short8;
typedef __attribute__((ext_vector_type(4))) float floatx4;
typedef __attribute__((ext_vector_type(2))) float floatx2;

__device__ __forceinline__ float gelu_exact(float x){
    return 0.5f * x * (1.0f + erff(x * 0.7071067811865475f));
}

__device__ __forceinline__ floatx2 bf2x(unsigned int u){
    floatx2 r;
    r.x = __uint_as_float(u << 16);
    r.y = __uint_as_float(u & 0xffff0000u);
    return r;
}

// ---------------- feat transpose tile: (N,C,H,W) fp32 -> (N,H,W,C) bf16 ----------------
// LDS-tiled: coalesced reads along x, coalesced 16B HWC writes.
template<int CW, int HL, int WL>
__device__ __forceinline__ void ft_tile(
    float* tile, const float* __restrict__ in, __hip_bfloat16* __restrict__ out,
    int n, int y, int x0, int base, int t)
{
    const float* src = in + ((size_t)n * 128 * HL + y) * WL + x0;
    constexpr int NE = 128 * CW;
    for (int idx = t; idx < NE; idx += 256) {
        int c = idx / CW, x = idx - c * CW;
        tile[c * 45 + x] = src[(size_t)c * (HL * WL) + x];
    }
    __syncthreads();
    __hip_bfloat16* dst = out + base + ((size_t)(n * HL + y) * WL + x0) * 128;
    constexpr int NO = CW * 16;
    for (int idx = t; idx < NO; idx += 256) {
        int x = idx >> 4, g = idx & 15;
        union { __hip_bfloat16 h[8]; uint4 u; } pk;
        #pragma unroll
        for (int jj = 0; jj < 8; jj++)
            pk.h[jj] = __float2bfloat16(tile[(g * 8 + jj) * 45 + x]);
        *(uint4*)&dst[(size_t)x * 128 + g * 8] = pk.u;
    }
}

// ---------------- unified setup: feat transpose + weight prep + qT border zero + stats zero
// ---------------- + first CHW->padded-HWC pack of bev_query (no stats) ----------------
__global__ __launch_bounds__(256) void setup_k(
    const float* __restrict__ f0, const float* __restrict__ f1,
    const float* __restrict__ f2, const float* __restrict__ f3,
    __hip_bfloat16* __restrict__ fT,
    const float* __restrict__ mid_w1, const float* __restrict__ mid_w2,
    const float* __restrict__ mid_w3, const float* __restrict__ pe_w2,
    const float* __restrict__ off_w,  const float* __restrict__ off_b,
    const float* __restrict__ sw_w,   const float* __restrict__ sw_b,
    const float* __restrict__ in_w,   const float* __restrict__ out_w,
    const float* __restrict__ bev_query,
    __hip_bfloat16* __restrict__ Wb1, __hip_bfloat16* __restrict__ Wb2,
    __hip_bfloat16* __restrict__ Wb3, __hip_bfloat16* __restrict__ Wpe,
    __hip_bfloat16* __restrict__ Wof, float* __restrict__ Bof,
    __hip_bfloat16* __restrict__ Wcv1, __hip_bfloat16* __restrict__ Wcv2,
    __hip_bfloat16* __restrict__ qTo, float* __restrict__ Stats)
{
    __shared__ float tile[128 * 65];
    int b = blockIdx.x, t = threadIdx.x;
    if (b < 384) {            // feat l0: 6 cams * 32 y * 2 xchunks
        int n = b >> 6, q = b & 63, y = q >> 1, x0 = (q & 1) * 44;
        ft_tile<44, 32, 88>(tile, f0, fT, n, y, x0, 0, t);
    } else if (b < 480) {     // feat l1: 6 * 16
        int r = b - 384, n = r >> 4, y = r & 15;
        ft_tile<44, 16, 44>(tile, f1, fT, n, y, 0, 2162688, t);
    } else if (b < 528) {     // feat l2: 6 * 8
        int r = b - 480, n = r >> 3, y = r & 7;
        ft_tile<22, 8, 22>(tile, f2, fT, n, y, 0, 2703360, t);
    } else if (b < 552) {     // feat l3: 6 * 4
        int r = b - 528, n = r >> 2, y = r & 3;
        ft_tile<11, 4, 11>(tile, f3, fT, n, y, 0, 2838528, t);
    } else if (b < 2600) {
        int i = (b - 552) * 256 + t; Wb1[i] = __float2bfloat16(mid_w1[i]);
    } else if (b < 3624) {
        int i = (b - 2600) * 256 + t; Wb2[i] = __float2bfloat16(mid_w2[i]);
    } else if (b < 3880) {
        int i = (b - 3624) * 256 + t; Wb3[i] = __float2bfloat16(mid_w3[i]);
    } else if (b < 4008) {
        int n = b - 3880; Wpe[n * 256 + t] = __float2bfloat16(pe_w2[t * 128 + n]);
    } else if (b < 4072) {    // packed offsw weight: 64 rows (24 off + 32 sw + 8 zero)
        int n = b - 4008;
        if (t < 128) {
            float w = 0.f;
            if (n < 24)      w = off_w[n * 128 + t];
            else if (n < 56) w = sw_w[(n - 24) * 128 + t];
            Wof[n * 128 + t] = __float2bfloat16(w);
            if (t == 0) Bof[n] = (n < 24) ? off_b[n] : ((n < 56) ? sw_b[n - 24] : 0.f);
        }
    } else if (b < 4200) {
        int o = b - 4072;
        for (int idx = t; idx < 1152; idx += 256) {
            int s = idx >> 7, i = idx & 127;
            Wcv1[o * 1152 + idx] = __float2bfloat16(in_w[(o * 128 + i) * 9 + s]);
        }
    } else if (b < 4328) {
        int o = b - 4200;
        for (int idx = t; idx < 1152; idx += 256) {
            int s = idx >> 7, i = idx & 127;
            Wcv2[o * 1152 + idx] = __float2bfloat16(out_w[(o * 128 + i) * 9 + s]);
        }
    } else if (b < 4361) {    // qT border zero: 516 border pixels x 16 uint4
        int g = (b - 4328) * 256 + t;
        if (g < 8256) {
            int pixi = g >> 4, part = g & 15;
            int row, col;
            if (pixi < 130)      { row = 0;   col = pixi; }
            else if (pixi < 260) { row = 129; col = pixi - 130; }
            else {
                int r = pixi - 260;
                row = 1 + (r & 127);
                col = (r < 128) ? 0 : 129;
            }
            uint4 z = {0u, 0u, 0u, 0u};
            *(uint4*)&qTo[((size_t)row * 130 + col) * 128 + part * 8] = z;
        }
    } else if (b < 4362) {    // stats zero: 768 floats
        Stats[t] = 0.f; Stats[256 + t] = 0.f; Stats[512 + t] = 0.f;
    } else {                  // bev_query CHW -> padded HWC bf16 interior (256 blocks)
        int rel = b - 4362;
        int y = rel >> 1, x0 = (rel & 1) * 64;
        int xi = t & 63, c0 = t >> 6;
        for (int c = c0; c < 128; c += 4)
            tile[c * 65 + xi] = bev_query[c * HW + y * 128 + x0 + xi];
        __syncthreads();
        int xp = t >> 2, cg = (t & 3) * 32;
        __hip_bfloat16* dst = qTo + ((size_t)(y + 1) * 130 + (x0 + 1 + xp)) * 128;
        #pragma unroll
        for (int g = 0; g < 4; g++) {
            int c = cg + g * 8;
            union { __hip_bfloat16 h[8]; uint4 u; } pk;
            #pragma unroll
            for (int j = 0; j < 8; j++)
                pk.h[j] = __float2bfloat16(tile[(c + j) * 65 + xp]);
            *(uint4*)&dst[c] = pk.u;
        }
    }
}

// ---------------- CHW fp32 [128][128^2] -> padded HWC bf16 [130][130][128] (interior) ----------------
// stats (optional): per-channel {sum, sumsq}; applies instance-norm while packing.
__global__ __launch_bounds__(256) void chw2hwc_pad_k(
    const float* __restrict__ q, const float* __restrict__ stats,
    __hip_bfloat16* __restrict__ out)
{
    __shared__ float tile[128][65];
    __shared__ float sm[128], sr[128];
    int t = threadIdx.x;
    if (t < 128) {
        if (stats) {
            float s = stats[2 * t], s2 = stats[2 * t + 1];
            float mean = s * (1.0f / HW);
            sm[t] = mean;
            sr[t] = rsqrtf(s2 * (1.0f / HW) - mean * mean + 1e-5f);
        } else {
            sm[t] = 0.f; sr[t] = 1.f;
        }
    }
    int b = blockIdx.x;            // 256 blocks: y = b>>1, x0 = (b&1)*64
    int y = b >> 1, x0 = (b & 1) * 64;
    int xi = t & 63, c0 = t >> 6;
    for (int c = c0; c < 128; c += 4)
        tile[c][xi] = q[c * HW + y * 128 + x0 + xi];
    __syncthreads();
    int xp = t >> 2, cg = (t & 3) * 32;
    __hip_bfloat16* dst = out + ((size_t)(y + 1) * 130 + (x0 + 1 + xp)) * 128;
    #pragma unroll
    for (int g = 0; g < 4; g++) {
        int c = cg + g * 8;
        union { __hip_bfloat16 h[8]; uint4 u; } pk;
        #pragma unroll
        for (int j = 0; j < 8; j++)
            pk.h[j] = __float2bfloat16((tile[c + j][xp] - sm[c + j]) * sr[c + j]);
        *(uint4*)&dst[c] = pk.u;
    }
}

// ---------------- bf16 MFMA GEMM: out[m][n] = act(bias[n] + sum_k X[m][k] W[n][k]) ----------------
// OUTT: 0 -> bf16 [M][N]; 1 -> fp32 [N][M] (CHW, + optional residual res[n][m]).
// CONV: X is padded HWC bf16 [130][130][128]; k = s*128+c.
// rstats: normalize residual with {sum,sumsq}; ostats: accumulate output {sum,sumsq} (OUTT==1 only).
// K-loop: NBUF-deep LDS pipeline with counted vmcnt (never 0 in steady state) + raw s_barrier.
// LDS XOR-swizzle (both-sides): global source chunk permuted on stage, ds_read slot permuted to match.
// BK: 32 or 64. NX: column-blocks per row-tile; 1D grid with reuse-aware XCD swizzle so the
// NX blocks sharing an A-tile land on the SAME XCD (bid mod 8) -> A stays in that XCD's L2.
template<int BM, int BN, int BK, int ACT, int OUTT, int CONV, int NX>
__global__ __launch_bounds__(256) void bgemm_k(
    const __hip_bfloat16* __restrict__ X, const __hip_bfloat16* __restrict__ W,
    const float* __restrict__ bias, void* __restrict__ outp,
    const float* __restrict__ res,
    const float* __restrict__ rstats, float* __restrict__ ostats,
    int M, int K, int N)
{
    constexpr int ROWS = BM + BN;
    constexpr int CPR  = BK / 8;                       // 16B chunks per row
    constexpr int ITERS = (ROWS * CPR) / 256;          // global_load_lds per lane per stage
    constexpr int BUFE  = ROWS * BK;                   // bf16 elements per buffer
    constexpr int NBUF  = (BK == 64) ? 4 : ((ITERS == 2) ? 4 : 3);
    __shared__ __align__(16) __hip_bfloat16 SH[NBUF * BUFE];
    int t = threadIdx.x;
    int w = t >> 6, lane = t & 63;
    // reuse-aware XCD swizzle: all NX col-blocks of one row-tile share (g & 7) -> same XCD.
    int g = blockIdx.x;
    int nyq = (int)(gridDim.x >> 3) / NX;              // NY/8
    int s0 = g >> 3;
    int mb = ((g & 7) * nyq + s0 / NX) * BM;
    int nb = (s0 % NX) * BN;
    int cy = mb >> 7, cx = mb & 127;   // conv tile coords (CONV only)
    constexpr int WM = BM / 2;
    constexpr int MI = WM / 16;
    constexpr int NJ = BN / 32;
    int wm = (w & 1) * WM, wn = (w >> 1) * (BN / 2);
    int lm = lane & 15, lq = lane >> 4;
    int sl = (lq ^ ((lm >> 1) & 3)) * 8;               // BK=32 swizzled k-slot
    floatx4 zero = {0.f, 0.f, 0.f, 0.f};
    floatx4 acc[MI][NJ];
    #pragma unroll
    for (int i = 0; i < MI; i++)
        #pragma unroll
        for (int j = 0; j < NJ; j++) acc[i][j] = zero;

    const int nsteps = K / BK;

    auto STAGE = [&](int bufi, int tk2) {
        int kb_ = tk2 * BK;
        int s_ = kb_ >> 7;
        int dyi_ = s_ / 3, dxi_ = s_ - dyi_ * 3;       // tap indices (CONV only)
        #pragma unroll
        for (int it = 0; it < ITERS; it++) {
            int chunk = it * 256 + t;
            int row, ko;
            if constexpr (BK == 32) {
                row = chunk >> 2;
                ko = ((chunk & 3) ^ ((row >> 1) & 3)) * 8;
            } else {
                row = chunk >> 3;
                ko = ((chunk & 7) ^ (row & 7)) * 8;
            }
            const __hip_bfloat16* src;
            if (row < BM) {
                if (CONV)
                    src = X + (((size_t)(cy + dyi_) * 130) + (cx + dxi_ + row)) * 128 + (kb_ & 127) + ko;
                else
                    src = X + (size_t)(mb + row) * K + kb_ + ko;
            } else {
                src = W + (size_t)(nb + row - BM) * K + kb_ + ko;
            }
            __builtin_amdgcn_global_load_lds(
                (const __attribute__((address_space(1))) void*)src,
                (__attribute__((address_space(3))) void*)&SH[bufi * BUFE + (it * 256 + (t & ~63)) * 8],
                16, 0, 0);
        }
    };

    #pragma unroll
    for (int pi = 0; pi < NBUF - 1; pi++)
        if (pi < nsteps) STAGE(pi, pi);

    for (int tk = 0; tk < nsteps; ++tk) {
        int rem = nsteps - 1 - tk;
        if constexpr (NBUF == 4 && ITERS == 2) {
            if (rem >= 2)      asm volatile("s_waitcnt vmcnt(4)" ::: "memory");
            else if (rem == 1) asm volatile("s_waitcnt vmcnt(2)" ::: "memory");
            else               asm volatile("s_waitcnt vmcnt(0)" ::: "memory");
        } else if constexpr (NBUF == 4) {              // ITERS == 4 (BK=64)
            if (rem >= 2)      asm volatile("s_waitcnt vmcnt(8)" ::: "memory");
            else if (rem == 1) asm volatile("s_waitcnt vmcnt(4)" ::: "memory");
            else               asm volatile("s_waitcnt vmcnt(0)" ::: "memory");
        } else {                                       // NBUF==3, ITERS==4
            if (rem >= 1)      asm volatile("s_waitcnt vmcnt(4)" ::: "memory");
            else               asm volatile("s_waitcnt vmcnt(0)" ::: "memory");
        }
        __builtin_amdgcn_s_barrier();
        int tkn = tk + NBUF - 1;
        if (tkn < nsteps) STAGE(tkn % NBUF, tkn);

        const __hip_bfloat16* As = SH + (tk % NBUF) * BUFE;
        const __hip_bfloat16* Bs = As + BM * BK;
        if constexpr (BK == 32) {
            short8 af[MI], bf[NJ];
            #pragma unroll
            for (int i = 0; i < MI; i++)
                af[i] = *(const short8*)&As[(wm + i * 16 + lm) * 32 + sl];
            #pragma unroll
            for (int j = 0; j < NJ; j++)
                bf[j] = *(const short8*)&Bs[(wn + j * 16 + lm) * 32 + sl];
            #pragma unroll
            for (int i = 0; i < MI; i++)
                #pragma unroll
                for (int j = 0; j < NJ; j++)
                    acc[i][j] = __builtin_amdgcn_mfma_f32_16x16x32_bf16(af[i], bf[j], acc[i][j], 0, 0, 0);
        } else {
            short8 af[MI][2], bf[NJ][2];
            #pragma unroll
            for (int i = 0; i < MI; i++) {
                int ra = wm + i * 16 + lm, sw = ra & 7;
                af[i][0] = *(const short8*)&As[ra * 64 + (lq ^ sw) * 8];
                af[i][1] = *(const short8*)&As[ra * 64 + ((4 | lq) ^ sw) * 8];
            }
            #pragma unroll
            for (int j = 0; j < NJ; j++) {
                int rb = wn + j * 16 + lm, sw = rb & 7;
                bf[j][0] = *(const short8*)&Bs[rb * 64 + (lq ^ sw) * 8];
                bf[j][1] = *(const short8*)&Bs[rb * 64 + ((4 | lq) ^ sw) * 8];
            }
            #pragma unroll
            for (int i = 0; i < MI; i++)
                #pragma unroll
                for (int j = 0; j < NJ; j++) {
                    acc[i][j] = __builtin_amdgcn_mfma_f32_16x16x32_bf16(af[i][0], bf[j][0], acc[i][j], 0, 0, 0);
                    acc[i][j] = __builtin_amdgcn_mfma_f32_16x16x32_bf16(af[i][1], bf[j][1], acc[i][j], 0, 0, 0);
                }
        }
    }

    float invM = 1.0f / (float)M;
    #pragma unroll
    for (int j = 0; j < NJ; j++) {
        int n = nb + wn + j * 16 + lm;
        float bv = bias[n];
        float rmean = 0.f, rrstd = 0.f;
        if (OUTT == 1 && res && rstats) {
            float s = rstats[2 * n], s2 = rstats[2 * n + 1];
            rmean = s * invM;
            rrstd = rsqrtf(s2 * invM - rmean * rmean + 1e-5f);
        }
        float ss = 0.f, ss2 = 0.f;
        #pragma unroll
        for (int i = 0; i < MI; i++) {
            #pragma unroll
            for (int r = 0; r < 4; r++) {
                int m = mb + wm + i * 16 + lq * 4 + r;
                float v = acc[i][j][r] + bv;
                if (ACT) v = gelu_exact(v);
                if (OUTT == 0) {
                    ((__hip_bfloat16*)outp)[(size_t)m * N + n] = __float2bfloat16(v);
                } else {
                    if (res) {
                        float rv = res[(size_t)n * M + m];
                        v += rstats ? (rv - rmean) * rrstd : rv;
                    }
                    ((float*)outp)[(size_t)n * M + m] = v;
                    ss += v; ss2 += v * v;
                }
            }
        }
        if (OUTT == 1 && ostats) {
            ss  += __shfl_xor(ss, 16);  ss  += __shfl_xor(ss, 32);
            ss2 += __shfl_xor(ss2, 16); ss2 += __shfl_xor(ss2, 32);
            if (lq == 0) {
                atomicAdd(&ostats[2 * n], ss);
                atomicAdd(&ostats[2 * n + 1], ss2);
            }
        }
    }
}

// ---------------- fused offsets/sample-weights GEMM + epilogue ----------------
// BM=BN=64, K=128, CONV-style X addressing (center tap of padded normalized q0).
// Block (1D grid, 256 blocks) holds ALL 64 channels for its 64 pixels, so the
// offpost math (sigmoid->pts/height, 4-way softmax->swn) runs in-register.
// Softmax group (l = n&3) = 4 adjacent lanes -> shfl_xor(1)+shfl_xor(2).
__global__ __launch_bounds__(256) void offgemm_k(
    const __hip_bfloat16* __restrict__ X, const __hip_bfloat16* __restrict__ W,
    const float* __restrict__ bias, const float* __restrict__ bev_pos,
    float* __restrict__ pts, float* __restrict__ swn, float* __restrict__ height_out)
{
    constexpr int BUFE = 128 * 32;
    __shared__ __align__(16) __hip_bfloat16 SH[4 * BUFE];
    int t = threadIdx.x;
    int w = t >> 6, lane = t & 63;
    int mb = blockIdx.x * 64;
    int cy = mb >> 7, cx = mb & 127;
    int wm = (w & 1) * 32, wn = (w >> 1) * 32;
    int lm = lane & 15, lq = lane >> 4;
    int sl = (lq ^ ((lm >> 1) & 3)) * 8;
    floatx4 zero = {0.f, 0.f, 0.f, 0.f};
    floatx4 acc[2][2];
    acc[0][0] = zero; acc[0][1] = zero; acc[1][0] = zero; acc[1][1] = zero;

    auto STAGE = [&](int bufi, int tk2) {
        int kb_ = tk2 * 32;
        #pragma unroll
        for (int it = 0; it < 2; it++) {
            int chunk = it * 256 + t;
            int row = chunk >> 2;
            int ko = ((chunk & 3) ^ ((row >> 1) & 3)) * 8;
            const __hip_bfloat16* src;
            if (row < 64) src = X + ((size_t)cy * 130 + cx + row) * 128 + kb_ + ko;
            else          src = W + (size_t)(row - 64) * 128 + kb_ + ko;
            __builtin_amdgcn_global_load_lds(
                (const __attribute__((address_space(1))) void*)src,
                (__attribute__((address_space(3))) void*)&SH[bufi * BUFE + (it * 256 + (t & ~63)) * 8],
                16, 0, 0);
        }
    };

    STAGE(0, 0); STAGE(1, 1); STAGE(2, 2);
    for (int tk = 0; tk < 4; ++tk) {
        int rem = 3 - tk;
        if (rem >= 2)      asm volatile("s_waitcnt vmcnt(4)" ::: "memory");
        else if (rem == 1) asm volatile("s_waitcnt vmcnt(2)" ::: "memory");
        else               asm volatile("s_waitcnt vmcnt(0)" ::: "memory");
        __builtin_amdgcn_s_barrier();
        if (tk + 3 < 4) STAGE((tk + 3) & 3, tk + 3);
        const __hip_bfloat16* As = SH + (tk & 3) * BUFE;
        const __hip_bfloat16* Bs = As + 64 * 32;
        short8 af[2], bf[2];
        #pragma unroll
        for (int i = 0; i < 2; i++)
            af[i] = *(const short8*)&As[(wm + i * 16 + lm) * 32 + sl];
        #pragma unroll
        for (int j = 0; j < 2; j++)
            bf[j] = *(const short8*)&Bs[(wn + j * 16 + lm) * 32 + sl];
        #pragma unroll
        for (int i = 0; i < 2; i++)
            #pragma unroll
            for (int j = 0; j < 2; j++)
                acc[i][j] = __builtin_amdgcn_mfma_f32_16x16x32_bf16(af[i], bf[j], acc[i][j], 0, 0, 0);
    }

    const float rngv[3]  = {100.f, 100.f, 8.f};
    const float pcm[3]   = {-50.f, -50.f, -4.f};
    #pragma unroll
    for (int j = 0; j < 2; j++) {
        int n = wn + j * 16 + lm;
        float bv = bias[n];
        int p3 = n / 3, d3 = n - p3 * 3;                 // off path (n<24)
        float lim = (d3 == 2) ? (4.0f + 1e-6f) : (0.25f + 1e-6f);
        #pragma unroll
        for (int i = 0; i < 2; i++) {
            #pragma unroll
            for (int r = 0; r < 4; r++) {
                int m = mb + wm + i * 16 + lq * 4 + r;
                float v = acc[i][j][r] + bv;
                // softmax over 4-lane groups, executed by all lanes (writes predicated)
                float mm = fmaxf(v, __shfl_xor(v, 1));
                mm = fmaxf(mm, __shfl_xor(mm, 2));
                float e = expf(v - mm);
                float s = e + __shfl_xor(e, 1);
                s += __shfl_xor(s, 2);
                if (n < 24) {
                    float sv = 1.f / (1.f + expf(-v));
                    float offv = sv * 2.f * lim - lim;
                    float refv = bev_pos[m * 3 + d3] * rngv[d3] + pcm[d3];
                    pts[m * 24 + n] = refv + offv;
                    if (d3 == 2) height_out[p3 * HW + m] = offv;
                } else if (n < 56) {
                    swn[m * 32 + (n - 24)] = e / s;
                }
            }
        }
    }
}

// ---------------- fused PE: hidden = relu(rn @ w1 + b1) on the fly, GEMM vs Wpe ----------------
__global__ __launch_bounds__(256) void pe_bgemm_k(
    const float* __restrict__ pts, const float* __restrict__ pe_w1,
    const float* __restrict__ pe_b1, const __hip_bfloat16* __restrict__ W,
    const float* __restrict__ bias, __hip_bfloat16* __restrict__ out)
{
    __shared__ __align__(16) __hip_bfloat16 As[128 * 32];
    __shared__ __align__(16) __hip_bfloat16 Bs[128 * 32];
    __shared__ __align__(16) float wps[4][256];   // [b1, w1_x, w1_y, w1_z][256]
    int t = threadIdx.x;
    int w = t >> 6, lane = t & 63;
    int mb = blockIdx.x * 128;
    {
        int d = t >> 6, c = (t & 63) * 4;
        float4 v;
        if (d == 0) v = *(const float4*)&pe_b1[c];
        else        v = *(const float4*)&pe_w1[(d - 1) * 256 + c];
        *(float4*)&wps[d][c] = v;
    }
    int cg = t & 3;
    int r0 = t >> 2;
    float rn[2][3];
    #pragma unroll
    for (int h = 0; h < 2; h++) {
        int r = mb + r0 + h * 64;
        rn[h][0] = (pts[(size_t)r * 3 + 0] + 50.f) * 0.01f;
        rn[h][1] = (pts[(size_t)r * 3 + 1] + 50.f) * 0.01f;
        rn[h][2] = (pts[(size_t)r * 3 + 2] + 4.f) * 0.125f;
    }
    int wm = (w & 1) * 64, wn = (w >> 1) * 64;
    int lm = lane & 15, lq = lane >> 4;
    floatx4 zero = {0.f, 0.f, 0.f, 0.f};
    floatx4 acc[4][4];
    #pragma unroll
    for (int i = 0; i < 4; i++)
        #pragma unroll
        for (int j = 0; j < 4; j++) acc[i][j] = zero;
    for (int kb = 0; kb < 256; kb += 32) {
        __syncthreads();
        #pragma unroll
        for (int it = 0; it < 2; it++) {
            int chunk = it * 256 + t;
            int brow = chunk >> 2, ko = (chunk & 3) * 8;
            const __hip_bfloat16* src = W + (size_t)brow * 256 + kb + ko;
            __builtin_amdgcn_global_load_lds(
                (const __attribute__((address_space(1))) void*)src,
                (__attribute__((address_space(3))) void*)&Bs[(size_t)(it * 256 + (t & ~63)) * 8],
                16, 0, 0);
        }
        int c0 = kb + cg * 8;
        float4 bva = *(const float4*)&wps[0][c0], bvb = *(const float4*)&wps[0][c0 + 4];
        float4 wxa = *(const float4*)&wps[1][c0], wxb = *(const float4*)&wps[1][c0 + 4];
        float4 wya = *(const float4*)&wps[2][c0], wyb = *(const float4*)&wps[2][c0 + 4];
        float4 wza = *(const float4*)&wps[3][c0], wzb = *(const float4*)&wps[3][c0 + 4];
        #pragma unroll
        for (int h = 0; h < 2; h++) {
            const float* bv = (const float*)&bva;
            const float* wx = (const float*)&wxa;
            const float* wy = (const float*)&wya;
            const float* wz = (const float*)&wza;
            union { __hip_bfloat16 hh[8]; uint4 u; } pk;
            #pragma unroll
            for (int j = 0; j < 4; j++) {
                float v = bv[j] + rn[h][0] * wx[j] + rn[h][1] * wy[j] + rn[h][2] * wz[j];
                pk.hh[j] = __float2bfloat16(fmaxf(v, 0.f));
            }
            bv = (const float*)&bvb; wx = (const float*)&wxb;
            wy = (const float*)&wyb; wz = (const float*)&wzb;
            #pragma unroll
            for (int j = 0; j < 4; j++) {
                float v = bv[j] + rn[h][0] * wx[j] + rn[h][1] * wy[j] + rn[h][2] * wz[j];
                pk.hh[4 + j] = __float2bfloat16(fmaxf(v, 0.f));
            }
            *(uint4*)&As[(r0 + h * 64) * 32 + cg * 8] = pk.u;
        }
        __syncthreads();
        short8 af[4], bf[4];
        #pragma unroll
        for (int i = 0; i < 4; i++)
            af[i] = *(const short8*)&As[(wm + i * 16 + lm) * 32 + lq * 8];
        #pragma unroll
        for (int j = 0; j < 4; j++)
            bf[j] = *(const short8*)&Bs[(wn + j * 16 + lm) * 32 + lq * 8];
        #pragma unroll
        for (int i = 0; i < 4; i++)
            #pragma unroll
            for (int j = 0; j < 4; j++)
                acc[i][j] = __builtin_amdgcn_mfma_f32_16x16x32_bf16(af[i], bf[j], acc[i][j], 0, 0, 0);
    }
    #pragma unroll
    for (int i = 0; i < 4; i++) {
        #pragma unroll
        for (int j = 0; j < 4; j++) {
            int n = wn + j * 16 + lm;
            float bv = bias[n];
            #pragma unroll
            for (int r = 0; r < 4; r++) {
                int m = mb + wm + i * 16 + lq * 4 + r;
                out[(size_t)m * 128 + n] = __float2bfloat16(acc[i][j][r] + bv);
            }
        }
    }
}

// ---------------- final instance norm apply (stats precomputed in producer epilogue) ----------------
__global__ __launch_bounds__(256) void inorm_apply_k(
    const float* __restrict__ in, const float* __restrict__ stats, float* __restrict__ out)
{
    int b = blockIdx.x;           // 1024 blocks: c = b>>3, seg = b&7 (2048 floats each)
    int c = b >> 3, seg = b & 7;
    float s = stats[2 * c], s2 = stats[2 * c + 1];
    float mean = s * (1.0f / HW);
    float rstd = rsqrtf(s2 * (1.0f / HW) - mean * mean + 1e-5f);
    const float4* pi = (const float4*)(in + (size_t)c * HW + seg * 2048);
    float4*       po = (float4*)(out + (size_t)c * HW + seg * 2048);
    int t = threadIdx.x;
    #pragma unroll
    for (int k = 0; k < 2; k++) {
        float4 v = pi[t + k * 256];
        v.x = (v.x - mean) * rstd; v.y = (v.y - mean) * rstd;
        v.z = (v.z - mean) * rstd; v.w = (v.w - mean) * rstd;
        po[t + k * 256] = v;
    }
}

// ---------------- sampling: phase-1 projection + cull, phase-2 bf16 packed gather ----------------
// 256 threads = 4 waves; wave wv owns p = wv*2 + {0,1}; offsets stored as BYTE offsets;
// main loop processes 2 taps/iter with split accumulators (8 loads in flight).
__global__ __launch_bounds__(256) void sample_k(
    const __hip_bfloat16* __restrict__ featT, const float* __restrict__ pts,
    const float* __restrict__ swn,   const float* __restrict__ l2i,
    __hip_bfloat16* __restrict__ sf)
{
    int pix = blockIdx.x;
    int t = threadIdx.x;
    int lane = t & 63, wv = t >> 6;
    __shared__ float pts_s[24];
    __shared__ float swl_s[32];
    __shared__ float M[96];
    __shared__ __align__(16) int   offs[8][24][4];   // byte offsets into featT
    __shared__ __align__(16) float wts[8][24][4];
    __shared__ int cnt[8];
    if (t < 96) M[t] = l2i[t];
    if (t < 24) pts_s[t] = pts[pix * 24 + t];
    if (t < 32) swl_s[t] = swn[pix * 32 + t];
    if (t < 8)  cnt[t] = 0;
    __syncthreads();

    floatx2 acc[2];
    #pragma unroll
    for (int i = 0; i < 2; i++) {
        unsigned int u = *(const unsigned int*)&sf[(size_t)pix * 1024 + (wv * 2 + i) * 128 + 2 * lane];
        acc[i] = bf2x(u);
    }

    const int lHt[4] = {32, 16, 8, 4}, lWt[4] = {88, 44, 22, 11};
    const int loff[4] = {0, 2162688, 2703360, 2838528};
    if (t < 192) {
        int p = t / 24;
        int rr = t - p * 24;
        int n = rr >> 2, l = rr & 3;
        float X = pts_s[p * 3], Y = pts_s[p * 3 + 1], Z = pts_s[p * 3 + 2];
        const float* Mn = &M[n * 16];
        float zc = Mn[8] * X + Mn[9] * Y + Mn[10] * Z + Mn[11];
        if (zc > 1e-5f) {
            float inv = 1.f / zc;
            float xn = (Mn[0] * X + Mn[1] * Y + Mn[2] * Z + Mn[3]) * inv * (1.f / 704.f);
            float yn = (Mn[4] * X + Mn[5] * Y + Mn[6] * Z + Mn[7]) * inv * (1.f / 256.f);
            int Wl = lWt[l], Hl = lHt[l];
            float px = xn * Wl - 0.5f, py = yn * Hl - 0.5f;
            px = fminf(fmaxf(px, -2.f), (float)(Wl + 1));
            py = fminf(fmaxf(py, -2.f), (float)(Hl + 1));
            float x0f = floorf(px), y0f = floorf(py);
            float wx = px - x0f, wy = py - y0f;
            int x0 = (int)x0f, y0 = (int)y0f;
            bool xi0 = (unsigned)x0 < (unsigned)Wl, xi1 = (unsigned)(x0 + 1) < (unsigned)Wl;
            bool yi0 = (unsigned)y0 < (unsigned)Hl, yi1 = (unsigned)(y0 + 1) < (unsigned)Hl;
            if ((xi0 || xi1) && (yi0 || yi1)) {
                float wl = swl_s[p * 4 + l];
                float w00 = wl * (1.f - wx) * (1.f - wy) * (float)(xi0 && yi0);
                float w10 = wl * wx * (1.f - wy)         * (float)(xi1 && yi0);
                float w01 = wl * (1.f - wx) * wy         * (float)(xi0 && yi1);
                float w11 = wl * wx * wy                 * (float)(xi1 && yi1);
                int x0c = min(max(x0, 0), Wl - 1), x1c = min(max(x0 + 1, 0), Wl - 1);
                int y0c = min(max(y0, 0), Hl - 1), y1c = min(max(y0 + 1, 0), Hl - 1);
                int base = loff[l] + n * Hl * Wl * 128;
                int idx = atomicAdd(&cnt[p], 1);
                offs[p][idx][0] = (base + (y0c * Wl + x0c) * 128) * 2;
                offs[p][idx][1] = (base + (y0c * Wl + x1c) * 128) * 2;
                offs[p][idx][2] = (base + (y1c * Wl + x0c) * 128) * 2;
                offs[p][idx][3] = (base + (y1c * Wl + x1c) * 128) * 2;
                wts[p][idx][0] = w00; wts[p][idx][1] = w10;
                wts[p][idx][2] = w01; wts[p][idx][3] = w11;
            }
        }
    }
    __syncthreads();

    const char* fbase = (const char*)featT;
    int lane4 = lane * 4;
    #pragma unroll
    for (int i = 0; i < 2; i++) {
        int p = wv * 2 + i;
        int np = cnt[p];
        floatx2 a0 = acc[i];
        floatx2 a1 = {0.f, 0.f};
        int j = 0;
        #pragma unroll 1
        for (; j + 2 <= np; j += 2) {
            int4   oA = *(const int4*)&offs[p][j][0];
            float4 wA = *(const float4*)&wts[p][j][0];
            int4   oB = *(const int4*)&offs[p][j + 1][0];
            float4 wB = *(const float4*)&wts[p][j + 1][0];
            unsigned int v0 = *(const unsigned int*)(fbase + (unsigned)(oA.x + lane4));
            unsigned int v1 = *(const unsigned int*)(fbase + (unsigned)(oA.y + lane4));
            unsigned int v2 = *(const unsigned int*)(fbase + (unsigned)(oA.z + lane4));
            unsigned int v3 = *(const unsigned int*)(fbase + (unsigned)(oA.w + lane4));
            unsigned int v4 = *(const unsigned int*)(fbase + (unsigned)(oB.x + lane4));
            unsigned int v5 = *(const unsigned int*)(fbase + (unsigned)(oB.y + lane4));
            unsigned int v6 = *(const unsigned int*)(fbase + (unsigned)(oB.z + lane4));
            unsigned int v7 = *(const unsigned int*)(fbase + (unsigned)(oB.w + lane4));
            a0 += bf2x(v0) * wA.x;
            a0 += bf2x(v1) * wA.y;
            a0 += bf2x(v2) * wA.z;
            a0 += bf2x(v3) * wA.w;
            a1 += bf2x(v4) * wB.x;
            a1 += bf2x(v5) * wB.y;
            a1 += bf2x(v6) * wB.z;
            a1 += bf2x(v7) * wB.w;
        }
        if (j < np) {
            int4   o = *(const int4*)&offs[p][j][0];
            float4 w = *(const float4*)&wts[p][j][0];
            unsigned int v0 = *(const unsigned int*)(fbase + (unsigned)(o.x + lane4));
            unsigned int v1 = *(const unsigned int*)(fbase + (unsigned)(o.y + lane4));
            unsigned int v2 = *(const unsigned int*)(fbase + (unsigned)(o.z + lane4));
            unsigned int v3 = *(const unsigned int*)(fbase + (unsigned)(o.w + lane4));
            a0 += bf2x(v0) * w.x;
            a0 += bf2x(v1) * w.y;
            a0 += bf2x(v2) * w.z;
            a0 += bf2x(v3) * w.w;
        }
        acc[i] = a0 + a1;
    }
    #pragma unroll
    for (int i = 0; i < 2; i++) {
        union { __hip_bfloat16 h[2]; unsigned int u; } pk;
        pk.h[0] = __float2bfloat16(acc[i].x);
        pk.h[1] = __float2bfloat16(acc[i].y);
        *(unsigned int*)&sf[(size_t)pix * 1024 + (wv * 2 + i) * 128 + 2 * lane] = pk.u;
    }
}

extern "C" void kernel_launch(void* const* d_in, const int* in_sizes, int n_in,
                              void* d_out, int out_size, void* d_ws, size_t ws_size,
                              hipStream_t stream)
{
    const float* feat[4] = {(const float*)d_in[0], (const float*)d_in[1],
                            (const float*)d_in[2], (const float*)d_in[3]};
    const float* l2i       = (const float*)d_in[4];
    const float* bev_query = (const float*)d_in[5];
    const float* bev_pos   = (const float*)d_in[6];
    const float* in_w  = (const float*)d_in[7];  const float* in_b  = (const float*)d_in[8];
    const float* off_w = (const float*)d_in[9];  const float* off_b = (const float*)d_in[10];
    const float* sw_w  = (const float*)d_in[11]; const float* sw_b  = (const float*)d_in[12];
    const float* pe_w1 = (const float*)d_in[13]; const float* pe_b1 = (const float*)d_in[14];
    const float* pe_w2 = (const float*)d_in[15]; const float* pe_b2 = (const float*)d_in[16];
    const float* mid_w1 = (const float*)d_in[17]; const float* mid_b1 = (const float*)d_in[18];
    const float* mid_w2 = (const float*)d_in[19]; const float* mid_b2 = (const float*)d_in[20];
    const float* mid_w3 = (const float*)d_in[21]; const float* mid_b3 = (const float*)d_in[22];
    const float* out_w  = (const float*)d_in[23]; const float* out_b  = (const float*)d_in[24];

    float* ws = (float*)d_ws;
    float* fTf = ws;                    // 1,436,160 : transposed feats bf16
    __hip_bfloat16* fT = (__hip_bfloat16*)fTf;
    float* Bb  = fTf + 1436160;         // 2,097,152 : q1 raw (CHW)
    float* Cb  = Bb + 2097152;          // 2,097,152 : q0 raw (conv1 out, CHW)
    float* Gb  = Cb + 2097152;          // 2,097,152 : conv2 raw (CHW)
    float* Dp  = Gb + 2097152;          //   393,216 : pts
    float* Eb  = Dp + 393216;           //   524,288 : swn
    float* QTf = Eb + 524288;           // 1,081,600 : padded HWC bf16 (130*130*128)
    __hip_bfloat16* qT = (__hip_bfloat16*)QTf;
    float* SFf = QTf + 1081600;         // 8,388,608 : sf bf16 131072x128
    __hip_bfloat16* sfb = (__hip_bfloat16*)SFf;
    float* M1f = SFf + 8388608;         // 4,194,304 : m1 bf16
    __hip_bfloat16* m1b = (__hip_bfloat16*)M1f;
    float* M2f = M1f + 4194304;         // 4,194,304 : m2 bf16
    __hip_bfloat16* m2b = (__hip_bfloat16*)M2f;
    float* WC1 = M2f + 4194304;         //    73,728 : conv1 weights bf16
    __hip_bfloat16* Wcv1 = (__hip_bfloat16*)WC1;
    float* WC2 = WC1 + 73728;           //    73,728 : conv2 weights bf16
    __hip_bfloat16* Wcv2 = (__hip_bfloat16*)WC2;
    float* W1f = WC2 + 73728;           //   262,144
    __hip_bfloat16* Wb1 = (__hip_bfloat16*)W1f;
    float* W2f = W1f + 262144;          //   131,072
    __hip_bfloat16* Wb2 = (__hip_bfloat16*)W2f;
    float* W3f = W2f + 131072;          //    32,768
    __hip_bfloat16* Wb3 = (__hip_bfloat16*)W3f;
    float* WPf = W3f + 32768;           //    16,384 : pe_w2^T bf16
    __hip_bfloat16* Wpe = (__hip_bfloat16*)WPf;
    float* WOf = WPf + 16384;           //     8,192 : offsw packed weight bf16 (64x128 used)
    __hip_bfloat16* Wof = (__hip_bfloat16*)WOf;
    float* Bof = WOf + 8192;            //       128 : offsw packed bias fp32 (64 used)
    float* Stats = Bof + 128;           //       768 : 3 x 128 x {sum,sumsq}
    float* stats1 = Stats;
    float* stats2 = Stats + 256;
    float* stats3 = Stats + 512;

    float* q_out = (float*)d_out;
    float* h_out = q_out + 2097152;

    // setup: feat transpose + weight prep + qT border zero + stats zero + bev_query pad
    setup_k<<<4618, 256, 0, stream>>>(feat[0], feat[1], feat[2], feat[3], fT,
                                      mid_w1, mid_w2, mid_w3, pe_w2, off_w, off_b, sw_w, sw_b,
                                      in_w, out_w, bev_query,
                                      Wb1, Wb2, Wb3, Wpe, Wof, Bof, Wcv1, Wcv2,
                                      qT, Stats);

    // conv1: q0raw = bev_query + conv3x3(bev_query) -> Cb, stats1 accumulated in epilogue
    bgemm_k<64, 64, 64, 0, 1, 1, 2><<<512, 256, 0, stream>>>(
        qT, Wcv1, in_b, Cb, bev_query, nullptr, stats1, HW, 1152, 128);

    // offsets/sample-weights: normalized-q0 pack, then fused GEMM+epilogue -> pts/swn/height
    chw2hwc_pad_k<<<256, 256, 0, stream>>>(Cb, stats1, qT);   // applies inorm(q0raw)
    offgemm_k<<<256, 256, 0, stream>>>(qT + 131 * 128, Wof, Bof, bev_pos, Dp, Eb, h_out);

    // fused PE (hidden on the fly + MFMA GEMM) -> sf
    pe_bgemm_k<<<1024, 256, 0, stream>>>(Dp, pe_w1, pe_b1, Wpe, pe_b2, sfb);

    // sampling accumulates taps onto sf
    sample_k<<<HW, 256, 0, stream>>>(fT, Dp, Eb, l2i, sfb);

    // mid MLP: 1024 -> 512 gelu -> 512 gelu -> 128 linear (+ normalized q0 residual)
    bgemm_k<128, 128, 32, 1, 0, 0, 4><<<512, 256, 0, stream>>>(
        sfb, Wb1, mid_b1, m1b, nullptr, nullptr, nullptr, HW, 1024, 512);
    bgemm_k<128, 128, 32, 1, 0, 0, 4><<<512, 256, 0, stream>>>(
        m1b, Wb2, mid_b2, m2b, nullptr, nullptr, nullptr, HW, 512, 512);
    bgemm_k<64, 64, 64, 0, 1, 0, 2><<<512, 256, 0, stream>>>(
        m2b, Wb3, mid_b3, Bb, Cb, stats1, stats2, HW, 512, 128);   // q1raw -> Bb, stats2

    // conv2: q = inorm(q1n + conv3x3(q1n)); q1n applied on the fly from stats2
    chw2hwc_pad_k<<<256, 256, 0, stream>>>(Bb, stats2, qT);
    bgemm_k<64, 64, 64, 0, 1, 1, 2><<<512, 256, 0, stream>>>(
        qT, Wcv2, out_b, Gb, Bb, stats2, stats3, HW, 1152, 128);   // conv2 raw -> Gb, stats3
    inorm_apply_k<<<1024, 256, 0, stream>>>(Gb, stats3, q_out);
}